// Round 5
// baseline (858.798 us; speedup 1.0000x reference)
//
#include <hip/hip_runtime.h>
#include <hip/hip_bf16.h>

// STU forward, R5: global_load_lds(16B) staging in all GEMM variants,
// conv split-K=4 with XCD-grouped rectangle grid + bf16 partials.
// Sizes: B=2, L=1024, K=24(x2 branches), D=512, K_U=3, K_Y=2.

typedef unsigned short u16;
typedef __attribute__((ext_vector_type(8))) short  vshort8;
typedef __attribute__((ext_vector_type(4))) short  vshort4;
typedef __attribute__((ext_vector_type(4))) float  f32x4;
typedef __attribute__((ext_vector_type(4))) unsigned int vuint4;

__device__ __forceinline__ u16 f2b(float x) {
  __hip_bfloat16 h = __float2bfloat16(x);
  return __builtin_bit_cast(u16, h);
}
__device__ __forceinline__ float b2f(u16 x) {
  unsigned int u = ((unsigned int)x) << 16;
  return __builtin_bit_cast(float, u);
}

// async global->LDS, 16B per lane; LDS dest = wave-uniform base + lane*16
__device__ __forceinline__ void gll16(const u16* g, u16* l) {
  __builtin_amdgcn_global_load_lds((__attribute__((address_space(1))) void*)g,
                                   (__attribute__((address_space(3))) void*)l,
                                   16, 0, 0);
}

// ---------------------------------------------------------------------------
// Shared 128x128 MFMA GEMM template. C[m,n] = sum_k A[m,k]*Bmat[n,k].
//  V0 GEMM1: A=X(2048x512) B=W1(26112x512), grid (16 bm, 204 bn) -> A2T + Au
//  V1 CONV : A=Wtoep strip (d=bm-cj), B=A2T, grid (256 rest, 8 bm); bf16 parts
//  V2 ZGEMM: A=gather(ybf), B=Top (H_tau blocks), splitK over tau -> zparts f32
//  V3 FIXUP: A=Abnd(64x1024), B=Top[j+1] rows -> out = acc + zf
//  V5 SGEMM: A=Top[*+bz] (512x1024), B=STc -> Top[*+bz] bf16 (batched)
//  V6 UGEMM: A=Wm(64x1024), B=S32 rows -> ubuf = acc + w_{c+1} (f32)
//  V7 ODD  : A=Abnd even rows, B=S32 rows -> Abnd odd rows = acc + w_{2k}
// ---------------------------------------------------------------------------
struct GB {
  const u16* A; const u16* B;
  float* Cf; u16* Cb;
  const float* zf; float* out;
  u16* A2T; u16* Au;
  const u16* zp;
  int M, N;
};

template<int V>
__global__ __launch_bounds__(256) void g2(GB a) {
  const int tid = threadIdx.x;
  int bn = blockIdx.x, bm = blockIdx.y;
  const int bz = blockIdx.z;
  int cj = 0, cb = 0, cd = 0, slot = 0;
  int kbeg = 0, kend = 0;
  if (V == 0) { bm = blockIdx.x; bn = blockIdx.y; kend = 512; }
  if (V == 1) {
    int rest = blockIdx.x; bm = blockIdx.y;
    bn = rest & 3; cj = (rest >> 2) & 7;
    int chcb = rest >> 5;
    cd = bm - cj;
    if (cd < 0) return;               // dead block (uniform exit)
    cb = chcb & 1;
    slot = (chcb << 3) | cj;
    kbeg = (chcb >> 1) * 1536; kend = kbeg + 1536;
  }
  const int m0 = bm * 128, n0 = bn * 128;
  if (V == 2) {
    int jmax = (m0 >> 6) + 1;
    kbeg = bz * 2048;
    kend = kbeg + 2048;
    int tk = (jmax + 1) * 512;
    if (kend > tk) kend = tk;
    if (kend < kbeg) kend = kbeg;
  }
  if (V == 3 || V == 5 || V == 6 || V == 7) kend = 1024;

  __shared__ u16 lA[4096], lB[4096];
  f32x4 acc[4][4];
#pragma unroll
  for (int i = 0; i < 4; i++)
#pragma unroll
    for (int j = 0; j < 4; j++) acc[i][j] = f32x4{0.f, 0.f, 0.f, 0.f};

  const int lane = tid & 63, wv = tid >> 6, wr = wv >> 1, wc = wv & 1;
  const u16* Ap = a.A;
  if (V == 5) Ap = a.A + (size_t)bz * 524288;
  const u16* zp = a.zp + lane * 8;

  for (int k0 = kbeg; k0 < kend; k0 += 32) {
#pragma unroll
    for (int it = 0; it < 2; ++it) {
      const int weff = wv + it * 4;
      const int lrow = weff * 16 + (lane & 15);
      const int kk = k0 + ((lane >> 4) << 3);
      // ---- A operand ----
      const u16* ga;
      if (V == 0) {
        ga = Ap + (size_t)(m0 + lrow) * 512 + kk;
      } else if (V == 1) {
        ga = Ap + (size_t)cd * 786432 + (size_t)lrow * 6144 + kk;
      } else if (V == 2) {
        int m = m0 + lrow, j = m >> 6, b = (m >> 5) & 1, c = m & 31;
        int tau = kk >> 9, p = kk & 511;
        ga = (tau > j) ? zp
                       : Ap + (size_t)(b * 1024 + c * 32 + j - tau) * 512 + p;
      } else if (V == 3) {
        int m = m0 + lrow;
        ga = (m < a.M) ? Ap + (size_t)m * 1024 + kk : zp;
      } else if (V == 5) {
        ga = Ap + (size_t)(m0 + lrow) * 1024 + kk;
      } else if (V == 6) {
        ga = (lrow < 64) ? Ap + (size_t)lrow * 1024 + kk : zp;
      } else { // V7
        if (lrow < 32) {
          int b = lrow & 1, k2 = lrow >> 1;
          ga = Ap + (size_t)(b * 32 + 2 * k2) * 1024 + kk;
        } else ga = zp;
      }
      gll16(ga, &lA[weff * 512]);
      // ---- B operand ----
      const int n = n0 + lrow;
      const u16* gb;
      if (V == 0) {
        gb = a.B + (size_t)n * 512 + kk;
      } else if (V == 1) {
        int kh = kk >> 7, sp = kk & 127;
        gb = a.B + (size_t)(cb * 512 + n) * 49152 + kh * 1024 + cj * 128 + sp;
      } else if (V == 2) {
        int tau = kk >> 9, p = kk & 511;
        gb = a.B + (size_t)tau * 524288 + (size_t)n * 1024 + p;
      } else if (V == 3) {
        int jn = n >> 9, o = n & 511;
        gb = a.B + (size_t)(jn + 1) * 524288 + (size_t)o * 1024 + kk;
      } else if (V == 5) {
        gb = a.B + (size_t)n * 1024 + kk;
      } else { // V6/V7: rows of S32 = [Top32 ; Top31]
        gb = (n < 512)
            ? a.B + (size_t)32 * 524288 + (size_t)n * 1024 + kk
            : a.B + (size_t)31 * 524288 + (size_t)(n - 512) * 1024 + kk;
      }
      gll16(gb, &lB[weff * 512]);
    }
    __syncthreads();
    vshort8 af[4], bf_[4];
#pragma unroll
    for (int s = 0; s < 4; s++) {
      af[s]  = *(const vshort8*)&lA[(((wr * 4 + s) * 4 + (lane >> 4)) * 16 + (lane & 15)) * 8];
      bf_[s] = *(const vshort8*)&lB[(((wc * 4 + s) * 4 + (lane >> 4)) * 16 + (lane & 15)) * 8];
    }
#pragma unroll
    for (int i = 0; i < 4; i++)
#pragma unroll
      for (int j = 0; j < 4; j++)
        acc[i][j] = __builtin_amdgcn_mfma_f32_16x16x32_bf16(af[i], bf_[j], acc[i][j], 0, 0, 0);
    __syncthreads();
  }

  // epilogue
#pragma unroll
  for (int i = 0; i < 4; i++) {
    int em = m0 + wr * 64 + i * 16 + ((lane >> 4) << 2);
#pragma unroll
    for (int j = 0; j < 4; j++) {
      int n = n0 + wc * 64 + j * 16 + (lane & 15);
      f32x4 v = acc[i][j];
      if (V == 0) {
        int b = em >> 10, s = em & 1023;
        if (n < 24576) {
          int kh = n >> 9, o = n & 511;
          vshort4 pk = { (short)f2b(v[0]), (short)f2b(v[1]), (short)f2b(v[2]), (short)f2b(v[3]) };
          *(vshort4*)(&a.A2T[(size_t)(b * 512 + o) * 49152 + (size_t)kh * 1024 + s]) = pk;
        } else {
          int jj = (n - 24576) >> 9, o = n & 511;
#pragma unroll
          for (int t = 0; t < 4; t++)
            a.Au[((size_t)(b * 3 + jj) * 1024 + (s + t)) * 512 + o] = f2b(v[t]);
        }
      } else if (V == 1) {
        u16* C = a.Cb + (size_t)slot * 524288;
#pragma unroll
        for (int t = 0; t < 4; t++) C[(size_t)(em + t) * 512 + n] = f2b(v[t]);
      } else if (V == 2) {
        float* C = a.Cf + (size_t)bz * 1048576;
#pragma unroll
        for (int t = 0; t < 4; t++) C[(size_t)(em + t) * 512 + n] = v[t];
      } else if (V == 3) {
        int jj = n >> 9, oo = n & 511;
#pragma unroll
        for (int t = 0; t < 4; t++) {
          int m = em + t;
          if (m < a.M) {
            int b = m >> 5, c = m & 31;
            float zv = a.zf[(size_t)(jj * 64 + b * 32 + c) * 512 + oo];
            a.out[(size_t)b * 524288 + (size_t)(c * 32 + jj) * 512 + oo] = v[t] + zv;
          }
        }
      } else if (V == 5) {
        u16* C = a.Cb + (size_t)bz * 524288;
#pragma unroll
        for (int t = 0; t < 4; t++) C[(size_t)(em + t) * 1024 + n] = f2b(v[t]);
      } else if (V == 6) {
        int jrow = (n < 512) ? 31 : 30, oo = n & 511;
#pragma unroll
        for (int t = 0; t < 4; t++) {
          int m = em + t;
          if (m < 62) {
            int b = m & 1, c = m >> 1;
            a.Cf[(size_t)m * 1024 + n] =
                v[t] + a.zf[(size_t)(jrow * 64 + b * 32 + (c + 1)) * 512 + oo];
          }
        }
      } else { // V7: odd states
        int jrow = (n < 512) ? 31 : 30, oo = n & 511;
#pragma unroll
        for (int t = 0; t < 4; t++) {
          int m = em + t;
          if (m < 32) {
            int b = m & 1, k2 = m >> 1;
            float val = v[t] + a.zf[(size_t)(jrow * 64 + b * 32 + 2 * k2) * 512 + oo];
            a.Cb[(size_t)(b * 32 + 2 * k2 + 1) * 1024 + n] = f2b(val);
          }
        }
      }
    }
  }
}

// ---------------------------------------------------------------------------
// prep / glue kernels
// ---------------------------------------------------------------------------
__global__ void k_prep_X(const float* __restrict__ u, u16* __restrict__ X, int n) {
  int i = blockIdx.x * 256 + threadIdx.x;
  if (i < n) X[i] = f2b(u[i]);
}

__global__ void k_prep_phis(const float* __restrict__ phi, const float* __restrict__ sigma,
                            float* __restrict__ phis) {
  int i = blockIdx.x * 256 + threadIdx.x;
  if (i >= 1024 * 48) return;
  int tau = i / 48, kf = i % 48, k = (kf >= 24) ? kf - 24 : kf;
  float v = phi[tau * 24 + k] * powf(sigma[k], 0.25f);
  if (kf >= 24 && (tau & 1)) v = -v;
  phis[i] = v;
}

__global__ void k_prep_W1(const float* __restrict__ Mp, const float* __restrict__ Mm,
                          const float* __restrict__ Mu, u16* __restrict__ W1) {
  int i = blockIdx.x * 256 + threadIdx.x;
  if (i >= 13369344) return;
  float v;
  if (i < 6291456) v = Mp[i];
  else if (i < 12582912) v = Mm[i - 6291456];
  else v = Mu[i - 12582912];
  W1[i] = f2b(v);
}

// Wtoep[d][t'][kh*128+s'] = phis[(d*128+t'-s')*48 + kh] (0 if tau<0)
__global__ void k_prep_Wtoep(const float* __restrict__ phis, u16* __restrict__ W) {
  int i = blockIdx.x * 256 + threadIdx.x;
  if (i >= 6291456) return;
  int kap = i % 6144, row = i / 6144;
  int tp = row & 127, d = row >> 7;
  int kh = kap >> 7, sp = kap & 127;
  int tau = d * 128 + tp - sp;
  W[i] = (tau >= 0 && tau < 1024) ? f2b(phis[tau * 48 + kh]) : (u16)0;
}

// Top[0]=[I|0], Top[1]=[M1|M2]
__global__ void k_initTop(const float* __restrict__ my, u16* __restrict__ Top) {
  int i = blockIdx.x * 256 + threadIdx.x;
  if (i >= 1048576) return;
  int mat = i >> 19, rem = i & 524287, o = rem >> 10, k = rem & 1023;
  u16 v;
  if (mat == 0) v = (k == o) ? (u16)0x3F80 : (u16)0;
  else v = (k < 512) ? f2b(my[o * 512 + k]) : f2b(my[262144 + o * 512 + (k - 512)]);
  Top[i] = v;
}

// STc[n][k] = S^c[k][n];  S^c = [Top[c]; Top[c-1]]  (tiled transpose)
__global__ __launch_bounds__(256) void k_transT(const u16* __restrict__ Top,
                                                u16* __restrict__ STc, int c) {
  __shared__ u16 tile[64][72];
  int tx = blockIdx.x, ty = blockIdx.y;  // n-tile, k-tile
  int tid = threadIdx.x;
  int r = tid >> 2, seg = tid & 3;
  int k = ty * 64 + r;
  const u16* src = (k < 512) ? Top + (size_t)c * 524288 + (size_t)k * 1024 + tx * 64
                             : Top + (size_t)(c - 1) * 524288 + (size_t)(k - 512) * 1024 + tx * 64;
  *(vuint4*)&tile[r][seg * 16]     = *(const vuint4*)(src + seg * 16);
  *(vuint4*)&tile[r][seg * 16 + 8] = *(const vuint4*)(src + seg * 16 + 8);
  __syncthreads();
  int n = tx * 64 + r;
  u16 tmp[16];
#pragma unroll
  for (int j = 0; j < 16; j++) tmp[j] = tile[seg * 16 + j][r];
  *(vuint4*)&STc[(size_t)n * 1024 + ty * 64 + seg * 16]     = *(vuint4*)&tmp[0];
  *(vuint4*)&STc[(size_t)n * 1024 + ty * 64 + seg * 16 + 8] = *(vuint4*)&tmp[8];
}

__device__ __forceinline__ void addp(float* acc, vuint4 v) {
  const unsigned int* vu = (const unsigned int*)&v;
#pragma unroll
  for (int e = 0; e < 4; ++e) {
    unsigned int pw = vu[e];
    acc[2 * e]     += __builtin_bit_cast(float, (pw & 0xffffu) << 16);
    acc[2 * e + 1] += __builtin_bit_cast(float, pw & 0xffff0000u);
  }
}

// ybf[b,t,og*8..] = sum_j Au[b,j,t-j,:] + (t>=2 ? valid bf16 conv partials : 0)
__global__ void k_combine(const u16* __restrict__ parts, const u16* __restrict__ Au,
                          u16* __restrict__ ybf) {
  int i = blockIdx.x * 256 + threadIdx.x;
  if (i >= 131072) return;
  int og = i & 63, t = (i >> 6) & 1023, b = i >> 16;
  float acc[8];
#pragma unroll
  for (int e = 0; e < 8; ++e) acc[e] = 0.f;
#pragma unroll
  for (int j = 0; j < 3; j++)
    if (t >= j)
      addp(acc, *(const vuint4*)(Au + ((size_t)(b * 3 + j) * 1024 + (t - j)) * 512 + og * 8));
  if (t >= 2) {
    int tp = t - 2, bmv = tp >> 7;
    for (int g = 0; g < 8; ++g) {
      const u16* base = parts + (size_t)(b * 0 + g * 8) * 524288 + (size_t)tp * 512 + og * 8;
      // NOTE: slot layout has no b-dim inside; b enters via cb in slot index:
      // slot = (ch*2+cb)*8+cj, cb==b selects the batch. g here = ch*2+cb, so
      // only take g with (g&1)==b.
      if ((g & 1) != b) continue;
      for (int j = 0; j <= bmv; ++j)
        addp(acc, *(const vuint4*)(base + (size_t)j * 524288));
    }
  }
  u16 o16[8];
#pragma unroll
  for (int e = 0; e < 8; ++e) o16[e] = f2b(acc[e]);
  *(vuint4*)(ybf + ((size_t)(b * 1024 + t)) * 512 + og * 8) = *(vuint4*)o16;
}

__global__ void k_zreduce(const float* __restrict__ zp, float* __restrict__ z) {
  int i = blockIdx.x * 256 + threadIdx.x;
  if (i >= 1048576) return;
  float s = 0.f;
#pragma unroll
  for (int j = 0; j < 8; j++) s += zp[(size_t)j * 1048576 + i];
  z[i] = s;
}

// Wm[(c<<1)|b][n] = bf16(w_c(b)[n]) from zf rows 31 (n<512) / 30 (n>=512)
__global__ void k_wm(const float* __restrict__ zf, u16* __restrict__ Wm) {
  int i = blockIdx.x * 256 + threadIdx.x;
  if (i >= 65536) return;
  int row = i >> 10, n = i & 1023;
  int b = row & 1, c = row >> 1;
  int jrow = (n < 512) ? 31 : 30, oo = n & 511;
  Wm[i] = f2b(zf[(size_t)(jrow * 64 + b * 32 + c) * 512 + oo]);
}

// even chain step k: E_{k+1} = S64 E_k + u_{2k}; emit Abnd row (b*32+2k+2)
__global__ __launch_bounds__(256) void k_bnd2(const u16* __restrict__ Top,
                                              const float* __restrict__ ubuf,
                                              float* __restrict__ bnd,
                                              u16* __restrict__ Abnd, int k) {
  __shared__ float st[2048];
  int tid = threadIdx.x;
  const float* s0 = bnd + (size_t)k * 2048;
  for (int j = tid; j < 2048; j += 256) st[j] = s0[j];
  __syncthreads();
  int q4 = blockIdx.x * 256 + tid;  // [0,8192)
  int q = q4 >> 2, quarter = q4 & 3;
  int b = q >> 10, kk = q & 1023;
  const u16* row = (kk < 512) ? Top + (size_t)64 * 524288 + (size_t)kk * 1024
                              : Top + (size_t)63 * 524288 + (size_t)(kk - 512) * 1024;
  const float* stb = st + b * 1024 + quarter * 256;
  const u16* rp = row + quarter * 256;
  float sum = 0.f;
  for (int t = 0; t < 32; ++t) {
    vuint4 v = *(const vuint4*)(rp + t * 8);
    const unsigned int* vu = (const unsigned int*)&v;
#pragma unroll
    for (int e = 0; e < 4; ++e) {
      unsigned int pw = vu[e];
      float lo = __builtin_bit_cast(float, (pw & 0xffffu) << 16);
      float hi = __builtin_bit_cast(float, pw & 0xffff0000u);
      sum += lo * stb[t * 8 + e * 2] + hi * stb[t * 8 + e * 2 + 1];
    }
  }
  sum += __shfl_xor(sum, 1);
  sum += __shfl_xor(sum, 2);
  if (quarter == 0) {
    float s = sum + ubuf[(size_t)(4 * k + b) * 1024 + kk];
    bnd[(size_t)(k + 1) * 2048 + b * 1024 + kk] = s;
    Abnd[(size_t)(b * 32 + 2 * k + 2) * 1024 + kk] = f2b(s);
  }
}

// ---------------------------------------------------------------------------
extern "C" void kernel_launch(void* const* d_in, const int* in_sizes, int n_in,
                              void* d_out, int out_size, void* d_ws, size_t ws_size,
                              hipStream_t stream) {
  const float* u     = (const float*)d_in[0];
  const float* Mu    = (const float*)d_in[1];
  const float* Mp    = (const float*)d_in[2];
  const float* Mm    = (const float*)d_in[3];
  const float* my    = (const float*)d_in[4];
  const float* sigma = (const float*)d_in[5];
  const float* phi   = (const float*)d_in[6];
  float* out = (float*)d_out;

  char* ws = (char*)d_ws;
  size_t off = 0;
  auto alc = [&](size_t b) { size_t p = off; off = (off + b + 255) & ~(size_t)255; return p; };
  u16*  X     = (u16*)(ws + alc(2097152));
  u16*  Wtoep = (u16*)(ws + alc(12582912));    // 8 d x 128 x 6144
  u16*  A2T   = (u16*)(ws + alc(100663296));   // (b,o)[48 kh][1024 s]
  u16*  Au    = (u16*)(ws + alc(6291456));
  u16*  W1    = (u16*)(ws + alc(26738688));    // 26112x512; parts region spans W1+tail
  char* ptail = ws + alc(40370176); (void)ptail; // W1+tail = 64 MiB exactly
  float* phis = (float*)(ws + alc(196608));
  float* bnd  = (float*)(ws + alc(131072));    // 16 even states x 2048 f32
  u16*  Abnd  = (u16*)(ws + alc(131072));      // 64 x 1024 bf16 boundary states
  u16*  Wm    = (u16*)(ws + alc(131072));      // 64 x 1024 bf16 w_c
  float* ubuf = (float*)(ws + alc(262144));    // 64 x 1024 f32 u_c
  u16*  zpad  = (u16*)(ws + alc(32768));       // zero page for predicated loads
  if (off > ws_size) return;
  // lifetime-disjoint aliases:
  u16*  partsBf = (u16*)W1;                    // 64 conv slots x [1024][512] bf16
  float* zparts = (float*)W1;                  // 8 zgemm slots x 4 MiB f32
  u16*  ybf = A2T;                             // 2 MiB (after conv)
  float* zf = (float*)((char*)A2T + (4 << 20));
  u16*  Top = (u16*)((char*)A2T + (size_t)(8 << 20));   // 65 x 1 MiB
  u16*  STc = (u16*)((char*)A2T + (size_t)(76 << 20));  // 2 MiB scratch

  hipMemsetAsync(zpad, 0, 32768, stream);

  // prep
  k_prep_X<<<dim3(4096), 256, 0, stream>>>(u, X, 1048576);
  k_prep_phis<<<dim3(192), 256, 0, stream>>>(phi, sigma, phis);
  k_prep_W1<<<dim3(52224), 256, 0, stream>>>(Mp, Mm, Mu, W1);
  k_prep_Wtoep<<<dim3(24576), 256, 0, stream>>>(phis, Wtoep);

  // GEMM1: projections (spectral plus/minus + ar_u); grid (bm,bn) for XCD reuse
  {
    GB g{}; g.A = X; g.B = W1; g.A2T = A2T; g.Au = Au; g.zp = zpad;
    g.M = 2048; g.N = 26112;
    g2<0><<<dim3(16, 204, 1), 256, 0, stream>>>(g);
  }
  // CONV: rectangle grid (256 rest, 8 bm); same-B blocks 256 apart -> same XCD
  {
    GB g{}; g.A = Wtoep; g.B = A2T; g.Cb = partsBf; g.zp = zpad;
    g.M = 1024; g.N = 512;
    g2<1><<<dim3(256, 8, 1), 256, 0, stream>>>(g);
  }
  k_combine<<<dim3(512), 256, 0, stream>>>(partsBf, Au, ybf);

  // companion-power stack Top[0..32], then Top[63],Top[64] (= S32^2 halves)
  k_initTop<<<dim3(4096), 256, 0, stream>>>(my, Top);
  {
    const int cs[5] = {1, 2, 4, 8, 16};
    for (int li = 0; li < 5; ++li) {
      int c = cs[li];
      k_transT<<<dim3(16, 16), 256, 0, stream>>>(Top, STc, c);
      GB s{}; s.A = Top + 524288; s.B = STc; s.Cb = Top + (size_t)(c + 1) * 524288;
      s.zp = zpad; s.M = 512; s.N = 1024;
      g2<5><<<dim3(8, 4, c), 256, 0, stream>>>(s);
    }
    // Top[63] = Top[31] * S^32, Top[64] = Top[32] * S^32
    k_transT<<<dim3(16, 16), 256, 0, stream>>>(Top, STc, 32);
    GB s{}; s.A = Top + (size_t)31 * 524288; s.B = STc;
    s.Cb = Top + (size_t)63 * 524288; s.zp = zpad; s.M = 512; s.N = 1024;
    g2<5><<<dim3(8, 4, 2), 256, 0, stream>>>(s);
  }

  // within-chunk solve: z = Tri(H) y, splitK over tau-blocks
  {
    GB g{}; g.A = ybf; g.B = Top; g.Cf = zparts; g.zp = zpad; g.M = 2048; g.N = 512;
    g2<2><<<dim3(4, 16, 8), 256, 0, stream>>>(g);
  }
  k_zreduce<<<dim3(4096), 256, 0, stream>>>(zparts, zf);

  // boundary chain: u_c precompute, 15 even steps, batched odd fill
  k_wm<<<dim3(256), 256, 0, stream>>>(zf, Wm);
  {
    GB g{}; g.A = Wm; g.B = Top; g.Cf = ubuf; g.zf = zf; g.zp = zpad;
    g.M = 64; g.N = 1024;
    g2<6><<<dim3(8, 1, 1), 256, 0, stream>>>(g);
  }
  hipMemsetAsync(bnd, 0, 8192, stream);
  hipMemsetAsync(Abnd, 0, 131072, stream);
  for (int k = 0; k < 15; ++k)
    k_bnd2<<<dim3(32), 256, 0, stream>>>(Top, ubuf, bnd, Abnd, k);
  {
    GB g{}; g.A = Abnd; g.B = Top; g.Cb = Abnd; g.zf = zf; g.zp = zpad;
    g.M = 32; g.N = 1024;
    g2<7><<<dim3(8, 1, 1), 256, 0, stream>>>(g);
  }

  // fixup: out = z + [H_{j+1}|G_j] @ Abnd
  {
    GB g{}; g.A = Abnd; g.B = Top; g.zf = zf; g.out = out; g.zp = zpad;
    g.M = 64; g.N = 16384;
    g2<3><<<dim3(128, 1, 1), 256, 0, stream>>>(g);
  }
}

// Round 6
// 769.109 us; speedup vs baseline: 1.1166x; 1.1166x over previous
//
#include <hip/hip_runtime.h>
#include <hip/hip_bf16.h>

// STU forward, R6: VGPR-staged double-buffered LDS (1 barrier/iter, prefetch
// next k-tile during MFMA), conflict-free linear ds_write_b128 staging.
// Sizes: B=2, L=1024, K=24(x2 branches), D=512, K_U=3, K_Y=2.

typedef unsigned short u16;
typedef __attribute__((ext_vector_type(8))) short  vshort8;
typedef __attribute__((ext_vector_type(4))) short  vshort4;
typedef __attribute__((ext_vector_type(4))) float  f32x4;
typedef __attribute__((ext_vector_type(4))) unsigned int vuint4;

__device__ __forceinline__ u16 f2b(float x) {
  __hip_bfloat16 h = __float2bfloat16(x);
  return __builtin_bit_cast(u16, h);
}
__device__ __forceinline__ float b2f(u16 x) {
  unsigned int u = ((unsigned int)x) << 16;
  return __builtin_bit_cast(float, u);
}

// ---------------------------------------------------------------------------
// Shared 128x128 MFMA GEMM template. C[m,n] = sum_k A[m,k]*Bmat[n,k].
//  V0 GEMM1: A=X(2048x512) B=W1(26112x512), grid (16 bm, 204 bn) -> A2T + Au
//  V1 CONV : A=Wtoep strip (d=bm-cj), B=A2T, grid (36 tri, 4 bn, 4 ch*cb)
//  V2 ZGEMM: A=gather(ybf), B=Top (H_tau blocks), splitK over tau -> zparts f32
//  V3 FIXUP: A=Abnd(64x1024), B=Top[j+1] rows -> out = acc + zf
//  V5 SGEMM: A=Top[*+bz] (512x1024), B=STc -> Top[*+bz] bf16 (batched)
//  V6 UGEMM: A=Wm(64x1024), B=S32 rows -> ubuf = acc + w_{c+1} (f32)
//  V7 ODD  : A=Abnd even rows, B=S32 rows -> Abnd odd rows = acc + w_{2k}
// ---------------------------------------------------------------------------
struct GB {
  const u16* A; const u16* B;
  float* Cf; u16* Cb;
  const float* zf; float* out;
  u16* A2T; u16* Au;
  int M, N;
};

template<int V>
__global__ __launch_bounds__(256) void g2(GB a) {
  const int tid = threadIdx.x;
  int bn = blockIdx.x, bm = blockIdx.y;
  const int bz = blockIdx.z;
  int cj = 0, cb = 0, cd = 0, slot = 0;
  int kbeg = 0, kend = 0;
  if (V == 0) { bm = blockIdx.x; bn = blockIdx.y; kend = 512; }
  if (V == 1) {
    int p = blockIdx.x;
    bm = (int)((sqrtf(8.f * (float)p + 1.f) - 1.f) * 0.5f);
    cj = p - (bm * (bm + 1)) / 2;
    bn = blockIdx.y;
    cb = bz & 1; cd = bm - cj;
    slot = bz * 8 + cj;
    kbeg = (bz >> 1) * 3072; kend = kbeg + 3072;
  }
  const int m0 = bm * 128, n0 = bn * 128;
  if (V == 2) {
    int jmax = (m0 >> 6) + 1;
    kbeg = bz * 2048;
    kend = kbeg + 2048;
    int tk = (jmax + 1) * 512;
    if (kend > tk) kend = tk;
    if (kend < kbeg) kend = kbeg;
  }
  if (V == 3 || V == 5 || V == 6 || V == 7) kend = 1024;

  __shared__ u16 lA[2][4096], lB[2][4096];
  f32x4 acc[4][4];
#pragma unroll
  for (int i = 0; i < 4; i++)
#pragma unroll
    for (int j = 0; j < 4; j++) acc[i][j] = f32x4{0.f, 0.f, 0.f, 0.f};

  const int lane = tid & 63, wv = tid >> 6, wr = wv >> 1, wc = wv & 1;
  const u16* Ap = a.A;
  if (V == 5) Ap = a.A + (size_t)bz * 524288;

  // per-lane staging addresses (R5 mapping -> linear LDS = frag-major image)
  auto gaddrA = [&](int it, int k0) -> const u16* {
    int lrow = (it * 4 + wv) * 16 + (lane & 15);
    int kk = k0 + ((lane >> 4) << 3);
    if (V == 0) return Ap + (size_t)(m0 + lrow) * 512 + kk;
    if (V == 1) return Ap + (size_t)cd * 786432 + (size_t)lrow * 6144 + kk;
    if (V == 2) {
      int m = m0 + lrow, j = m >> 6, b = (m >> 5) & 1, c = m & 31;
      int tau = kk >> 9, p = kk & 511;
      if (tau > j) return nullptr;
      return Ap + (size_t)(b * 1024 + c * 32 + j - tau) * 512 + p;
    }
    if (V == 3) { int m = m0 + lrow; return (m < a.M) ? Ap + (size_t)m * 1024 + kk : nullptr; }
    if (V == 5) return Ap + (size_t)(m0 + lrow) * 1024 + kk;
    if (V == 6) return (lrow < 64) ? Ap + (size_t)lrow * 1024 + kk : nullptr;
    // V7
    if (lrow < 32) {
      int b = lrow & 1, k2 = lrow >> 1;
      return Ap + (size_t)(b * 32 + 2 * k2) * 1024 + kk;
    }
    return nullptr;
  };
  auto gaddrB = [&](int it, int k0) -> const u16* {
    int lrow = (it * 4 + wv) * 16 + (lane & 15);
    int kk = k0 + ((lane >> 4) << 3);
    int n = n0 + lrow;
    if (V == 0) return a.B + (size_t)n * 512 + kk;
    if (V == 1) {
      int kh = kk >> 7, sp = kk & 127;
      return a.B + (size_t)(cb * 512 + n) * 49152 + kh * 1024 + cj * 128 + sp;
    }
    if (V == 2) {
      int tau = kk >> 9, p = kk & 511;
      return a.B + (size_t)tau * 524288 + (size_t)n * 1024 + p;
    }
    if (V == 3) {
      int jn = n >> 9, o = n & 511;
      return a.B + (size_t)(jn + 1) * 524288 + (size_t)o * 1024 + kk;
    }
    if (V == 5) return a.B + (size_t)n * 1024 + kk;
    // V6/V7: rows of S32 = [Top32 ; Top31]
    return (n < 512)
        ? a.B + (size_t)32 * 524288 + (size_t)n * 1024 + kk
        : a.B + (size_t)31 * 524288 + (size_t)(n - 512) * 1024 + kk;
  };

  vuint4 ra[2] = {vuint4{0,0,0,0}, vuint4{0,0,0,0}};
  vuint4 rb[2] = {vuint4{0,0,0,0}, vuint4{0,0,0,0}};
  auto loadtile = [&](int k0) {
#pragma unroll
    for (int it = 0; it < 2; ++it) {
      const u16* pa = gaddrA(it, k0);
      ra[it] = pa ? *(const vuint4*)pa : vuint4{0u, 0u, 0u, 0u};
      rb[it] = *(const vuint4*)gaddrB(it, k0);
    }
  };
  auto writetile = [&](int c) {
#pragma unroll
    for (int it = 0; it < 2; ++it) {
      *(vuint4*)&lA[c][it * 2048 + tid * 8] = ra[it];
      *(vuint4*)&lB[c][it * 2048 + tid * 8] = rb[it];
    }
  };

  if (kbeg < kend) loadtile(kbeg);
  writetile(0);
  __syncthreads();
  int cur = 0;
  for (int k0 = kbeg; k0 < kend; k0 += 32) {
    bool hasnext = (k0 + 32 < kend);
    if (hasnext) loadtile(k0 + 32);   // prefetch next tile into VGPRs
    vshort8 af[4], bf_[4];
#pragma unroll
    for (int s = 0; s < 4; s++) {
      af[s]  = *(const vshort8*)&lA[cur][(((wr * 4 + s) * 4 + (lane >> 4)) * 16 + (lane & 15)) * 8];
      bf_[s] = *(const vshort8*)&lB[cur][(((wc * 4 + s) * 4 + (lane >> 4)) * 16 + (lane & 15)) * 8];
    }
#pragma unroll
    for (int i = 0; i < 4; i++)
#pragma unroll
      for (int j = 0; j < 4; j++)
        acc[i][j] = __builtin_amdgcn_mfma_f32_16x16x32_bf16(af[i], bf_[j], acc[i][j], 0, 0, 0);
    if (hasnext) writetile(cur ^ 1);
    __syncthreads();
    cur ^= 1;
  }

  // epilogue
#pragma unroll
  for (int i = 0; i < 4; i++) {
    int em = m0 + wr * 64 + i * 16 + ((lane >> 4) << 2);
#pragma unroll
    for (int j = 0; j < 4; j++) {
      int n = n0 + wc * 64 + j * 16 + (lane & 15);
      f32x4 v = acc[i][j];
      if (V == 0) {
        int b = em >> 10, s = em & 1023;
        if (n < 24576) {
          int kh = n >> 9, o = n & 511;
          vshort4 pk = { (short)f2b(v[0]), (short)f2b(v[1]), (short)f2b(v[2]), (short)f2b(v[3]) };
          *(vshort4*)(&a.A2T[(size_t)(b * 512 + o) * 49152 + (size_t)kh * 1024 + s]) = pk;
        } else {
          int jj = (n - 24576) >> 9, o = n & 511;
#pragma unroll
          for (int t = 0; t < 4; t++)
            a.Au[((size_t)(b * 3 + jj) * 1024 + (s + t)) * 512 + o] = f2b(v[t]);
        }
      } else if (V == 1) {
        u16* C = a.Cb + (size_t)slot * 524288;
#pragma unroll
        for (int t = 0; t < 4; t++) C[(size_t)(em + t) * 512 + n] = f2b(v[t]);
      } else if (V == 2) {
        float* C = a.Cf + (size_t)bz * 1048576;
#pragma unroll
        for (int t = 0; t < 4; t++) C[(size_t)(em + t) * 512 + n] = v[t];
      } else if (V == 3) {
        int jj = n >> 9, oo = n & 511;
#pragma unroll
        for (int t = 0; t < 4; t++) {
          int m = em + t;
          if (m < a.M) {
            int b = m >> 5, c = m & 31;
            float zv = a.zf[(size_t)(jj * 64 + b * 32 + c) * 512 + oo];
            a.out[(size_t)b * 524288 + (size_t)(c * 32 + jj) * 512 + oo] = v[t] + zv;
          }
        }
      } else if (V == 5) {
        u16* C = a.Cb + (size_t)bz * 524288;
#pragma unroll
        for (int t = 0; t < 4; t++) C[(size_t)(em + t) * 1024 + n] = f2b(v[t]);
      } else if (V == 6) {
        int jrow = (n < 512) ? 31 : 30, oo = n & 511;
#pragma unroll
        for (int t = 0; t < 4; t++) {
          int m = em + t;
          if (m < 62) {
            int b = m & 1, c = m >> 1;
            a.Cf[(size_t)m * 1024 + n] =
                v[t] + a.zf[(size_t)(jrow * 64 + b * 32 + (c + 1)) * 512 + oo];
          }
        }
      } else { // V7: odd states
        int jrow = (n < 512) ? 31 : 30, oo = n & 511;
#pragma unroll
        for (int t = 0; t < 4; t++) {
          int m = em + t;
          if (m < 32) {
            int b = m & 1, k2 = m >> 1;
            float val = v[t] + a.zf[(size_t)(jrow * 64 + b * 32 + 2 * k2) * 512 + oo];
            a.Cb[(size_t)(b * 32 + 2 * k2 + 1) * 1024 + n] = f2b(val);
          }
        }
      }
    }
  }
}

// ---------------------------------------------------------------------------
// prep / glue kernels
// ---------------------------------------------------------------------------
__global__ void k_prep_X(const float* __restrict__ u, u16* __restrict__ X, int n) {
  int i = blockIdx.x * 256 + threadIdx.x;
  if (i < n) X[i] = f2b(u[i]);
}

__global__ void k_prep_phis(const float* __restrict__ phi, const float* __restrict__ sigma,
                            float* __restrict__ phis) {
  int i = blockIdx.x * 256 + threadIdx.x;
  if (i >= 1024 * 48) return;
  int tau = i / 48, kf = i % 48, k = (kf >= 24) ? kf - 24 : kf;
  float v = phi[tau * 24 + k] * powf(sigma[k], 0.25f);
  if (kf >= 24 && (tau & 1)) v = -v;
  phis[i] = v;
}

__global__ void k_prep_W1(const float* __restrict__ Mp, const float* __restrict__ Mm,
                          const float* __restrict__ Mu, u16* __restrict__ W1) {
  int i = blockIdx.x * 256 + threadIdx.x;
  if (i >= 13369344) return;
  float v;
  if (i < 6291456) v = Mp[i];
  else if (i < 12582912) v = Mm[i - 6291456];
  else v = Mu[i - 12582912];
  W1[i] = f2b(v);
}

// Wtoep[d][t'][kh*128+s'] = phis[(d*128+t'-s')*48 + kh] (0 if tau<0)
__global__ void k_prep_Wtoep(const float* __restrict__ phis, u16* __restrict__ W) {
  int i = blockIdx.x * 256 + threadIdx.x;
  if (i >= 6291456) return;
  int kap = i % 6144, row = i / 6144;
  int tp = row & 127, d = row >> 7;
  int kh = kap >> 7, sp = kap & 127;
  int tau = d * 128 + tp - sp;
  W[i] = (tau >= 0 && tau < 1024) ? f2b(phis[tau * 48 + kh]) : (u16)0;
}

// Top[0]=[I|0], Top[1]=[M1|M2]
__global__ void k_initTop(const float* __restrict__ my, u16* __restrict__ Top) {
  int i = blockIdx.x * 256 + threadIdx.x;
  if (i >= 1048576) return;
  int mat = i >> 19, rem = i & 524287, o = rem >> 10, k = rem & 1023;
  u16 v;
  if (mat == 0) v = (k == o) ? (u16)0x3F80 : (u16)0;
  else v = (k < 512) ? f2b(my[o * 512 + k]) : f2b(my[262144 + o * 512 + (k - 512)]);
  Top[i] = v;
}

// STc[n][k] = S^c[k][n];  S^c = [Top[c]; Top[c-1]]  (tiled transpose)
__global__ __launch_bounds__(256) void k_transT(const u16* __restrict__ Top,
                                                u16* __restrict__ STc, int c) {
  __shared__ u16 tile[64][72];
  int tx = blockIdx.x, ty = blockIdx.y;  // n-tile, k-tile
  int tid = threadIdx.x;
  int r = tid >> 2, seg = tid & 3;
  int k = ty * 64 + r;
  const u16* src = (k < 512) ? Top + (size_t)c * 524288 + (size_t)k * 1024 + tx * 64
                             : Top + (size_t)(c - 1) * 524288 + (size_t)(k - 512) * 1024 + tx * 64;
  *(vuint4*)&tile[r][seg * 16]     = *(const vuint4*)(src + seg * 16);
  *(vuint4*)&tile[r][seg * 16 + 8] = *(const vuint4*)(src + seg * 16 + 8);
  __syncthreads();
  int n = tx * 64 + r;
  u16 tmp[16];
#pragma unroll
  for (int j = 0; j < 16; j++) tmp[j] = tile[seg * 16 + j][r];
  *(vuint4*)&STc[(size_t)n * 1024 + ty * 64 + seg * 16]     = *(vuint4*)&tmp[0];
  *(vuint4*)&STc[(size_t)n * 1024 + ty * 64 + seg * 16 + 8] = *(vuint4*)&tmp[8];
}

__device__ __forceinline__ void addp(float* acc, vuint4 v) {
  const unsigned int* vu = (const unsigned int*)&v;
#pragma unroll
  for (int e = 0; e < 4; ++e) {
    unsigned int pw = vu[e];
    acc[2 * e]     += __builtin_bit_cast(float, (pw & 0xffffu) << 16);
    acc[2 * e + 1] += __builtin_bit_cast(float, pw & 0xffff0000u);
  }
}

// ybf[b,t,og*8..] = sum_j Au[b,j,t-j,:] + (t>=2 ? valid bf16 conv partials : 0)
// conv slots: slot = g*8 + j (g = ch*2+cb in [0,4), j = s-block), pick g&1==b
__global__ void k_combine(const u16* __restrict__ parts, const u16* __restrict__ Au,
                          u16* __restrict__ ybf) {
  int i = blockIdx.x * 256 + threadIdx.x;
  if (i >= 131072) return;
  int og = i & 63, t = (i >> 6) & 1023, b = i >> 16;
  float acc[8];
#pragma unroll
  for (int e = 0; e < 8; ++e) acc[e] = 0.f;
#pragma unroll
  for (int j = 0; j < 3; j++)
    if (t >= j)
      addp(acc, *(const vuint4*)(Au + ((size_t)(b * 3 + j) * 1024 + (t - j)) * 512 + og * 8));
  if (t >= 2) {
    int tp = t - 2, bmv = tp >> 7;
#pragma unroll
    for (int g = 0; g < 4; ++g) {
      if ((g & 1) != b) continue;
      const u16* base = parts + (size_t)(g * 8) * 524288 + (size_t)tp * 512 + og * 8;
      for (int j = 0; j <= bmv; ++j)
        addp(acc, *(const vuint4*)(base + (size_t)j * 524288));
    }
  }
  u16 o16[8];
#pragma unroll
  for (int e = 0; e < 8; ++e) o16[e] = f2b(acc[e]);
  *(vuint4*)(ybf + ((size_t)(b * 1024 + t)) * 512 + og * 8) = *(vuint4*)o16;
}

__global__ void k_zreduce(const float* __restrict__ zp, float* __restrict__ z) {
  int i = blockIdx.x * 256 + threadIdx.x;
  if (i >= 1048576) return;
  float s = 0.f;
#pragma unroll
  for (int j = 0; j < 8; j++) s += zp[(size_t)j * 1048576 + i];
  z[i] = s;
}

// Wm[(c<<1)|b][n] = bf16(w_c(b)[n]) from zf rows 31 (n<512) / 30 (n>=512)
__global__ void k_wm(const float* __restrict__ zf, u16* __restrict__ Wm) {
  int i = blockIdx.x * 256 + threadIdx.x;
  if (i >= 65536) return;
  int row = i >> 10, n = i & 1023;
  int b = row & 1, c = row >> 1;
  int jrow = (n < 512) ? 31 : 30, oo = n & 511;
  Wm[i] = f2b(zf[(size_t)(jrow * 64 + b * 32 + c) * 512 + oo]);
}

// even chain step k: E_{k+1} = S64 E_k + u_{2k}; emit Abnd row (b*32+2k+2)
__global__ __launch_bounds__(256) void k_bnd2(const u16* __restrict__ Top,
                                              const float* __restrict__ ubuf,
                                              float* __restrict__ bnd,
                                              u16* __restrict__ Abnd, int k) {
  __shared__ float st[2048];
  int tid = threadIdx.x;
  const float* s0 = bnd + (size_t)k * 2048;
  for (int j = tid; j < 2048; j += 256) st[j] = s0[j];
  __syncthreads();
  int q4 = blockIdx.x * 256 + tid;  // [0,8192)
  int q = q4 >> 2, quarter = q4 & 3;
  int b = q >> 10, kk = q & 1023;
  const u16* row = (kk < 512) ? Top + (size_t)64 * 524288 + (size_t)kk * 1024
                              : Top + (size_t)63 * 524288 + (size_t)(kk - 512) * 1024;
  const float* stb = st + b * 1024 + quarter * 256;
  const u16* rp = row + quarter * 256;
  float sum = 0.f;
  for (int t = 0; t < 32; ++t) {
    vuint4 v = *(const vuint4*)(rp + t * 8);
    const unsigned int* vu = (const unsigned int*)&v;
#pragma unroll
    for (int e = 0; e < 4; ++e) {
      unsigned int pw = vu[e];
      float lo = __builtin_bit_cast(float, (pw & 0xffffu) << 16);
      float hi = __builtin_bit_cast(float, pw & 0xffff0000u);
      sum += lo * stb[t * 8 + e * 2] + hi * stb[t * 8 + e * 2 + 1];
    }
  }
  sum += __shfl_xor(sum, 1);
  sum += __shfl_xor(sum, 2);
  if (quarter == 0) {
    float s = sum + ubuf[(size_t)(4 * k + b) * 1024 + kk];
    bnd[(size_t)(k + 1) * 2048 + b * 1024 + kk] = s;
    Abnd[(size_t)(b * 32 + 2 * k + 2) * 1024 + kk] = f2b(s);
  }
}

// ---------------------------------------------------------------------------
extern "C" void kernel_launch(void* const* d_in, const int* in_sizes, int n_in,
                              void* d_out, int out_size, void* d_ws, size_t ws_size,
                              hipStream_t stream) {
  const float* u     = (const float*)d_in[0];
  const float* Mu    = (const float*)d_in[1];
  const float* Mp    = (const float*)d_in[2];
  const float* Mm    = (const float*)d_in[3];
  const float* my    = (const float*)d_in[4];
  const float* sigma = (const float*)d_in[5];
  const float* phi   = (const float*)d_in[6];
  float* out = (float*)d_out;

  char* ws = (char*)d_ws;
  size_t off = 0;
  auto alc = [&](size_t b) { size_t p = off; off = (off + b + 255) & ~(size_t)255; return p; };
  u16*  X     = (u16*)(ws + alc(2097152));
  u16*  Wtoep = (u16*)(ws + alc(12582912));    // 8 d x 128 x 6144
  u16*  A2T   = (u16*)(ws + alc(100663296));   // (b,o)[48 kh][1024 s]
  u16*  Au    = (u16*)(ws + alc(6291456));
  u16*  W1    = (u16*)(ws + alc(26738688));    // 26112x512; parts region spans W1+tail
  char* ptail = ws + alc(40370176); (void)ptail; // W1+tail = 64 MiB exactly
  float* phis = (float*)(ws + alc(196608));
  float* bnd  = (float*)(ws + alc(131072));    // 16 even states x 2048 f32
  u16*  Abnd  = (u16*)(ws + alc(131072));      // 64 x 1024 bf16 boundary states
  u16*  Wm    = (u16*)(ws + alc(131072));      // 64 x 1024 bf16 w_c
  float* ubuf = (float*)(ws + alc(262144));    // 64 x 1024 f32 u_c
  if (off > ws_size) return;
  // lifetime-disjoint aliases:
  u16*  partsBf = (u16*)W1;                    // 32 conv slots x [1024][512] bf16
  float* zparts = (float*)W1;                  // 8 zgemm slots x 4 MiB f32
  u16*  ybf = A2T;                             // 2 MiB (after conv)
  float* zf = (float*)((char*)A2T + (4 << 20));
  u16*  Top = (u16*)((char*)A2T + (size_t)(8 << 20));   // 65 x 1 MiB
  u16*  STc = (u16*)((char*)A2T + (size_t)(76 << 20));  // 2 MiB scratch

  // prep
  k_prep_X<<<dim3(4096), 256, 0, stream>>>(u, X, 1048576);
  k_prep_phis<<<dim3(192), 256, 0, stream>>>(phi, sigma, phis);
  k_prep_W1<<<dim3(52224), 256, 0, stream>>>(Mp, Mm, Mu, W1);
  k_prep_Wtoep<<<dim3(24576), 256, 0, stream>>>(phis, Wtoep);

  // GEMM1: projections (spectral plus/minus + ar_u)
  {
    GB g{}; g.A = X; g.B = W1; g.A2T = A2T; g.Au = Au;
    g.M = 2048; g.N = 26112;
    g2<0><<<dim3(16, 204, 1), 256, 0, stream>>>(g);
  }
  // CONV: triangular all-active grid, splitK=2 x batch=2
  {
    GB g{}; g.A = Wtoep; g.B = A2T; g.Cb = partsBf;
    g.M = 1024; g.N = 512;
    g2<1><<<dim3(36, 4, 4), 256, 0, stream>>>(g);
  }
  k_combine<<<dim3(512), 256, 0, stream>>>(partsBf, Au, ybf);

  // companion-power stack Top[0..32], then Top[63],Top[64] (= S32^2 halves)
  k_initTop<<<dim3(4096), 256, 0, stream>>>(my, Top);
  {
    const int cs[5] = {1, 2, 4, 8, 16};
    for (int li = 0; li < 5; ++li) {
      int c = cs[li];
      k_transT<<<dim3(16, 16), 256, 0, stream>>>(Top, STc, c);
      GB s{}; s.A = Top + 524288; s.B = STc; s.Cb = Top + (size_t)(c + 1) * 524288;
      s.M = 512; s.N = 1024;
      g2<5><<<dim3(8, 4, c), 256, 0, stream>>>(s);
    }
    // Top[63] = Top[31] * S^32, Top[64] = Top[32] * S^32
    k_transT<<<dim3(16, 16), 256, 0, stream>>>(Top, STc, 32);
    GB s{}; s.A = Top + (size_t)31 * 524288; s.B = STc;
    s.Cb = Top + (size_t)63 * 524288; s.M = 512; s.N = 1024;
    g2<5><<<dim3(8, 4, 2), 256, 0, stream>>>(s);
  }

  // within-chunk solve: z = Tri(H) y, splitK over tau-blocks
  {
    GB g{}; g.A = ybf; g.B = Top; g.Cf = zparts; g.M = 2048; g.N = 512;
    g2<2><<<dim3(4, 16, 8), 256, 0, stream>>>(g);
  }
  k_zreduce<<<dim3(4096), 256, 0, stream>>>(zparts, zf);

  // boundary chain: u_c precompute, 15 even steps, batched odd fill
  k_wm<<<dim3(256), 256, 0, stream>>>(zf, Wm);
  {
    GB g{}; g.A = Wm; g.B = Top; g.Cf = ubuf; g.zf = zf;
    g.M = 64; g.N = 1024;
    g2<6><<<dim3(8, 1, 1), 256, 0, stream>>>(g);
  }
  hipMemsetAsync(bnd, 0, 8192, stream);
  hipMemsetAsync(Abnd, 0, 131072, stream);
  for (int k = 0; k < 15; ++k)
    k_bnd2<<<dim3(32), 256, 0, stream>>>(Top, ubuf, bnd, Abnd, k);
  {
    GB g{}; g.A = Abnd; g.B = Top; g.Cb = Abnd; g.zf = zf;
    g.M = 32; g.N = 1024;
    g2<7><<<dim3(8, 1, 1), 256, 0, stream>>>(g);
  }

  // fixup: out = z + [H_{j+1}|G_j] @ Abnd
  {
    GB g{}; g.A = Abnd; g.B = Top; g.zf = zf; g.out = out;
    g.M = 64; g.N = 16384;
    g2<3><<<dim3(128, 1, 1), 256, 0, stream>>>(g);
  }
}

// Round 7
// 766.796 us; speedup vs baseline: 1.1200x; 1.0030x over previous
//
#include <hip/hip_runtime.h>
#include <hip/hip_bf16.h>

// STU forward, R7: on-the-fly Toeplitz A-build from LDS phi-band (kills 432MB
// A-fetch), locality-ordered 1-D grids + bijective XCD-chunk swizzle for
// GEMM1/CONV/ZGEMM. Sizes: B=2, L=1024, K=24(x2), D=512, K_U=3, K_Y=2.

typedef unsigned short u16;
typedef __attribute__((ext_vector_type(8))) short  vshort8;
typedef __attribute__((ext_vector_type(4))) short  vshort4;
typedef __attribute__((ext_vector_type(4))) float  f32x4;
typedef __attribute__((ext_vector_type(4))) unsigned int vuint4;

__device__ __forceinline__ u16 f2b(float x) {
  __hip_bfloat16 h = __float2bfloat16(x);
  return __builtin_bit_cast(u16, h);
}
__device__ __forceinline__ float b2f(u16 x) {
  unsigned int u = ((unsigned int)x) << 16;
  return __builtin_bit_cast(float, u);
}

// ---------------------------------------------------------------------------
// Shared 128x128 MFMA GEMM template. C[m,n] = sum_k A[m,k]*Bmat[n,k].
//  V0 GEMM1: A=X(2048x512) B=W1(26112x512); 1-D grid 3264, XCD-chunked
//  V1 CONV : A=Toeplitz(phi band, built in-block), B=A2T; 1-D grid 576
//  V2 ZGEMM: A=gather(ybf), B=Top; 1-D grid 512, XCD-chunked
//  V3 FIXUP: A=Abnd(64x1024), B=Top[j+1] rows -> out = acc + zf
//  V5 SGEMM: A=Top[*+bz] (512x1024), B=STc -> Top[*+bz] bf16 (batched)
//  V6 UGEMM: A=Wm(64x1024), B=S32 rows -> ubuf = acc + w_{c+1} (f32)
//  V7 ODD  : A=Abnd even rows, B=S32 rows -> Abnd odd rows = acc + w_{2k}
// ---------------------------------------------------------------------------
struct GB {
  const u16* A; const u16* B;
  float* Cf; u16* Cb;
  const float* zf; float* out;
  u16* A2T; u16* Au;
  const float* phisT;
  int M, N;
};

template<int V>
__global__ __launch_bounds__(256) void g2(GB a) {
  const int tid = threadIdx.x;
  int bn = blockIdx.x, bm = blockIdx.y;
  int zz = blockIdx.z;
  int cj = 0, cb = 0, cd = 0, slot = 0;
  int kbeg = 0, kend = 0;
  if (V == 0) {
    int f = blockIdx.x;
    int o = (f & 7) * 408 + (f >> 3);
    bm = o & 15; bn = o >> 4; kend = 512;
  }
  if (V == 1) {
    int f = blockIdx.x;
    int o = (f & 7) * 72 + (f >> 3);           // XCD-chunk swizzle (576=8x72)
    const int off1 = 128, off2 = 240, off3 = 336, off4 = 416,
              off5 = 480, off6 = 528, off7 = 560;
    cj = 0;
    if (o >= off1) cj = 1; if (o >= off2) cj = 2; if (o >= off3) cj = 3;
    if (o >= off4) cj = 4; if (o >= off5) cj = 5; if (o >= off6) cj = 6;
    if (o >= off7) cj = 7;
    const int offs[8] = {0, off1, off2, off3, off4, off5, off6, off7};
    int r = o - offs[cj];
    int run = 8 - cj;
    int combo = r / run;
    bm = cj + (r - combo * run);
    zz = combo >> 2; bn = combo & 3;
    cb = zz & 1; cd = bm - cj;
    slot = zz * 8 + cj;
    kbeg = (zz >> 1) * 3072; kend = kbeg + 3072;
  }
  if (V == 2) {
    int f = blockIdx.x;
    int o = (f & 7) * 64 + (f >> 3);           // 512 = 8x64
    bm = o & 15; bn = (o >> 4) & 3; zz = o >> 6;
  }
  const int m0 = bm * 128, n0 = bn * 128;
  if (V == 2) {
    int jmax = (m0 >> 6) + 1;
    kbeg = zz * 2048;
    kend = kbeg + 2048;
    int tk = (jmax + 1) * 512;
    if (kend > tk) kend = tk;
    if (kend < kbeg) kend = kbeg;
  }
  if (V == 3 || V == 5 || V == 6 || V == 7) kend = 1024;

  __shared__ u16 lA[2][4096], lB[2][4096];
  __shared__ u16 band[V == 1 ? 12288 : 8];     // [48 kh][256 taurel]
  f32x4 acc[4][4];
#pragma unroll
  for (int i = 0; i < 4; i++)
#pragma unroll
    for (int j = 0; j < 4; j++) acc[i][j] = f32x4{0.f, 0.f, 0.f, 0.f};

  const int lane = tid & 63, wv = tid >> 6, wr = wv >> 1, wc = wv & 1;
  const u16* Ap = a.A;
  if (V == 5) Ap = a.A + (size_t)zz * 524288;

  if (V == 1) {
    // stage phi band: band[kh*256+row] = phi_s[d*128+row-128][kh] (0 if tau<0)
    for (int i = tid; i < 12288; i += 256) {
      int kh = i >> 8, row = i & 255;
      int tau = cd * 128 + row - 128;
      band[i] = (tau >= 0) ? f2b(a.phisT[kh * 1024 + tau]) : (u16)0;
    }
    __syncthreads();
  }

  auto gaddrA = [&](int it, int k0) -> const u16* {
    int lrow = (it * 4 + wv) * 16 + (lane & 15);
    int kk = k0 + ((lane >> 4) << 3);
    if (V == 0) return Ap + (size_t)(m0 + lrow) * 512 + kk;
    if (V == 2) {
      int m = m0 + lrow, j = m >> 6, b = (m >> 5) & 1, c = m & 31;
      int tau = kk >> 9, p = kk & 511;
      if (tau > j) return nullptr;
      return Ap + (size_t)(b * 1024 + c * 32 + j - tau) * 512 + p;
    }
    if (V == 3) { int m = m0 + lrow; return (m < a.M) ? Ap + (size_t)m * 1024 + kk : nullptr; }
    if (V == 5) return Ap + (size_t)(m0 + lrow) * 1024 + kk;
    if (V == 6) return (lrow < 64) ? Ap + (size_t)lrow * 1024 + kk : nullptr;
    // V7
    if (lrow < 32) {
      int b = lrow & 1, k2 = lrow >> 1;
      return Ap + (size_t)(b * 32 + 2 * k2) * 1024 + kk;
    }
    return nullptr;
  };
  auto gaddrB = [&](int it, int k0) -> const u16* {
    int lrow = (it * 4 + wv) * 16 + (lane & 15);
    int kk = k0 + ((lane >> 4) << 3);
    int n = n0 + lrow;
    if (V == 0) return a.B + (size_t)n * 512 + kk;
    if (V == 1) {
      int kh = kk >> 7, sp = kk & 127;
      return a.B + (size_t)(cb * 512 + n) * 49152 + kh * 1024 + cj * 128 + sp;
    }
    if (V == 2) {
      int tau = kk >> 9, p = kk & 511;
      return a.B + (size_t)tau * 524288 + (size_t)n * 1024 + p;
    }
    if (V == 3) {
      int jn = n >> 9, o = n & 511;
      return a.B + (size_t)(jn + 1) * 524288 + (size_t)o * 1024 + kk;
    }
    if (V == 5) return a.B + (size_t)n * 1024 + kk;
    // V6/V7: rows of S32 = [Top32 ; Top31]
    return (n < 512)
        ? a.B + (size_t)32 * 524288 + (size_t)n * 1024 + kk
        : a.B + (size_t)31 * 524288 + (size_t)(n - 512) * 1024 + kk;
  };

  vuint4 ra[2] = {vuint4{0,0,0,0}, vuint4{0,0,0,0}};
  vuint4 rb[2] = {vuint4{0,0,0,0}, vuint4{0,0,0,0}};
  auto loadtile = [&](int k0) {
#pragma unroll
    for (int it = 0; it < 2; ++it) {
      if (V == 1) {
        // build Toeplitz A chunk from band: elem e = band[kh][lrow-s0-e+128]
        int lrow = (it * 4 + wv) * 16 + (lane & 15);
        int kk = k0 + ((lane >> 4) << 3);
        int kh = kk >> 7, s0 = kk & 127;
        int tr0 = kh * 256 + (lrow - s0 + 128);
        unsigned int w32[4];
#pragma unroll
        for (int e2 = 0; e2 < 4; ++e2) {
          unsigned int lo = band[tr0 - 2 * e2];
          unsigned int hi = band[tr0 - 2 * e2 - 1];
          w32[e2] = lo | (hi << 16);
        }
        ra[it] = vuint4{w32[0], w32[1], w32[2], w32[3]};
      } else {
        const u16* pa = gaddrA(it, k0);
        ra[it] = pa ? *(const vuint4*)pa : vuint4{0u, 0u, 0u, 0u};
      }
      rb[it] = *(const vuint4*)gaddrB(it, k0);
    }
  };
  auto writetile = [&](int c) {
#pragma unroll
    for (int it = 0; it < 2; ++it) {
      *(vuint4*)&lA[c][it * 2048 + tid * 8] = ra[it];
      *(vuint4*)&lB[c][it * 2048 + tid * 8] = rb[it];
    }
  };

  if (kbeg < kend) loadtile(kbeg);
  writetile(0);
  __syncthreads();
  int cur = 0;
  for (int k0 = kbeg; k0 < kend; k0 += 32) {
    bool hasnext = (k0 + 32 < kend);
    if (hasnext) loadtile(k0 + 32);   // prefetch next tile into VGPRs
    vshort8 af[4], bf_[4];
#pragma unroll
    for (int s = 0; s < 4; s++) {
      af[s]  = *(const vshort8*)&lA[cur][(((wr * 4 + s) * 4 + (lane >> 4)) * 16 + (lane & 15)) * 8];
      bf_[s] = *(const vshort8*)&lB[cur][(((wc * 4 + s) * 4 + (lane >> 4)) * 16 + (lane & 15)) * 8];
    }
#pragma unroll
    for (int i = 0; i < 4; i++)
#pragma unroll
      for (int j = 0; j < 4; j++)
        acc[i][j] = __builtin_amdgcn_mfma_f32_16x16x32_bf16(af[i], bf_[j], acc[i][j], 0, 0, 0);
    if (hasnext) writetile(cur ^ 1);
    __syncthreads();
    cur ^= 1;
  }

  // epilogue
#pragma unroll
  for (int i = 0; i < 4; i++) {
    int em = m0 + wr * 64 + i * 16 + ((lane >> 4) << 2);
#pragma unroll
    for (int j = 0; j < 4; j++) {
      int n = n0 + wc * 64 + j * 16 + (lane & 15);
      f32x4 v = acc[i][j];
      if (V == 0) {
        int b = em >> 10, s = em & 1023;
        if (n < 24576) {
          int kh = n >> 9, o = n & 511;
          vshort4 pk = { (short)f2b(v[0]), (short)f2b(v[1]), (short)f2b(v[2]), (short)f2b(v[3]) };
          *(vshort4*)(&a.A2T[(size_t)(b * 512 + o) * 49152 + (size_t)kh * 1024 + s]) = pk;
        } else {
          int jj = (n - 24576) >> 9, o = n & 511;
#pragma unroll
          for (int t = 0; t < 4; t++)
            a.Au[((size_t)(b * 3 + jj) * 1024 + (s + t)) * 512 + o] = f2b(v[t]);
        }
      } else if (V == 1) {
        u16* C = a.Cb + (size_t)slot * 524288;
#pragma unroll
        for (int t = 0; t < 4; t++) C[(size_t)(em + t) * 512 + n] = f2b(v[t]);
      } else if (V == 2) {
        float* C = a.Cf + (size_t)zz * 1048576;
#pragma unroll
        for (int t = 0; t < 4; t++) C[(size_t)(em + t) * 512 + n] = v[t];
      } else if (V == 3) {
        int jj = n >> 9, oo = n & 511;
#pragma unroll
        for (int t = 0; t < 4; t++) {
          int m = em + t;
          if (m < a.M) {
            int b = m >> 5, c = m & 31;
            float zv = a.zf[(size_t)(jj * 64 + b * 32 + c) * 512 + oo];
            a.out[(size_t)b * 524288 + (size_t)(c * 32 + jj) * 512 + oo] = v[t] + zv;
          }
        }
      } else if (V == 5) {
        u16* C = a.Cb + (size_t)zz * 524288;
#pragma unroll
        for (int t = 0; t < 4; t++) C[(size_t)(em + t) * 1024 + n] = f2b(v[t]);
      } else if (V == 6) {
        int jrow = (n < 512) ? 31 : 30, oo = n & 511;
#pragma unroll
        for (int t = 0; t < 4; t++) {
          int m = em + t;
          if (m < 62) {
            int b = m & 1, c = m >> 1;
            a.Cf[(size_t)m * 1024 + n] =
                v[t] + a.zf[(size_t)(jrow * 64 + b * 32 + (c + 1)) * 512 + oo];
          }
        }
      } else { // V7: odd states
        int jrow = (n < 512) ? 31 : 30, oo = n & 511;
#pragma unroll
        for (int t = 0; t < 4; t++) {
          int m = em + t;
          if (m < 32) {
            int b = m & 1, k2 = m >> 1;
            float val = v[t] + a.zf[(size_t)(jrow * 64 + b * 32 + 2 * k2) * 512 + oo];
            a.Cb[(size_t)(b * 32 + 2 * k2 + 1) * 1024 + n] = f2b(val);
          }
        }
      }
    }
  }
}

// ---------------------------------------------------------------------------
// prep / glue kernels
// ---------------------------------------------------------------------------
__global__ void k_prep_X(const float* __restrict__ u, u16* __restrict__ X, int n) {
  int i = blockIdx.x * 256 + threadIdx.x;
  if (i < n) X[i] = f2b(u[i]);
}

// phisT[kf*1024 + tau]: kf<24 -> phi_s[tau,kf]; kf>=24 -> phi_s[tau,kf-24]*(-1)^tau
__global__ void k_prep_phis(const float* __restrict__ phi, const float* __restrict__ sigma,
                            float* __restrict__ phisT) {
  int i = blockIdx.x * 256 + threadIdx.x;
  if (i >= 1024 * 48) return;
  int tau = i / 48, kf = i % 48, k = (kf >= 24) ? kf - 24 : kf;
  float v = phi[tau * 24 + k] * powf(sigma[k], 0.25f);
  if (kf >= 24 && (tau & 1)) v = -v;
  phisT[kf * 1024 + tau] = v;
}

__global__ void k_prep_W1(const float* __restrict__ Mp, const float* __restrict__ Mm,
                          const float* __restrict__ Mu, u16* __restrict__ W1) {
  int i = blockIdx.x * 256 + threadIdx.x;
  if (i >= 13369344) return;
  float v;
  if (i < 6291456) v = Mp[i];
  else if (i < 12582912) v = Mm[i - 6291456];
  else v = Mu[i - 12582912];
  W1[i] = f2b(v);
}

// Top[0]=[I|0], Top[1]=[M1|M2]
__global__ void k_initTop(const float* __restrict__ my, u16* __restrict__ Top) {
  int i = blockIdx.x * 256 + threadIdx.x;
  if (i >= 1048576) return;
  int mat = i >> 19, rem = i & 524287, o = rem >> 10, k = rem & 1023;
  u16 v;
  if (mat == 0) v = (k == o) ? (u16)0x3F80 : (u16)0;
  else v = (k < 512) ? f2b(my[o * 512 + k]) : f2b(my[262144 + o * 512 + (k - 512)]);
  Top[i] = v;
}

// STc[n][k] = S^c[k][n];  S^c = [Top[c]; Top[c-1]]  (tiled transpose)
__global__ __launch_bounds__(256) void k_transT(const u16* __restrict__ Top,
                                                u16* __restrict__ STc, int c) {
  __shared__ u16 tile[64][72];
  int tx = blockIdx.x, ty = blockIdx.y;  // n-tile, k-tile
  int tid = threadIdx.x;
  int r = tid >> 2, seg = tid & 3;
  int k = ty * 64 + r;
  const u16* src = (k < 512) ? Top + (size_t)c * 524288 + (size_t)k * 1024 + tx * 64
                             : Top + (size_t)(c - 1) * 524288 + (size_t)(k - 512) * 1024 + tx * 64;
  *(vuint4*)&tile[r][seg * 16]     = *(const vuint4*)(src + seg * 16);
  *(vuint4*)&tile[r][seg * 16 + 8] = *(const vuint4*)(src + seg * 16 + 8);
  __syncthreads();
  int n = tx * 64 + r;
  u16 tmp[16];
#pragma unroll
  for (int j = 0; j < 16; j++) tmp[j] = tile[seg * 16 + j][r];
  *(vuint4*)&STc[(size_t)n * 1024 + ty * 64 + seg * 16]     = *(vuint4*)&tmp[0];
  *(vuint4*)&STc[(size_t)n * 1024 + ty * 64 + seg * 16 + 8] = *(vuint4*)&tmp[8];
}

__device__ __forceinline__ void addp(float* acc, vuint4 v) {
  const unsigned int* vu = (const unsigned int*)&v;
#pragma unroll
  for (int e = 0; e < 4; ++e) {
    unsigned int pw = vu[e];
    acc[2 * e]     += __builtin_bit_cast(float, (pw & 0xffffu) << 16);
    acc[2 * e + 1] += __builtin_bit_cast(float, pw & 0xffff0000u);
  }
}

// ybf[b,t,og*8..] = sum_j Au[b,j,t-j,:] + (t>=2 ? valid bf16 conv partials : 0)
// conv slots: slot = g*8 + j (g = ch*2+cb in [0,4), j = s-block), pick g&1==b
__global__ void k_combine(const u16* __restrict__ parts, const u16* __restrict__ Au,
                          u16* __restrict__ ybf) {
  int i = blockIdx.x * 256 + threadIdx.x;
  if (i >= 131072) return;
  int og = i & 63, t = (i >> 6) & 1023, b = i >> 16;
  float acc[8];
#pragma unroll
  for (int e = 0; e < 8; ++e) acc[e] = 0.f;
#pragma unroll
  for (int j = 0; j < 3; j++)
    if (t >= j)
      addp(acc, *(const vuint4*)(Au + ((size_t)(b * 3 + j) * 1024 + (t - j)) * 512 + og * 8));
  if (t >= 2) {
    int tp = t - 2, bmv = tp >> 7;
#pragma unroll
    for (int g = 0; g < 4; ++g) {
      if ((g & 1) != b) continue;
      const u16* base = parts + (size_t)(g * 8) * 524288 + (size_t)tp * 512 + og * 8;
      for (int j = 0; j <= bmv; ++j)
        addp(acc, *(const vuint4*)(base + (size_t)j * 524288));
    }
  }
  u16 o16[8];
#pragma unroll
  for (int e = 0; e < 8; ++e) o16[e] = f2b(acc[e]);
  *(vuint4*)(ybf + ((size_t)(b * 1024 + t)) * 512 + og * 8) = *(vuint4*)o16;
}

__global__ void k_zreduce(const float* __restrict__ zp, float* __restrict__ z) {
  int i = blockIdx.x * 256 + threadIdx.x;
  if (i >= 1048576) return;
  float s = 0.f;
#pragma unroll
  for (int j = 0; j < 8; j++) s += zp[(size_t)j * 1048576 + i];
  z[i] = s;
}

// Wm[(c<<1)|b][n] = bf16(w_c(b)[n]) from zf rows 31 (n<512) / 30 (n>=512)
__global__ void k_wm(const float* __restrict__ zf, u16* __restrict__ Wm) {
  int i = blockIdx.x * 256 + threadIdx.x;
  if (i >= 65536) return;
  int row = i >> 10, n = i & 1023;
  int b = row & 1, c = row >> 1;
  int jrow = (n < 512) ? 31 : 30, oo = n & 511;
  Wm[i] = f2b(zf[(size_t)(jrow * 64 + b * 32 + c) * 512 + oo]);
}

// even chain step k: E_{k+1} = S64 E_k + u_{2k}; emit Abnd row (b*32+2k+2)
__global__ __launch_bounds__(256) void k_bnd2(const u16* __restrict__ Top,
                                              const float* __restrict__ ubuf,
                                              float* __restrict__ bnd,
                                              u16* __restrict__ Abnd, int k) {
  __shared__ float st[2048];
  int tid = threadIdx.x;
  const float* s0 = bnd + (size_t)k * 2048;
  for (int j = tid; j < 2048; j += 256) st[j] = s0[j];
  __syncthreads();
  int q4 = blockIdx.x * 256 + tid;  // [0,8192)
  int q = q4 >> 2, quarter = q4 & 3;
  int b = q >> 10, kk = q & 1023;
  const u16* row = (kk < 512) ? Top + (size_t)64 * 524288 + (size_t)kk * 1024
                              : Top + (size_t)63 * 524288 + (size_t)(kk - 512) * 1024;
  const float* stb = st + b * 1024 + quarter * 256;
  const u16* rp = row + quarter * 256;
  float sum = 0.f;
  for (int t = 0; t < 32; ++t) {
    vuint4 v = *(const vuint4*)(rp + t * 8);
    const unsigned int* vu = (const unsigned int*)&v;
#pragma unroll
    for (int e = 0; e < 4; ++e) {
      unsigned int pw = vu[e];
      float lo = __builtin_bit_cast(float, (pw & 0xffffu) << 16);
      float hi = __builtin_bit_cast(float, pw & 0xffff0000u);
      sum += lo * stb[t * 8 + e * 2] + hi * stb[t * 8 + e * 2 + 1];
    }
  }
  sum += __shfl_xor(sum, 1);
  sum += __shfl_xor(sum, 2);
  if (quarter == 0) {
    float s = sum + ubuf[(size_t)(4 * k + b) * 1024 + kk];
    bnd[(size_t)(k + 1) * 2048 + b * 1024 + kk] = s;
    Abnd[(size_t)(b * 32 + 2 * k + 2) * 1024 + kk] = f2b(s);
  }
}

// ---------------------------------------------------------------------------
extern "C" void kernel_launch(void* const* d_in, const int* in_sizes, int n_in,
                              void* d_out, int out_size, void* d_ws, size_t ws_size,
                              hipStream_t stream) {
  const float* u     = (const float*)d_in[0];
  const float* Mu    = (const float*)d_in[1];
  const float* Mp    = (const float*)d_in[2];
  const float* Mm    = (const float*)d_in[3];
  const float* my    = (const float*)d_in[4];
  const float* sigma = (const float*)d_in[5];
  const float* phi   = (const float*)d_in[6];
  float* out = (float*)d_out;

  char* ws = (char*)d_ws;
  size_t off = 0;
  auto alc = [&](size_t b) { size_t p = off; off = (off + b + 255) & ~(size_t)255; return p; };
  u16*  X     = (u16*)(ws + alc(2097152));
  u16*  A2T   = (u16*)(ws + alc(100663296));   // (b,o)[48 kh][1024 s]
  u16*  Au    = (u16*)(ws + alc(6291456));
  u16*  W1    = (u16*)(ws + alc(26738688));    // 26112x512; parts region spans W1+tail
  char* ptail = ws + alc(40370176); (void)ptail; // W1+tail = 64 MiB exactly
  float* phisT = (float*)(ws + alc(196608));   // [48 kf][1024 tau] f32
  float* bnd  = (float*)(ws + alc(131072));    // 16 even states x 2048 f32
  u16*  Abnd  = (u16*)(ws + alc(131072));      // 64 x 1024 bf16 boundary states
  u16*  Wm    = (u16*)(ws + alc(131072));      // 64 x 1024 bf16 w_c
  float* ubuf = (float*)(ws + alc(262144));    // 64 x 1024 f32 u_c
  if (off > ws_size) return;
  // lifetime-disjoint aliases:
  u16*  partsBf = (u16*)W1;                    // 32 conv slots x [1024][512] bf16
  float* zparts = (float*)W1;                  // 8 zgemm slots x 4 MiB f32
  u16*  ybf = A2T;                             // 2 MiB (after conv)
  float* zf = (float*)((char*)A2T + (4 << 20));
  u16*  Top = (u16*)((char*)A2T + (size_t)(8 << 20));   // 65 x 1 MiB
  u16*  STc = (u16*)((char*)A2T + (size_t)(76 << 20));  // 2 MiB scratch

  // prep
  k_prep_X<<<dim3(4096), 256, 0, stream>>>(u, X, 1048576);
  k_prep_phis<<<dim3(192), 256, 0, stream>>>(phi, sigma, phisT);
  k_prep_W1<<<dim3(52224), 256, 0, stream>>>(Mp, Mm, Mu, W1);

  // GEMM1: projections (spectral plus/minus + ar_u); 1-D XCD-chunked grid
  {
    GB g{}; g.A = X; g.B = W1; g.A2T = A2T; g.Au = Au;
    g.M = 2048; g.N = 26112;
    g2<0><<<dim3(3264), 256, 0, stream>>>(g);
  }
  // CONV: Toeplitz-from-band A, locality-ordered 1-D XCD-chunked grid
  {
    GB g{}; g.B = A2T; g.Cb = partsBf; g.phisT = phisT;
    g.M = 1024; g.N = 512;
    g2<1><<<dim3(576), 256, 0, stream>>>(g);
  }
  k_combine<<<dim3(512), 256, 0, stream>>>(partsBf, Au, ybf);

  // companion-power stack Top[0..32], then Top[63],Top[64] (= S32^2 halves)
  k_initTop<<<dim3(4096), 256, 0, stream>>>(my, Top);
  {
    const int cs[5] = {1, 2, 4, 8, 16};
    for (int li = 0; li < 5; ++li) {
      int c = cs[li];
      k_transT<<<dim3(16, 16), 256, 0, stream>>>(Top, STc, c);
      GB s{}; s.A = Top + 524288; s.B = STc; s.Cb = Top + (size_t)(c + 1) * 524288;
      s.M = 512; s.N = 1024;
      g2<5><<<dim3(8, 4, c), 256, 0, stream>>>(s);
    }
    // Top[63] = Top[31] * S^32, Top[64] = Top[32] * S^32
    k_transT<<<dim3(16, 16), 256, 0, stream>>>(Top, STc, 32);
    GB s{}; s.A = Top + (size_t)31 * 524288; s.B = STc;
    s.Cb = Top + (size_t)63 * 524288; s.M = 512; s.N = 1024;
    g2<5><<<dim3(8, 4, 2), 256, 0, stream>>>(s);
  }

  // within-chunk solve: z = Tri(H) y, splitK over tau-blocks; XCD-chunked
  {
    GB g{}; g.A = ybf; g.B = Top; g.Cf = zparts; g.M = 2048; g.N = 512;
    g2<2><<<dim3(512), 256, 0, stream>>>(g);
  }
  k_zreduce<<<dim3(4096), 256, 0, stream>>>(zparts, zf);

  // boundary chain: u_c precompute, 15 even steps, batched odd fill
  k_wm<<<dim3(256), 256, 0, stream>>>(zf, Wm);
  {
    GB g{}; g.A = Wm; g.B = Top; g.Cf = ubuf; g.zf = zf;
    g.M = 64; g.N = 1024;
    g2<6><<<dim3(8, 1, 1), 256, 0, stream>>>(g);
  }
  hipMemsetAsync(bnd, 0, 8192, stream);
  hipMemsetAsync(Abnd, 0, 131072, stream);
  for (int k = 0; k < 15; ++k)
    k_bnd2<<<dim3(32), 256, 0, stream>>>(Top, ubuf, bnd, Abnd, k);
  {
    GB g{}; g.A = Abnd; g.B = Top; g.Cb = Abnd; g.zf = zf;
    g.M = 32; g.N = 1024;
    g2<7><<<dim3(8, 1, 1), 256, 0, stream>>>(g);
  }

  // fixup: out = z + [H_{j+1}|G_j] @ Abnd
  {
    GB g{}; g.A = Abnd; g.B = Top; g.zf = zf; g.out = out;
    g.M = 64; g.N = 16384;
    g2<3><<<dim3(128, 1, 1), 256, 0, stream>>>(g);
  }
}

// Round 9
// 756.948 us; speedup vs baseline: 1.1346x; 1.0130x over previous
//
#include <hip/hip_runtime.h>
#include <hip/hip_bf16.h>

// STU forward, R9: R8 structure (dbuf + global_load_lds staging, splitK=8
// conv, compact triangular ZGEMM) with FIXED monotone grid decodes.
// Sizes: B=2, L=1024, K=24(x2), D=512, K_U=3, K_Y=2.

typedef unsigned short u16;
typedef __attribute__((ext_vector_type(8))) short  vshort8;
typedef __attribute__((ext_vector_type(4))) short  vshort4;
typedef __attribute__((ext_vector_type(4))) float  f32x4;
typedef __attribute__((ext_vector_type(4))) unsigned int vuint4;

__device__ __forceinline__ u16 f2b(float x) {
  __hip_bfloat16 h = __float2bfloat16(x);
  return __builtin_bit_cast(u16, h);
}
__device__ __forceinline__ float b2f(u16 x) {
  unsigned int u = ((unsigned int)x) << 16;
  return __builtin_bit_cast(float, u);
}

// async global->LDS, 16B per lane; LDS dest = wave-uniform base + lane*16
__device__ __forceinline__ void gll16(const u16* g, u16* l) {
  __builtin_amdgcn_global_load_lds((__attribute__((address_space(1))) void*)g,
                                   (__attribute__((address_space(3))) void*)l,
                                   16, 0, 0);
}

// ---------------------------------------------------------------------------
// Shared 128x128 MFMA GEMM template. C[m,n] = sum_k A[m,k]*Bmat[n,k].
//  V0 GEMM1: A=X(2048x512) B=W1(26112x512); 1-D grid 3264, XCD-chunked
//  V1 CONV : A=Wtoep strip (d=bm-cj), B=A2T; 1-D grid 1152, splitK=8
//  V2 ZGEMM: A=gather(ybf), B=Top; 1-D grid 544 triangular, 16 slices
//  V3 FIXUP: A=Abnd(64x1024), B=Top[j+1] rows -> out = acc + zf
//  V5 SGEMM: A=Top[*+bz] (512x1024), B=STc -> Top[*+bz] bf16 (batched)
//  V6 UGEMM: A=Wm(64x1024), B=S32 rows -> ubuf = acc + w_{c+1} (f32)
//  V7 ODD  : A=Abnd even rows, B=S32 rows -> Abnd odd rows = acc + w_{2k}
// ---------------------------------------------------------------------------
struct GB {
  const u16* A; const u16* B;
  float* Cf; u16* Cb;
  const float* zf; float* out;
  u16* A2T; u16* Au;
  const u16* zp;
  int M, N;
};

template<int V>
__global__ __launch_bounds__(256) void g2(GB a) {
  const int tid = threadIdx.x;
  int bn = blockIdx.x, bm = blockIdx.y;
  int zz = blockIdx.z;
  int cj = 0, cb = 0, cd = 0, slot = 0;
  int kbeg = 0, kend = 0;
  if (V == 0) {
    int f = blockIdx.x;
    int o = (f & 7) * 408 + (f >> 3);
    bm = o & 15; bn = o >> 4; kend = 512;
  }
  if (V == 1) {
    int f = blockIdx.x;
    int o = (f & 7) * 144 + (f >> 3);          // 1152 = 8 x 144
    // monotone threshold decode; group cj has size (8-cj)*32
    const int offs1[8] = {0, 256, 480, 672, 832, 960, 1056, 1120};
    cj = 0;
    if (o >= offs1[1]) cj = 1;
    if (o >= offs1[2]) cj = 2;
    if (o >= offs1[3]) cj = 3;
    if (o >= offs1[4]) cj = 4;
    if (o >= offs1[5]) cj = 5;
    if (o >= offs1[6]) cj = 6;
    if (o >= offs1[7]) cj = 7;
    int r = o - offs1[cj];
    int run = 8 - cj;
    int combo = r / run;                       // [0,32): (zzc, bn)
    bm = cj + (r - combo * run);
    int zzc = combo >> 2; bn = combo & 3;
    cb = zzc & 1; cd = bm - cj;
    slot = zzc * 8 + cj;
    kbeg = (zzc >> 1) * 1536; kend = kbeg + 1536;
  }
  if (V == 2) {
    int f = blockIdx.x;
    int o = (f & 7) * 68 + (f >> 3);           // 544 = 8 x 68
    // monotone threshold decode; slice s has size (16-s)*4
    const int offs2[16] = {0, 64, 124, 180, 232, 280, 324, 364,
                           400, 432, 460, 484, 504, 520, 532, 540};
    int s = 0;
#pragma unroll
    for (int c = 1; c < 16; ++c)
      if (o >= offs2[c]) s = c;
    int r = o - offs2[s];
    bm = s + (r >> 2); bn = r & 3;
    zz = s;
    kbeg = s * 1024; kend = kbeg + 1024;       // s<=bm guarantees validity
  }
  const int m0 = bm * 128, n0 = bn * 128;
  if (V == 3 || V == 5 || V == 6 || V == 7) kend = 1024;

  __shared__ u16 lA[2][4096], lB[2][4096];
  f32x4 acc[4][4];
#pragma unroll
  for (int i = 0; i < 4; i++)
#pragma unroll
    for (int j = 0; j < 4; j++) acc[i][j] = f32x4{0.f, 0.f, 0.f, 0.f};

  const int lane = tid & 63, wv = tid >> 6, wr = wv >> 1, wc = wv & 1;
  const u16* Ap = a.A;
  if (V == 5) Ap = a.A + (size_t)zz * 524288;
  const u16* zpl = a.zp + lane * 8;

  auto gaddrA = [&](int it, int k0) -> const u16* {
    int lrow = (it * 4 + wv) * 16 + (lane & 15);
    int kk = k0 + ((lane >> 4) << 3);
    if (V == 0) return Ap + (size_t)(m0 + lrow) * 512 + kk;
    if (V == 1) return Ap + (size_t)cd * 786432 + (size_t)lrow * 6144 + kk;
    if (V == 2) {
      int m = m0 + lrow, j = m >> 6, b = (m >> 5) & 1, c = m & 31;
      int tau = kk >> 9, p = kk & 511;
      if (tau > j) return zpl;
      return Ap + (size_t)(b * 1024 + c * 32 + j - tau) * 512 + p;
    }
    if (V == 3) { int m = m0 + lrow; return (m < a.M) ? Ap + (size_t)m * 1024 + kk : zpl; }
    if (V == 5) return Ap + (size_t)(m0 + lrow) * 1024 + kk;
    if (V == 6) return (lrow < 64) ? Ap + (size_t)lrow * 1024 + kk : zpl;
    // V7
    if (lrow < 32) {
      int b = lrow & 1, k2 = lrow >> 1;
      return Ap + (size_t)(b * 32 + 2 * k2) * 1024 + kk;
    }
    return zpl;
  };
  auto gaddrB = [&](int it, int k0) -> const u16* {
    int lrow = (it * 4 + wv) * 16 + (lane & 15);
    int kk = k0 + ((lane >> 4) << 3);
    int n = n0 + lrow;
    if (V == 0) return a.B + (size_t)n * 512 + kk;
    if (V == 1) {
      int kh = kk >> 7, sp = kk & 127;
      return a.B + (size_t)(cb * 512 + n) * 49152 + kh * 1024 + cj * 128 + sp;
    }
    if (V == 2) {
      int tau = kk >> 9, p = kk & 511;
      return a.B + (size_t)tau * 524288 + (size_t)n * 1024 + p;
    }
    if (V == 3) {
      int jn = n >> 9, o = n & 511;
      return a.B + (size_t)(jn + 1) * 524288 + (size_t)o * 1024 + kk;
    }
    if (V == 5) return a.B + (size_t)n * 1024 + kk;
    // V6/V7: rows of S32 = [Top32 ; Top31]
    return (n < 512)
        ? a.B + (size_t)32 * 524288 + (size_t)n * 1024 + kk
        : a.B + (size_t)31 * 524288 + (size_t)(n - 512) * 1024 + kk;
  };

  auto stage = [&](int c, int k0) {
#pragma unroll
    for (int it = 0; it < 2; ++it) {
      int weff = wv + it * 4;
      gll16(gaddrA(it, k0), &lA[c][weff * 512]);
      gll16(gaddrB(it, k0), &lB[c][weff * 512]);
    }
  };

  if (kbeg < kend) stage(0, kbeg);
  __syncthreads();                 // drains the prologue stage
  int cur = 0;
  for (int k0 = kbeg; k0 < kend; k0 += 32) {
    if (k0 + 32 < kend) stage(cur ^ 1, k0 + 32);   // async prefetch next tile
    vshort8 af[4], bf_[4];
#pragma unroll
    for (int s = 0; s < 4; s++) {
      af[s]  = *(const vshort8*)&lA[cur][(((wr * 4 + s) * 4 + (lane >> 4)) * 16 + (lane & 15)) * 8];
      bf_[s] = *(const vshort8*)&lB[cur][(((wc * 4 + s) * 4 + (lane >> 4)) * 16 + (lane & 15)) * 8];
    }
#pragma unroll
    for (int i = 0; i < 4; i++)
#pragma unroll
      for (int j = 0; j < 4; j++)
        acc[i][j] = __builtin_amdgcn_mfma_f32_16x16x32_bf16(af[i], bf_[j], acc[i][j], 0, 0, 0);
    __syncthreads();               // drains prefetch + protects buffer swap
    cur ^= 1;
  }

  // epilogue
#pragma unroll
  for (int i = 0; i < 4; i++) {
    int em = m0 + wr * 64 + i * 16 + ((lane >> 4) << 2);
#pragma unroll
    for (int j = 0; j < 4; j++) {
      int n = n0 + wc * 64 + j * 16 + (lane & 15);
      f32x4 v = acc[i][j];
      if (V == 0) {
        int b = em >> 10, s = em & 1023;
        if (n < 24576) {
          int kh = n >> 9, o = n & 511;
          vshort4 pk = { (short)f2b(v[0]), (short)f2b(v[1]), (short)f2b(v[2]), (short)f2b(v[3]) };
          *(vshort4*)(&a.A2T[(size_t)(b * 512 + o) * 49152 + (size_t)kh * 1024 + s]) = pk;
        } else {
          int jj = (n - 24576) >> 9, o = n & 511;
#pragma unroll
          for (int t = 0; t < 4; t++)
            a.Au[((size_t)(b * 3 + jj) * 1024 + (s + t)) * 512 + o] = f2b(v[t]);
        }
      } else if (V == 1) {
        u16* C = a.Cb + (size_t)slot * 524288;
#pragma unroll
        for (int t = 0; t < 4; t++) C[(size_t)(em + t) * 512 + n] = f2b(v[t]);
      } else if (V == 2) {
        float* C = a.Cf + (size_t)zz * 1048576;
#pragma unroll
        for (int t = 0; t < 4; t++) C[(size_t)(em + t) * 512 + n] = v[t];
      } else if (V == 3) {
        int jj = n >> 9, oo = n & 511;
#pragma unroll
        for (int t = 0; t < 4; t++) {
          int m = em + t;
          if (m < a.M) {
            int b = m >> 5, c = m & 31;
            float zv = a.zf[(size_t)(jj * 64 + b * 32 + c) * 512 + oo];
            a.out[(size_t)b * 524288 + (size_t)(c * 32 + jj) * 512 + oo] = v[t] + zv;
          }
        }
      } else if (V == 5) {
        u16* C = a.Cb + (size_t)zz * 524288;
#pragma unroll
        for (int t = 0; t < 4; t++) C[(size_t)(em + t) * 1024 + n] = f2b(v[t]);
      } else if (V == 6) {
        int jrow = (n < 512) ? 31 : 30, oo = n & 511;
#pragma unroll
        for (int t = 0; t < 4; t++) {
          int m = em + t;
          if (m < 62) {
            int b = m & 1, c = m >> 1;
            a.Cf[(size_t)m * 1024 + n] =
                v[t] + a.zf[(size_t)(jrow * 64 + b * 32 + (c + 1)) * 512 + oo];
          }
        }
      } else { // V7: odd states
        int jrow = (n < 512) ? 31 : 30, oo = n & 511;
#pragma unroll
        for (int t = 0; t < 4; t++) {
          int m = em + t;
          if (m < 32) {
            int b = m & 1, k2 = m >> 1;
            float val = v[t] + a.zf[(size_t)(jrow * 64 + b * 32 + 2 * k2) * 512 + oo];
            a.Cb[(size_t)(b * 32 + 2 * k2 + 1) * 1024 + n] = f2b(val);
          }
        }
      }
    }
  }
}

// ---------------------------------------------------------------------------
// prep / glue kernels
// ---------------------------------------------------------------------------
__global__ void k_prep_X(const float* __restrict__ u, u16* __restrict__ X, int n) {
  int i = blockIdx.x * 256 + threadIdx.x;
  if (i < n) X[i] = f2b(u[i]);
}

// phis[tau*48 + kf]: kf<24 -> phi_s[tau,kf]; kf>=24 -> phi_s[tau,kf-24]*(-1)^tau
__global__ void k_prep_phis(const float* __restrict__ phi, const float* __restrict__ sigma,
                            float* __restrict__ phis) {
  int i = blockIdx.x * 256 + threadIdx.x;
  if (i >= 1024 * 48) return;
  int tau = i / 48, kf = i % 48, k = (kf >= 24) ? kf - 24 : kf;
  float v = phi[tau * 24 + k] * powf(sigma[k], 0.25f);
  if (kf >= 24 && (tau & 1)) v = -v;
  phis[i] = v;
}

__global__ void k_prep_W1(const float* __restrict__ Mp, const float* __restrict__ Mm,
                          const float* __restrict__ Mu, u16* __restrict__ W1) {
  int i = blockIdx.x * 256 + threadIdx.x;
  if (i >= 13369344) return;
  float v;
  if (i < 6291456) v = Mp[i];
  else if (i < 12582912) v = Mm[i - 6291456];
  else v = Mu[i - 12582912];
  W1[i] = f2b(v);
}

// Wtoep[d][t'][kh*128+s'] = phis[(d*128+t'-s')*48 + kh] (0 if tau<0)
__global__ void k_prep_Wtoep(const float* __restrict__ phis, u16* __restrict__ W) {
  int i = blockIdx.x * 256 + threadIdx.x;
  if (i >= 6291456) return;
  int kap = i % 6144, row = i / 6144;
  int tp = row & 127, d = row >> 7;
  int kh = kap >> 7, sp = kap & 127;
  int tau = d * 128 + tp - sp;
  W[i] = (tau >= 0 && tau < 1024) ? f2b(phis[tau * 48 + kh]) : (u16)0;
}

// Top[0]=[I|0], Top[1]=[M1|M2]
__global__ void k_initTop(const float* __restrict__ my, u16* __restrict__ Top) {
  int i = blockIdx.x * 256 + threadIdx.x;
  if (i >= 1048576) return;
  int mat = i >> 19, rem = i & 524287, o = rem >> 10, k = rem & 1023;
  u16 v;
  if (mat == 0) v = (k == o) ? (u16)0x3F80 : (u16)0;
  else v = (k < 512) ? f2b(my[o * 512 + k]) : f2b(my[262144 + o * 512 + (k - 512)]);
  Top[i] = v;
}

// STc[n][k] = S^c[k][n];  S^c = [Top[c]; Top[c-1]]  (tiled transpose)
__global__ __launch_bounds__(256) void k_transT(const u16* __restrict__ Top,
                                                u16* __restrict__ STc, int c) {
  __shared__ u16 tile[64][72];
  int tx = blockIdx.x, ty = blockIdx.y;  // n-tile, k-tile
  int tid = threadIdx.x;
  int r = tid >> 2, seg = tid & 3;
  int k = ty * 64 + r;
  const u16* src = (k < 512) ? Top + (size_t)c * 524288 + (size_t)k * 1024 + tx * 64
                             : Top + (size_t)(c - 1) * 524288 + (size_t)(k - 512) * 1024 + tx * 64;
  *(vuint4*)&tile[r][seg * 16]     = *(const vuint4*)(src + seg * 16);
  *(vuint4*)&tile[r][seg * 16 + 8] = *(const vuint4*)(src + seg * 16 + 8);
  __syncthreads();
  int n = tx * 64 + r;
  u16 tmp[16];
#pragma unroll
  for (int j = 0; j < 16; j++) tmp[j] = tile[seg * 16 + j][r];
  *(vuint4*)&STc[(size_t)n * 1024 + ty * 64 + seg * 16]     = *(vuint4*)&tmp[0];
  *(vuint4*)&STc[(size_t)n * 1024 + ty * 64 + seg * 16 + 8] = *(vuint4*)&tmp[8];
}

__device__ __forceinline__ void addp(float* acc, vuint4 v) {
  const unsigned int* vu = (const unsigned int*)&v;
#pragma unroll
  for (int e = 0; e < 4; ++e) {
    unsigned int pw = vu[e];
    acc[2 * e]     += __builtin_bit_cast(float, (pw & 0xffffu) << 16);
    acc[2 * e + 1] += __builtin_bit_cast(float, pw & 0xffff0000u);
  }
}

// ybf[b,t,og*8..] = sum_j Au[b,j,t-j,:] + (t>=2 ? valid bf16 conv partials : 0)
// conv slots: slot = g*8 + j (g = zzc = (kchunk<<1)|cb in [0,8)), pick g&1==b
__global__ void k_combine(const u16* __restrict__ parts, const u16* __restrict__ Au,
                          u16* __restrict__ ybf) {
  int i = blockIdx.x * 256 + threadIdx.x;
  if (i >= 131072) return;
  int og = i & 63, t = (i >> 6) & 1023, b = i >> 16;
  float acc[8];
#pragma unroll
  for (int e = 0; e < 8; ++e) acc[e] = 0.f;
#pragma unroll
  for (int j = 0; j < 3; j++)
    if (t >= j)
      addp(acc, *(const vuint4*)(Au + ((size_t)(b * 3 + j) * 1024 + (t - j)) * 512 + og * 8));
  if (t >= 2) {
    int tp = t - 2, bmv = tp >> 7;
#pragma unroll
    for (int g = 0; g < 8; ++g) {
      if ((g & 1) != b) continue;
      const u16* base = parts + (size_t)(g * 8) * 524288 + (size_t)tp * 512 + og * 8;
      for (int j = 0; j <= bmv; ++j)
        addp(acc, *(const vuint4*)(base + (size_t)j * 524288));
    }
  }
  u16 o16[8];
#pragma unroll
  for (int e = 0; e < 8; ++e) o16[e] = f2b(acc[e]);
  *(vuint4*)(ybf + ((size_t)(b * 1024 + t)) * 512 + og * 8) = *(vuint4*)o16;
}

// zf[i] = sum over valid slices (s <= bm(i)) of zparts[s][i]
__global__ void k_zreduce(const float* __restrict__ zp, float* __restrict__ z) {
  int i = blockIdx.x * 256 + threadIdx.x;
  if (i >= 1048576) return;
  int nsum = (i >> 16) + 1;        // bm = i>>16 in [0,16)
  float s = 0.f;
  for (int j = 0; j < nsum; ++j) s += zp[(size_t)j * 1048576 + i];
  z[i] = s;
}

// Wm[(c<<1)|b][n] = bf16(w_c(b)[n]) from zf rows 31 (n<512) / 30 (n>=512)
__global__ void k_wm(const float* __restrict__ zf, u16* __restrict__ Wm) {
  int i = blockIdx.x * 256 + threadIdx.x;
  if (i >= 65536) return;
  int row = i >> 10, n = i & 1023;
  int b = row & 1, c = row >> 1;
  int jrow = (n < 512) ? 31 : 30, oo = n & 511;
  Wm[i] = f2b(zf[(size_t)(jrow * 64 + b * 32 + c) * 512 + oo]);
}

// even chain step k: E_{k+1} = S64 E_k + u_{2k}; emit Abnd row (b*32+2k+2)
__global__ __launch_bounds__(256) void k_bnd2(const u16* __restrict__ Top,
                                              const float* __restrict__ ubuf,
                                              float* __restrict__ bnd,
                                              u16* __restrict__ Abnd, int k) {
  __shared__ float st[2048];
  int tid = threadIdx.x;
  const float* s0 = bnd + (size_t)k * 2048;
  for (int j = tid; j < 2048; j += 256) st[j] = s0[j];
  __syncthreads();
  int q4 = blockIdx.x * 256 + tid;  // [0,8192)
  int q = q4 >> 2, quarter = q4 & 3;
  int b = q >> 10, kk = q & 1023;
  const u16* row = (kk < 512) ? Top + (size_t)64 * 524288 + (size_t)kk * 1024
                              : Top + (size_t)63 * 524288 + (size_t)(kk - 512) * 1024;
  const float* stb = st + b * 1024 + quarter * 256;
  const u16* rp = row + quarter * 256;
  float sum = 0.f;
  for (int t = 0; t < 32; ++t) {
    vuint4 v = *(const vuint4*)(rp + t * 8);
    const unsigned int* vu = (const unsigned int*)&v;
#pragma unroll
    for (int e = 0; e < 4; ++e) {
      unsigned int pw = vu[e];
      float lo = __builtin_bit_cast(float, (pw & 0xffffu) << 16);
      float hi = __builtin_bit_cast(float, pw & 0xffff0000u);
      sum += lo * stb[t * 8 + e * 2] + hi * stb[t * 8 + e * 2 + 1];
    }
  }
  sum += __shfl_xor(sum, 1);
  sum += __shfl_xor(sum, 2);
  if (quarter == 0) {
    float s = sum + ubuf[(size_t)(4 * k + b) * 1024 + kk];
    bnd[(size_t)(k + 1) * 2048 + b * 1024 + kk] = s;
    Abnd[(size_t)(b * 32 + 2 * k + 2) * 1024 + kk] = f2b(s);
  }
}

// ---------------------------------------------------------------------------
extern "C" void kernel_launch(void* const* d_in, const int* in_sizes, int n_in,
                              void* d_out, int out_size, void* d_ws, size_t ws_size,
                              hipStream_t stream) {
  const float* u     = (const float*)d_in[0];
  const float* Mu    = (const float*)d_in[1];
  const float* Mp    = (const float*)d_in[2];
  const float* Mm    = (const float*)d_in[3];
  const float* my    = (const float*)d_in[4];
  const float* sigma = (const float*)d_in[5];
  const float* phi   = (const float*)d_in[6];
  float* out = (float*)d_out;

  char* ws = (char*)d_ws;
  size_t off = 0;
  auto alc = [&](size_t b) { size_t p = off; off = (off + b + 255) & ~(size_t)255; return p; };
  u16*  X     = (u16*)(ws + alc(2097152));
  u16*  Wtoep = (u16*)(ws + alc(12582912));    // 8 d x 128 x 6144
  u16*  A2T   = (u16*)(ws + alc(100663296));   // (b,o)[48 kh][1024 s]
  u16*  Au    = (u16*)(ws + alc(6291456));
  u16*  W1    = (u16*)(ws + alc(26738688));    // 26112x512; parts region spans W1+tail
  char* ptail = ws + alc(40370176); (void)ptail; // W1+tail = 64 MiB exactly
  float* phis = (float*)(ws + alc(196608));    // [1024 tau][48 kf] f32
  float* bnd  = (float*)(ws + alc(131072));    // 16 even states x 2048 f32
  u16*  Abnd  = (u16*)(ws + alc(131072));      // 64 x 1024 bf16 boundary states
  u16*  Wm    = (u16*)(ws + alc(131072));      // 64 x 1024 bf16 w_c
  float* ubuf = (float*)(ws + alc(262144));    // 64 x 1024 f32 u_c
  u16*  zpad  = (u16*)(ws + alc(32768));       // zero page for predicated lanes
  if (off > ws_size) return;
  // lifetime-disjoint aliases:
  u16*  partsBf = (u16*)W1;                    // 64 conv slots x [1024][512] bf16 = 64 MiB
  float* zparts = (float*)W1;                  // 16 zgemm slots x 4 MiB f32 = 64 MiB
  u16*  ybf = A2T;                             // 2 MiB (after conv)
  float* zf = (float*)((char*)A2T + (4 << 20));
  u16*  Top = (u16*)((char*)A2T + (size_t)(8 << 20));   // 65 x 1 MiB
  u16*  STc = (u16*)((char*)A2T + (size_t)(76 << 20));  // 2 MiB scratch

  hipMemsetAsync(zpad, 0, 32768, stream);

  // prep
  k_prep_X<<<dim3(4096), 256, 0, stream>>>(u, X, 1048576);
  k_prep_phis<<<dim3(192), 256, 0, stream>>>(phi, sigma, phis);
  k_prep_W1<<<dim3(52224), 256, 0, stream>>>(Mp, Mm, Mu, W1);
  k_prep_Wtoep<<<dim3(24576), 256, 0, stream>>>(phis, Wtoep);

  // GEMM1: projections (spectral plus/minus + ar_u); 1-D XCD-chunked grid
  {
    GB g{}; g.A = X; g.B = W1; g.A2T = A2T; g.Au = Au; g.zp = zpad;
    g.M = 2048; g.N = 26112;
    g2<0><<<dim3(3264), 256, 0, stream>>>(g);
  }
  // CONV: global Wtoep strips, locality-ordered XCD-chunked grid, splitK=8
  {
    GB g{}; g.A = Wtoep; g.B = A2T; g.Cb = partsBf; g.zp = zpad;
    g.M = 1024; g.N = 512;
    g2<1><<<dim3(1152), 256, 0, stream>>>(g);
  }
  k_combine<<<dim3(512), 256, 0, stream>>>(partsBf, Au, ybf);

  // companion-power stack Top[0..32], then Top[63],Top[64] (= S32^2 halves)
  k_initTop<<<dim3(4096), 256, 0, stream>>>(my, Top);
  {
    const int cs[5] = {1, 2, 4, 8, 16};
    for (int li = 0; li < 5; ++li) {
      int c = cs[li];
      k_transT<<<dim3(16, 16), 256, 0, stream>>>(Top, STc, c);
      GB s{}; s.A = Top + 524288; s.B = STc; s.Cb = Top + (size_t)(c + 1) * 524288;
      s.zp = zpad; s.M = 512; s.N = 1024;
      g2<5><<<dim3(8, 4, c), 256, 0, stream>>>(s);
    }
    // Top[63] = Top[31] * S^32, Top[64] = Top[32] * S^32
    k_transT<<<dim3(16, 16), 256, 0, stream>>>(Top, STc, 32);
    GB s{}; s.A = Top + (size_t)31 * 524288; s.B = STc;
    s.Cb = Top + (size_t)63 * 524288; s.zp = zpad; s.M = 512; s.N = 1024;
    g2<5><<<dim3(8, 4, 2), 256, 0, stream>>>(s);
  }

  // within-chunk solve: z = Tri(H) y; compact triangular grid, 16 slices
  {
    GB g{}; g.A = ybf; g.B = Top; g.Cf = zparts; g.zp = zpad;
    g.M = 2048; g.N = 512;
    g2<2><<<dim3(544), 256, 0, stream>>>(g);
  }
  k_zreduce<<<dim3(4096), 256, 0, stream>>>(zparts, zf);

  // boundary chain: u_c precompute, 15 even steps, batched odd fill
  k_wm<<<dim3(256), 256, 0, stream>>>(zf, Wm);
  {
    GB g{}; g.A = Wm; g.B = Top; g.Cf = ubuf; g.zf = zf; g.zp = zpad;
    g.M = 64; g.N = 1024;
    g2<6><<<dim3(8, 1, 1), 256, 0, stream>>>(g);
  }
  hipMemsetAsync(bnd, 0, 8192, stream);
  hipMemsetAsync(Abnd, 0, 131072, stream);
  for (int k = 0; k < 15; ++k)
    k_bnd2<<<dim3(32), 256, 0, stream>>>(Top, ubuf, bnd, Abnd, k);
  {
    GB g{}; g.A = Abnd; g.B = Top; g.Cb = Abnd; g.zf = zf; g.zp = zpad;
    g.M = 32; g.N = 1024;
    g2<7><<<dim3(8, 1, 1), 256, 0, stream>>>(g);
  }

  // fixup: out = z + [H_{j+1}|G_j] @ Abnd
  {
    GB g{}; g.A = Abnd; g.B = Top; g.zf = zf; g.out = out; g.zp = zpad;
    g.M = 64; g.N = 16384;
    g2<3><<<dim3(128, 1, 1), 256, 0, stream>>>(g);
  }
}

// Round 10
// 714.547 us; speedup vs baseline: 1.2019x; 1.0593x over previous
//
#include <hip/hip_runtime.h>
#include <hip/hip_bf16.h>

// STU forward, R10: R9 + LDS-transpose epilogue for GEMM1's A2T writes
// (8B scatter -> 256B coalesced runs), vectorized prep kernels.
// Sizes: B=2, L=1024, K=24(x2), D=512, K_U=3, K_Y=2.

typedef unsigned short u16;
typedef __attribute__((ext_vector_type(8))) short  vshort8;
typedef __attribute__((ext_vector_type(4))) short  vshort4;
typedef __attribute__((ext_vector_type(4))) float  f32x4;
typedef __attribute__((ext_vector_type(4))) unsigned int vuint4;

__device__ __forceinline__ u16 f2b(float x) {
  __hip_bfloat16 h = __float2bfloat16(x);
  return __builtin_bit_cast(u16, h);
}
__device__ __forceinline__ float b2f(u16 x) {
  unsigned int u = ((unsigned int)x) << 16;
  return __builtin_bit_cast(float, u);
}

// async global->LDS, 16B per lane; LDS dest = wave-uniform base + lane*16
__device__ __forceinline__ void gll16(const u16* g, u16* l) {
  __builtin_amdgcn_global_load_lds((__attribute__((address_space(1))) void*)g,
                                   (__attribute__((address_space(3))) void*)l,
                                   16, 0, 0);
}

// ---------------------------------------------------------------------------
// Shared 128x128 MFMA GEMM template. C[m,n] = sum_k A[m,k]*Bmat[n,k].
//  V0 GEMM1: A=X(2048x512) B=W1(26112x512); 1-D grid 3264, XCD-chunked
//  V1 CONV : A=Wtoep strip (d=bm-cj), B=A2T; 1-D grid 1152, splitK=8
//  V2 ZGEMM: A=gather(ybf), B=Top; 1-D grid 544 triangular, 16 slices
//  V3 FIXUP: A=Abnd(64x1024), B=Top[j+1] rows -> out = acc + zf
//  V5 SGEMM: A=Top[*+bz] (512x1024), B=STc -> Top[*+bz] bf16 (batched)
//  V6 UGEMM: A=Wm(64x1024), B=S32 rows -> ubuf = acc + w_{c+1} (f32)
//  V7 ODD  : A=Abnd even rows, B=S32 rows -> Abnd odd rows = acc + w_{2k}
// ---------------------------------------------------------------------------
struct GB {
  const u16* A; const u16* B;
  float* Cf; u16* Cb;
  const float* zf; float* out;
  u16* A2T; u16* Au;
  const u16* zp;
  int M, N;
};

template<int V>
__global__ __launch_bounds__(256) void g2(GB a) {
  const int tid = threadIdx.x;
  int bn = blockIdx.x, bm = blockIdx.y;
  int zz = blockIdx.z;
  int cj = 0, cb = 0, cd = 0, slot = 0;
  int kbeg = 0, kend = 0;
  if (V == 0) {
    int f = blockIdx.x;
    int o = (f & 7) * 408 + (f >> 3);
    bm = o & 15; bn = o >> 4; kend = 512;
  }
  if (V == 1) {
    int f = blockIdx.x;
    int o = (f & 7) * 144 + (f >> 3);          // 1152 = 8 x 144
    // monotone threshold decode; group cj has size (8-cj)*32
    const int offs1[8] = {0, 256, 480, 672, 832, 960, 1056, 1120};
    cj = 0;
    if (o >= offs1[1]) cj = 1;
    if (o >= offs1[2]) cj = 2;
    if (o >= offs1[3]) cj = 3;
    if (o >= offs1[4]) cj = 4;
    if (o >= offs1[5]) cj = 5;
    if (o >= offs1[6]) cj = 6;
    if (o >= offs1[7]) cj = 7;
    int r = o - offs1[cj];
    int run = 8 - cj;
    int combo = r / run;                       // [0,32): (zzc, bn)
    bm = cj + (r - combo * run);
    int zzc = combo >> 2; bn = combo & 3;
    cb = zzc & 1; cd = bm - cj;
    slot = zzc * 8 + cj;
    kbeg = (zzc >> 1) * 1536; kend = kbeg + 1536;
  }
  if (V == 2) {
    int f = blockIdx.x;
    int o = (f & 7) * 68 + (f >> 3);           // 544 = 8 x 68
    // monotone threshold decode; slice s has size (16-s)*4
    const int offs2[16] = {0, 64, 124, 180, 232, 280, 324, 364,
                           400, 432, 460, 484, 504, 520, 532, 540};
    int s = 0;
#pragma unroll
    for (int c = 1; c < 16; ++c)
      if (o >= offs2[c]) s = c;
    int r = o - offs2[s];
    bm = s + (r >> 2); bn = r & 3;
    zz = s;
    kbeg = s * 1024; kend = kbeg + 1024;       // s<=bm guarantees validity
  }
  const int m0 = bm * 128, n0 = bn * 128;
  if (V == 3 || V == 5 || V == 6 || V == 7) kend = 1024;

  __shared__ u16 smem[16384];                  // lA = smem, lB = smem+8192
  f32x4 acc[4][4];
#pragma unroll
  for (int i = 0; i < 4; i++)
#pragma unroll
    for (int j = 0; j < 4; j++) acc[i][j] = f32x4{0.f, 0.f, 0.f, 0.f};

  const int lane = tid & 63, wv = tid >> 6, wr = wv >> 1, wc = wv & 1;
  const u16* Ap = a.A;
  if (V == 5) Ap = a.A + (size_t)zz * 524288;
  const u16* zpl = a.zp + lane * 8;

  auto gaddrA = [&](int it, int k0) -> const u16* {
    int lrow = (it * 4 + wv) * 16 + (lane & 15);
    int kk = k0 + ((lane >> 4) << 3);
    if (V == 0) return Ap + (size_t)(m0 + lrow) * 512 + kk;
    if (V == 1) return Ap + (size_t)cd * 786432 + (size_t)lrow * 6144 + kk;
    if (V == 2) {
      int m = m0 + lrow, j = m >> 6, b = (m >> 5) & 1, c = m & 31;
      int tau = kk >> 9, p = kk & 511;
      if (tau > j) return zpl;
      return Ap + (size_t)(b * 1024 + c * 32 + j - tau) * 512 + p;
    }
    if (V == 3) { int m = m0 + lrow; return (m < a.M) ? Ap + (size_t)m * 1024 + kk : zpl; }
    if (V == 5) return Ap + (size_t)(m0 + lrow) * 1024 + kk;
    if (V == 6) return (lrow < 64) ? Ap + (size_t)lrow * 1024 + kk : zpl;
    // V7
    if (lrow < 32) {
      int b = lrow & 1, k2 = lrow >> 1;
      return Ap + (size_t)(b * 32 + 2 * k2) * 1024 + kk;
    }
    return zpl;
  };
  auto gaddrB = [&](int it, int k0) -> const u16* {
    int lrow = (it * 4 + wv) * 16 + (lane & 15);
    int kk = k0 + ((lane >> 4) << 3);
    int n = n0 + lrow;
    if (V == 0) return a.B + (size_t)n * 512 + kk;
    if (V == 1) {
      int kh = kk >> 7, sp = kk & 127;
      return a.B + (size_t)(cb * 512 + n) * 49152 + kh * 1024 + cj * 128 + sp;
    }
    if (V == 2) {
      int tau = kk >> 9, p = kk & 511;
      return a.B + (size_t)tau * 524288 + (size_t)n * 1024 + p;
    }
    if (V == 3) {
      int jn = n >> 9, o = n & 511;
      return a.B + (size_t)(jn + 1) * 524288 + (size_t)o * 1024 + kk;
    }
    if (V == 5) return a.B + (size_t)n * 1024 + kk;
    // V6/V7: rows of S32 = [Top32 ; Top31]
    return (n < 512)
        ? a.B + (size_t)32 * 524288 + (size_t)n * 1024 + kk
        : a.B + (size_t)31 * 524288 + (size_t)(n - 512) * 1024 + kk;
  };

  auto stage = [&](int c, int k0) {
#pragma unroll
    for (int it = 0; it < 2; ++it) {
      int weff = wv + it * 4;
      gll16(gaddrA(it, k0), smem + c * 4096 + weff * 512);
      gll16(gaddrB(it, k0), smem + 8192 + c * 4096 + weff * 512);
    }
  };

  if (kbeg < kend) stage(0, kbeg);
  __syncthreads();                 // drains the prologue stage
  int cur = 0;
  for (int k0 = kbeg; k0 < kend; k0 += 32) {
    if (k0 + 32 < kend) stage(cur ^ 1, k0 + 32);   // async prefetch next tile
    vshort8 af[4], bf_[4];
#pragma unroll
    for (int s = 0; s < 4; s++) {
      af[s]  = *(const vshort8*)&smem[cur * 4096 + (((wr * 4 + s) * 4 + (lane >> 4)) * 16 + (lane & 15)) * 8];
      bf_[s] = *(const vshort8*)&smem[8192 + cur * 4096 + (((wc * 4 + s) * 4 + (lane >> 4)) * 16 + (lane & 15)) * 8];
    }
#pragma unroll
    for (int i = 0; i < 4; i++)
#pragma unroll
      for (int j = 0; j < 4; j++)
        acc[i][j] = __builtin_amdgcn_mfma_f32_16x16x32_bf16(af[i], bf_[j], acc[i][j], 0, 0, 0);
    __syncthreads();               // drains prefetch + protects buffer swap
    cur ^= 1;
  }

  // ---- epilogue ----
  if (V == 0 && bn < 192) {
    // transpose C tile through LDS: smem[phys][stride 136], phys in [0,64)
    const int strd = 136;
    const int b = m0 >> 10;
#pragma unroll
    for (int p = 0; p < 2; ++p) {
      __syncthreads();
#pragma unroll
      for (int i = 0; i < 4; i++) {
#pragma unroll
        for (int jl = 0; jl < 2; jl++) {
          int j = p * 2 + jl;
          f32x4 v = acc[i][j];
          int mloc = wr * 64 + i * 16 + ((lane >> 4) << 2);
          int phys = (lane & 15) + (jl << 4) + (wc << 5);
          vshort4 pk = { (short)f2b(v[0]), (short)f2b(v[1]),
                         (short)f2b(v[2]), (short)f2b(v[3]) };
          *(vshort4*)&smem[phys * strd + mloc] = pk;
        }
      }
      __syncthreads();
      int rowp = tid >> 2, t4 = tid & 3;
      int c15 = rowp & 15, jl = (rowp >> 4) & 1, wcp = rowp >> 5;
      int n = n0 + wcp * 64 + p * 32 + jl * 16 + c15;
      int o = n & 511, kh = n >> 9;
      int sbase = (m0 & 1023) + t4 * 32;
      u16* dst = a.A2T + (size_t)(b * 512 + o) * 49152 + (size_t)kh * 1024 + sbase;
      const u16* srcl = &smem[rowp * strd + t4 * 32];
#pragma unroll
      for (int q = 0; q < 4; ++q)
        *(vuint4*)(dst + q * 8) = *(const vuint4*)(srcl + q * 8);
    }
    return;
  }

#pragma unroll
  for (int i = 0; i < 4; i++) {
    int em = m0 + wr * 64 + i * 16 + ((lane >> 4) << 2);
#pragma unroll
    for (int j = 0; j < 4; j++) {
      int n = n0 + wc * 64 + j * 16 + (lane & 15);
      f32x4 v = acc[i][j];
      if (V == 0) {
        int b = em >> 10, s = em & 1023;
        int jj = (n - 24576) >> 9, o = n & 511;
#pragma unroll
        for (int t = 0; t < 4; t++)
          a.Au[((size_t)(b * 3 + jj) * 1024 + (s + t)) * 512 + o] = f2b(v[t]);
      } else if (V == 1) {
        u16* C = a.Cb + (size_t)slot * 524288;
#pragma unroll
        for (int t = 0; t < 4; t++) C[(size_t)(em + t) * 512 + n] = f2b(v[t]);
      } else if (V == 2) {
        float* C = a.Cf + (size_t)zz * 1048576;
#pragma unroll
        for (int t = 0; t < 4; t++) C[(size_t)(em + t) * 512 + n] = v[t];
      } else if (V == 3) {
        int jj = n >> 9, oo = n & 511;
#pragma unroll
        for (int t = 0; t < 4; t++) {
          int m = em + t;
          if (m < a.M) {
            int b = m >> 5, c = m & 31;
            float zv = a.zf[(size_t)(jj * 64 + b * 32 + c) * 512 + oo];
            a.out[(size_t)b * 524288 + (size_t)(c * 32 + jj) * 512 + oo] = v[t] + zv;
          }
        }
      } else if (V == 5) {
        u16* C = a.Cb + (size_t)zz * 524288;
#pragma unroll
        for (int t = 0; t < 4; t++) C[(size_t)(em + t) * 1024 + n] = f2b(v[t]);
      } else if (V == 6) {
        int jrow = (n < 512) ? 31 : 30, oo = n & 511;
#pragma unroll
        for (int t = 0; t < 4; t++) {
          int m = em + t;
          if (m < 62) {
            int b = m & 1, c = m >> 1;
            a.Cf[(size_t)m * 1024 + n] =
                v[t] + a.zf[(size_t)(jrow * 64 + b * 32 + (c + 1)) * 512 + oo];
          }
        }
      } else { // V7: odd states
        int jrow = (n < 512) ? 31 : 30, oo = n & 511;
#pragma unroll
        for (int t = 0; t < 4; t++) {
          int m = em + t;
          if (m < 32) {
            int b = m & 1, k2 = m >> 1;
            float val = v[t] + a.zf[(size_t)(jrow * 64 + b * 32 + 2 * k2) * 512 + oo];
            a.Cb[(size_t)(b * 32 + 2 * k2 + 1) * 1024 + n] = f2b(val);
          }
        }
      }
    }
  }
}

// ---------------------------------------------------------------------------
// prep / glue kernels
// ---------------------------------------------------------------------------
__global__ void k_prep_X(const float* __restrict__ u, u16* __restrict__ X) {
  int i4 = (blockIdx.x * 256 + threadIdx.x) * 4;
  if (i4 >= 1048576) return;
  f32x4 v = *(const f32x4*)(u + i4);
  vshort4 pk = { (short)f2b(v[0]), (short)f2b(v[1]), (short)f2b(v[2]), (short)f2b(v[3]) };
  *(vshort4*)(X + i4) = pk;
}

// phis[tau*48 + kf]: kf<24 -> phi_s[tau,kf]; kf>=24 -> phi_s[tau,kf-24]*(-1)^tau
__global__ void k_prep_phis(const float* __restrict__ phi, const float* __restrict__ sigma,
                            float* __restrict__ phis) {
  int i = blockIdx.x * 256 + threadIdx.x;
  if (i >= 1024 * 48) return;
  int tau = i / 48, kf = i % 48, k = (kf >= 24) ? kf - 24 : kf;
  float v = phi[tau * 24 + k] * powf(sigma[k], 0.25f);
  if (kf >= 24 && (tau & 1)) v = -v;
  phis[i] = v;
}

__global__ void k_prep_W1(const float* __restrict__ Mp, const float* __restrict__ Mm,
                          const float* __restrict__ Mu, u16* __restrict__ W1) {
  int i4 = (blockIdx.x * 256 + threadIdx.x) * 4;
  if (i4 >= 13369344) return;
  const float* src; int off;
  if (i4 < 6291456) { src = Mp; off = i4; }
  else if (i4 < 12582912) { src = Mm; off = i4 - 6291456; }
  else { src = Mu; off = i4 - 12582912; }
  f32x4 v = *(const f32x4*)(src + off);
  vshort4 pk = { (short)f2b(v[0]), (short)f2b(v[1]), (short)f2b(v[2]), (short)f2b(v[3]) };
  *(vshort4*)(W1 + i4) = pk;
}

// Wtoep[d][t'][kh*128+s'] = phis[(d*128+t'-s')*48 + kh] (0 if tau<0)
__global__ void k_prep_Wtoep(const float* __restrict__ phis, u16* __restrict__ W) {
  int i = blockIdx.x * 256 + threadIdx.x;
  if (i >= 6291456) return;
  int kap = i % 6144, row = i / 6144;
  int tp = row & 127, d = row >> 7;
  int kh = kap >> 7, sp = kap & 127;
  int tau = d * 128 + tp - sp;
  W[i] = (tau >= 0 && tau < 1024) ? f2b(phis[tau * 48 + kh]) : (u16)0;
}

// Top[0]=[I|0], Top[1]=[M1|M2]
__global__ void k_initTop(const float* __restrict__ my, u16* __restrict__ Top) {
  int i = blockIdx.x * 256 + threadIdx.x;
  if (i >= 1048576) return;
  int mat = i >> 19, rem = i & 524287, o = rem >> 10, k = rem & 1023;
  u16 v;
  if (mat == 0) v = (k == o) ? (u16)0x3F80 : (u16)0;
  else v = (k < 512) ? f2b(my[o * 512 + k]) : f2b(my[262144 + o * 512 + (k - 512)]);
  Top[i] = v;
}

// STc[n][k] = S^c[k][n];  S^c = [Top[c]; Top[c-1]]  (tiled transpose)
__global__ __launch_bounds__(256) void k_transT(const u16* __restrict__ Top,
                                                u16* __restrict__ STc, int c) {
  __shared__ u16 tile[64][72];
  int tx = blockIdx.x, ty = blockIdx.y;  // n-tile, k-tile
  int tid = threadIdx.x;
  int r = tid >> 2, seg = tid & 3;
  int k = ty * 64 + r;
  const u16* src = (k < 512) ? Top + (size_t)c * 524288 + (size_t)k * 1024 + tx * 64
                             : Top + (size_t)(c - 1) * 524288 + (size_t)(k - 512) * 1024 + tx * 64;
  *(vuint4*)&tile[r][seg * 16]     = *(const vuint4*)(src + seg * 16);
  *(vuint4*)&tile[r][seg * 16 + 8] = *(const vuint4*)(src + seg * 16 + 8);
  __syncthreads();
  int n = tx * 64 + r;
  u16 tmp[16];
#pragma unroll
  for (int j = 0; j < 16; j++) tmp[j] = tile[seg * 16 + j][r];
  *(vuint4*)&STc[(size_t)n * 1024 + ty * 64 + seg * 16]     = *(vuint4*)&tmp[0];
  *(vuint4*)&STc[(size_t)n * 1024 + ty * 64 + seg * 16 + 8] = *(vuint4*)&tmp[8];
}

__device__ __forceinline__ void addp(float* acc, vuint4 v) {
  const unsigned int* vu = (const unsigned int*)&v;
#pragma unroll
  for (int e = 0; e < 4; ++e) {
    unsigned int pw = vu[e];
    acc[2 * e]     += __builtin_bit_cast(float, (pw & 0xffffu) << 16);
    acc[2 * e + 1] += __builtin_bit_cast(float, pw & 0xffff0000u);
  }
}

// ybf[b,t,og*8..] = sum_j Au[b,j,t-j,:] + (t>=2 ? valid bf16 conv partials : 0)
// conv slots: slot = g*8 + j (g = zzc = (kchunk<<1)|cb in [0,8)), pick g&1==b
__global__ void k_combine(const u16* __restrict__ parts, const u16* __restrict__ Au,
                          u16* __restrict__ ybf) {
  int i = blockIdx.x * 256 + threadIdx.x;
  if (i >= 131072) return;
  int og = i & 63, t = (i >> 6) & 1023, b = i >> 16;
  float acc[8];
#pragma unroll
  for (int e = 0; e < 8; ++e) acc[e] = 0.f;
#pragma unroll
  for (int j = 0; j < 3; j++)
    if (t >= j)
      addp(acc, *(const vuint4*)(Au + ((size_t)(b * 3 + j) * 1024 + (t - j)) * 512 + og * 8));
  if (t >= 2) {
    int tp = t - 2, bmv = tp >> 7;
#pragma unroll
    for (int g = 0; g < 8; ++g) {
      if ((g & 1) != b) continue;
      const u16* base = parts + (size_t)(g * 8) * 524288 + (size_t)tp * 512 + og * 8;
      for (int j = 0; j <= bmv; ++j)
        addp(acc, *(const vuint4*)(base + (size_t)j * 524288));
    }
  }
  u16 o16[8];
#pragma unroll
  for (int e = 0; e < 8; ++e) o16[e] = f2b(acc[e]);
  *(vuint4*)(ybf + ((size_t)(b * 1024 + t)) * 512 + og * 8) = *(vuint4*)o16;
}

// zf[i] = sum over valid slices (s <= bm(i)) of zparts[s][i]
__global__ void k_zreduce(const float* __restrict__ zp, float* __restrict__ z) {
  int i = blockIdx.x * 256 + threadIdx.x;
  if (i >= 1048576) return;
  int nsum = (i >> 16) + 1;        // bm = i>>16 in [0,16)
  float s = 0.f;
  for (int j = 0; j < nsum; ++j) s += zp[(size_t)j * 1048576 + i];
  z[i] = s;
}

// Wm[(c<<1)|b][n] = bf16(w_c(b)[n]) from zf rows 31 (n<512) / 30 (n>=512)
__global__ void k_wm(const float* __restrict__ zf, u16* __restrict__ Wm) {
  int i = blockIdx.x * 256 + threadIdx.x;
  if (i >= 65536) return;
  int row = i >> 10, n = i & 1023;
  int b = row & 1, c = row >> 1;
  int jrow = (n < 512) ? 31 : 30, oo = n & 511;
  Wm[i] = f2b(zf[(size_t)(jrow * 64 + b * 32 + c) * 512 + oo]);
}

// even chain step k: E_{k+1} = S64 E_k + u_{2k}; emit Abnd row (b*32+2k+2)
__global__ __launch_bounds__(256) void k_bnd2(const u16* __restrict__ Top,
                                              const float* __restrict__ ubuf,
                                              float* __restrict__ bnd,
                                              u16* __restrict__ Abnd, int k) {
  __shared__ float st[2048];
  int tid = threadIdx.x;
  const float* s0 = bnd + (size_t)k * 2048;
  for (int j = tid; j < 2048; j += 256) st[j] = s0[j];
  __syncthreads();
  int q4 = blockIdx.x * 256 + tid;  // [0,8192)
  int q = q4 >> 2, quarter = q4 & 3;
  int b = q >> 10, kk = q & 1023;
  const u16* row = (kk < 512) ? Top + (size_t)64 * 524288 + (size_t)kk * 1024
                              : Top + (size_t)63 * 524288 + (size_t)(kk - 512) * 1024;
  const float* stb = st + b * 1024 + quarter * 256;
  const u16* rp = row + quarter * 256;
  float sum = 0.f;
  for (int t = 0; t < 32; ++t) {
    vuint4 v = *(const vuint4*)(rp + t * 8);
    const unsigned int* vu = (const unsigned int*)&v;
#pragma unroll
    for (int e = 0; e < 4; ++e) {
      unsigned int pw = vu[e];
      float lo = __builtin_bit_cast(float, (pw & 0xffffu) << 16);
      float hi = __builtin_bit_cast(float, pw & 0xffff0000u);
      sum += lo * stb[t * 8 + e * 2] + hi * stb[t * 8 + e * 2 + 1];
    }
  }
  sum += __shfl_xor(sum, 1);
  sum += __shfl_xor(sum, 2);
  if (quarter == 0) {
    float s = sum + ubuf[(size_t)(4 * k + b) * 1024 + kk];
    bnd[(size_t)(k + 1) * 2048 + b * 1024 + kk] = s;
    Abnd[(size_t)(b * 32 + 2 * k + 2) * 1024 + kk] = f2b(s);
  }
}

// ---------------------------------------------------------------------------
extern "C" void kernel_launch(void* const* d_in, const int* in_sizes, int n_in,
                              void* d_out, int out_size, void* d_ws, size_t ws_size,
                              hipStream_t stream) {
  const float* u     = (const float*)d_in[0];
  const float* Mu    = (const float*)d_in[1];
  const float* Mp    = (const float*)d_in[2];
  const float* Mm    = (const float*)d_in[3];
  const float* my    = (const float*)d_in[4];
  const float* sigma = (const float*)d_in[5];
  const float* phi   = (const float*)d_in[6];
  float* out = (float*)d_out;

  char* ws = (char*)d_ws;
  size_t off = 0;
  auto alc = [&](size_t b) { size_t p = off; off = (off + b + 255) & ~(size_t)255; return p; };
  u16*  X     = (u16*)(ws + alc(2097152));
  u16*  Wtoep = (u16*)(ws + alc(12582912));    // 8 d x 128 x 6144
  u16*  A2T   = (u16*)(ws + alc(100663296));   // (b,o)[48 kh][1024 s]
  u16*  Au    = (u16*)(ws + alc(6291456));
  u16*  W1    = (u16*)(ws + alc(26738688));    // 26112x512; parts region spans W1+tail
  char* ptail = ws + alc(40370176); (void)ptail; // W1+tail = 64 MiB exactly
  float* phis = (float*)(ws + alc(196608));    // [1024 tau][48 kf] f32
  float* bnd  = (float*)(ws + alc(131072));    // 16 even states x 2048 f32
  u16*  Abnd  = (u16*)(ws + alc(131072));      // 64 x 1024 bf16 boundary states
  u16*  Wm    = (u16*)(ws + alc(131072));      // 64 x 1024 bf16 w_c
  float* ubuf = (float*)(ws + alc(262144));    // 64 x 1024 f32 u_c
  u16*  zpad  = (u16*)(ws + alc(32768));       // zero page for predicated lanes
  if (off > ws_size) return;
  // lifetime-disjoint aliases:
  u16*  partsBf = (u16*)W1;                    // 64 conv slots x [1024][512] bf16 = 64 MiB
  float* zparts = (float*)W1;                  // 16 zgemm slots x 4 MiB f32 = 64 MiB
  u16*  ybf = A2T;                             // 2 MiB (after conv)
  float* zf = (float*)((char*)A2T + (4 << 20));
  u16*  Top = (u16*)((char*)A2T + (size_t)(8 << 20));   // 65 x 1 MiB
  u16*  STc = (u16*)((char*)A2T + (size_t)(76 << 20));  // 2 MiB scratch

  hipMemsetAsync(zpad, 0, 32768, stream);

  // prep
  k_prep_X<<<dim3(1024), 256, 0, stream>>>(u, X);
  k_prep_phis<<<dim3(192), 256, 0, stream>>>(phi, sigma, phis);
  k_prep_W1<<<dim3(13056), 256, 0, stream>>>(Mp, Mm, Mu, W1);
  k_prep_Wtoep<<<dim3(24576), 256, 0, stream>>>(phis, Wtoep);

  // GEMM1: projections (spectral plus/minus + ar_u); 1-D XCD-chunked grid
  {
    GB g{}; g.A = X; g.B = W1; g.A2T = A2T; g.Au = Au; g.zp = zpad;
    g.M = 2048; g.N = 26112;
    g2<0><<<dim3(3264), 256, 0, stream>>>(g);
  }
  // CONV: global Wtoep strips, locality-ordered XCD-chunked grid, splitK=8
  {
    GB g{}; g.A = Wtoep; g.B = A2T; g.Cb = partsBf; g.zp = zpad;
    g.M = 1024; g.N = 512;
    g2<1><<<dim3(1152), 256, 0, stream>>>(g);
  }
  k_combine<<<dim3(512), 256, 0, stream>>>(partsBf, Au, ybf);

  // companion-power stack Top[0..32], then Top[63],Top[64] (= S32^2 halves)
  k_initTop<<<dim3(4096), 256, 0, stream>>>(my, Top);
  {
    const int cs[5] = {1, 2, 4, 8, 16};
    for (int li = 0; li < 5; ++li) {
      int c = cs[li];
      k_transT<<<dim3(16, 16), 256, 0, stream>>>(Top, STc, c);
      GB s{}; s.A = Top + 524288; s.B = STc; s.Cb = Top + (size_t)(c + 1) * 524288;
      s.zp = zpad; s.M = 512; s.N = 1024;
      g2<5><<<dim3(8, 4, c), 256, 0, stream>>>(s);
    }
    // Top[63] = Top[31] * S^32, Top[64] = Top[32] * S^32
    k_transT<<<dim3(16, 16), 256, 0, stream>>>(Top, STc, 32);
    GB s{}; s.A = Top + (size_t)31 * 524288; s.B = STc;
    s.Cb = Top + (size_t)63 * 524288; s.zp = zpad; s.M = 512; s.N = 1024;
    g2<5><<<dim3(8, 4, 2), 256, 0, stream>>>(s);
  }

  // within-chunk solve: z = Tri(H) y; compact triangular grid, 16 slices
  {
    GB g{}; g.A = ybf; g.B = Top; g.Cf = zparts; g.zp = zpad;
    g.M = 2048; g.N = 512;
    g2<2><<<dim3(544), 256, 0, stream>>>(g);
  }
  k_zreduce<<<dim3(4096), 256, 0, stream>>>(zparts, zf);

  // boundary chain: u_c precompute, 15 even steps, batched odd fill
  k_wm<<<dim3(256), 256, 0, stream>>>(zf, Wm);
  {
    GB g{}; g.A = Wm; g.B = Top; g.Cf = ubuf; g.zf = zf; g.zp = zpad;
    g.M = 64; g.N = 1024;
    g2<6><<<dim3(8, 1, 1), 256, 0, stream>>>(g);
  }
  hipMemsetAsync(bnd, 0, 8192, stream);
  hipMemsetAsync(Abnd, 0, 131072, stream);
  for (int k = 0; k < 15; ++k)
    k_bnd2<<<dim3(32), 256, 0, stream>>>(Top, ubuf, bnd, Abnd, k);
  {
    GB g{}; g.A = Abnd; g.B = Top; g.Cb = Abnd; g.zf = zf; g.zp = zpad;
    g.M = 32; g.N = 1024;
    g2<7><<<dim3(8, 1, 1), 256, 0, stream>>>(g);
  }

  // fixup: out = z + [H_{j+1}|G_j] @ Abnd
  {
    GB g{}; g.A = Abnd; g.B = Top; g.zf = zf; g.out = out; g.zp = zpad;
    g.M = 64; g.N = 16384;
    g2<3><<<dim3(128, 1, 1), 256, 0, stream>>>(g);
  }
}

// Round 11
// 702.646 us; speedup vs baseline: 1.2222x; 1.0169x over previous
//
#include <hip/hip_runtime.h>
#include <hip/hip_bf16.h>

// STU forward, R11: GEMM1 widened to 128x256 (512 thr, 8 waves), 4-phase
// transpose epilogue; fused prep + fused zreduce/wm/zero-init.
// Sizes: B=2, L=1024, K=24(x2), D=512, K_U=3, K_Y=2.

typedef unsigned short u16;
typedef __attribute__((ext_vector_type(8))) short  vshort8;
typedef __attribute__((ext_vector_type(4))) short  vshort4;
typedef __attribute__((ext_vector_type(4))) float  f32x4;
typedef __attribute__((ext_vector_type(4))) unsigned int vuint4;

__device__ __forceinline__ u16 f2b(float x) {
  __hip_bfloat16 h = __float2bfloat16(x);
  return __builtin_bit_cast(u16, h);
}
__device__ __forceinline__ float b2f(u16 x) {
  unsigned int u = ((unsigned int)x) << 16;
  return __builtin_bit_cast(float, u);
}

// async global->LDS, 16B per lane; LDS dest = wave-uniform base + lane*16
__device__ __forceinline__ void gll16(const u16* g, u16* l) {
  __builtin_amdgcn_global_load_lds((__attribute__((address_space(1))) void*)g,
                                   (__attribute__((address_space(3))) void*)l,
                                   16, 0, 0);
}

// ---------------------------------------------------------------------------
// Shared MFMA GEMM template. C[m,n] = sum_k A[m,k]*Bmat[n,k].
//  V0 GEMM1: 128x256 tile, 512 thr; A=X(2048x512) B=W1(26112x512); grid 1632
//  V1 CONV : A=Wtoep strip (d=bm-cj), B=A2T; 1-D grid 1152, splitK=8
//  V2 ZGEMM: A=gather(ybf), B=Top; 1-D grid 544 triangular, 16 slices
//  V3 FIXUP: A=Abnd(64x1024), B=Top[j+1] rows -> out = acc + zf
//  V5 SGEMM: A=Top[*+bz] (512x1024), B=STc -> Top[*+bz] bf16 (batched)
//  V6 UGEMM: A=Wm(64x1024), B=S32 rows -> ubuf = acc + w_{c+1} (f32)
//  V7 ODD  : A=Abnd even rows, B=S32 rows -> Abnd odd rows = acc + w_{2k}
// ---------------------------------------------------------------------------
struct GB {
  const u16* A; const u16* B;
  float* Cf; u16* Cb;
  const float* zf; float* out;
  u16* A2T; u16* Au;
  const u16* zp;
  int M, N;
};

template<int V>
__global__ __launch_bounds__(V == 0 ? 512 : 256) void g2(GB a) {
  const int tid = threadIdx.x;
  int bn = blockIdx.x, bm = blockIdx.y;
  int zz = blockIdx.z;
  int cj = 0, cb = 0, cd = 0, slot = 0;
  int kbeg = 0, kend = 0;
  if (V == 0) {
    int f = blockIdx.x;
    int o = (f & 7) * 204 + (f >> 3);          // 1632 = 8 x 204
    bm = o & 15; bn = o >> 4; kend = 512;
  }
  if (V == 1) {
    int f = blockIdx.x;
    int o = (f & 7) * 144 + (f >> 3);          // 1152 = 8 x 144
    const int offs1[8] = {0, 256, 480, 672, 832, 960, 1056, 1120};
    cj = 0;
    if (o >= offs1[1]) cj = 1;
    if (o >= offs1[2]) cj = 2;
    if (o >= offs1[3]) cj = 3;
    if (o >= offs1[4]) cj = 4;
    if (o >= offs1[5]) cj = 5;
    if (o >= offs1[6]) cj = 6;
    if (o >= offs1[7]) cj = 7;
    int r = o - offs1[cj];
    int run = 8 - cj;
    int combo = r / run;                       // [0,32): (zzc, bn)
    bm = cj + (r - combo * run);
    int zzc = combo >> 2; bn = combo & 3;
    cb = zzc & 1; cd = bm - cj;
    slot = zzc * 8 + cj;
    kbeg = (zzc >> 1) * 1536; kend = kbeg + 1536;
  }
  if (V == 2) {
    int f = blockIdx.x;
    int o = (f & 7) * 68 + (f >> 3);           // 544 = 8 x 68
    const int offs2[16] = {0, 64, 124, 180, 232, 280, 324, 364,
                           400, 432, 460, 484, 504, 520, 532, 540};
    int s = 0;
#pragma unroll
    for (int c = 1; c < 16; ++c)
      if (o >= offs2[c]) s = c;
    int r = o - offs2[s];
    bm = s + (r >> 2); bn = r & 3;
    zz = s;
    kbeg = s * 1024; kend = kbeg + 1024;       // s<=bm guarantees validity
  }
  const int m0 = bm * 128;
  const int n0 = (V == 0) ? bn * 256 : bn * 128;
  if (V == 3 || V == 5 || V == 6 || V == 7) kend = 1024;

  __shared__ u16 smem[V == 0 ? 24576 : 16384];
  // V0: lA[2][4096] @0, lB[2][8192] @8192 ; others: lA[2][4096]@0, lB[2][4096]@8192
  f32x4 acc[4][4];
#pragma unroll
  for (int i = 0; i < 4; i++)
#pragma unroll
    for (int j = 0; j < 4; j++) acc[i][j] = f32x4{0.f, 0.f, 0.f, 0.f};

  const int lane = tid & 63, wv = tid >> 6;
  const int wr = (V == 0) ? (wv >> 2) : (wv >> 1);
  const int wc = (V == 0) ? (wv & 3) : (wv & 1);
  const u16* Ap = a.A;
  if (V == 5) Ap = a.A + (size_t)zz * 524288;
  const u16* zpl = a.zp + lane * 8;

  auto gaddrA = [&](int it, int k0) -> const u16* {
    int lrow = (it * 4 + wv) * 16 + (lane & 15);
    int kk = k0 + ((lane >> 4) << 3);
    if (V == 1) return Ap + (size_t)cd * 786432 + (size_t)lrow * 6144 + kk;
    if (V == 2) {
      int m = m0 + lrow, j = m >> 6, b = (m >> 5) & 1, c = m & 31;
      int tau = kk >> 9, p = kk & 511;
      if (tau > j) return zpl;
      return Ap + (size_t)(b * 1024 + c * 32 + j - tau) * 512 + p;
    }
    if (V == 3) { int m = m0 + lrow; return (m < a.M) ? Ap + (size_t)m * 1024 + kk : zpl; }
    if (V == 5) return Ap + (size_t)(m0 + lrow) * 1024 + kk;
    if (V == 6) return (lrow < 64) ? Ap + (size_t)lrow * 1024 + kk : zpl;
    // V7
    if (lrow < 32) {
      int b = lrow & 1, k2 = lrow >> 1;
      return Ap + (size_t)(b * 32 + 2 * k2) * 1024 + kk;
    }
    return zpl;
  };
  auto gaddrB = [&](int it, int k0) -> const u16* {
    int lrow = (it * 4 + wv) * 16 + (lane & 15);
    int kk = k0 + ((lane >> 4) << 3);
    int n = n0 + lrow;
    if (V == 1) {
      int kh = kk >> 7, sp = kk & 127;
      return a.B + (size_t)(cb * 512 + n) * 49152 + kh * 1024 + cj * 128 + sp;
    }
    if (V == 2) {
      int tau = kk >> 9, p = kk & 511;
      return a.B + (size_t)tau * 524288 + (size_t)n * 1024 + p;
    }
    if (V == 3) {
      int jn = n >> 9, o = n & 511;
      return a.B + (size_t)(jn + 1) * 524288 + (size_t)o * 1024 + kk;
    }
    if (V == 5) return a.B + (size_t)n * 1024 + kk;
    // V6/V7: rows of S32 = [Top32 ; Top31]
    return (n < 512)
        ? a.B + (size_t)32 * 524288 + (size_t)n * 1024 + kk
        : a.B + (size_t)31 * 524288 + (size_t)(n - 512) * 1024 + kk;
  };

  auto stage = [&](int c, int k0) {
    if (V == 0) {
      int kk = k0 + ((lane >> 4) << 3);
      int lrowA = wv * 16 + (lane & 15);
      gll16(Ap + (size_t)(m0 + lrowA) * 512 + kk, smem + c * 4096 + wv * 512);
#pragma unroll
      for (int it = 0; it < 2; ++it) {
        int lrowB = (it * 8 + wv) * 16 + (lane & 15);
        gll16(a.B + (size_t)(n0 + lrowB) * 512 + kk,
              smem + 8192 + c * 8192 + (it * 8 + wv) * 512);
      }
    } else {
#pragma unroll
      for (int it = 0; it < 2; ++it) {
        int weff = wv + it * 4;
        gll16(gaddrA(it, k0), smem + c * 4096 + weff * 512);
        gll16(gaddrB(it, k0), smem + 8192 + c * 4096 + weff * 512);
      }
    }
  };

  if (kbeg < kend) stage(0, kbeg);
  __syncthreads();                 // drains the prologue stage
  int cur = 0;
  for (int k0 = kbeg; k0 < kend; k0 += 32) {
    if (k0 + 32 < kend) stage(cur ^ 1, k0 + 32);   // async prefetch next tile
    vshort8 af[4], bf_[4];
#pragma unroll
    for (int s = 0; s < 4; s++) {
      af[s] = *(const vshort8*)&smem[cur * 4096 +
                (((wr * 4 + s) * 4 + (lane >> 4)) * 16 + (lane & 15)) * 8];
      if (V == 0)
        bf_[s] = *(const vshort8*)&smem[8192 + cur * 8192 +
                  (((wc * 4 + s) * 4 + (lane >> 4)) * 16 + (lane & 15)) * 8];
      else
        bf_[s] = *(const vshort8*)&smem[8192 + cur * 4096 +
                  (((wc * 4 + s) * 4 + (lane >> 4)) * 16 + (lane & 15)) * 8];
    }
#pragma unroll
    for (int i = 0; i < 4; i++)
#pragma unroll
      for (int j = 0; j < 4; j++)
        acc[i][j] = __builtin_amdgcn_mfma_f32_16x16x32_bf16(af[i], bf_[j], acc[i][j], 0, 0, 0);
    __syncthreads();               // drains prefetch + protects buffer swap
    cur ^= 1;
  }

  // ---- epilogue ----
  if (V == 0 && bn < 96) {
    // 4 phases; phase p handles n-cols [n0+p*64, n0+p*64+64) via LDS transpose
    const int strd = 136;
    const int b = m0 >> 10;
#pragma unroll
    for (int p = 0; p < 4; ++p) {
      __syncthreads();
      if (wc == p) {
#pragma unroll
        for (int i = 0; i < 4; i++) {
#pragma unroll
          for (int j = 0; j < 4; j++) {
            f32x4 v = acc[i][j];
            int mloc = wr * 64 + i * 16 + ((lane >> 4) << 2);
            int phys = j * 16 + (lane & 15);
            vshort4 pk = { (short)f2b(v[0]), (short)f2b(v[1]),
                           (short)f2b(v[2]), (short)f2b(v[3]) };
            *(vshort4*)&smem[phys * strd + mloc] = pk;
          }
        }
      }
      __syncthreads();
      int rowp = tid >> 3, t8 = tid & 7;
      int n = n0 + p * 64 + rowp;
      int o = n & 511, kh = n >> 9;
      int sbase = (m0 & 1023) + t8 * 16;
      u16* dst = a.A2T + (size_t)(b * 512 + o) * 49152 + (size_t)kh * 1024 + sbase;
      const u16* srcl = &smem[rowp * strd + t8 * 16];
      *(vuint4*)(dst)     = *(const vuint4*)(srcl);
      *(vuint4*)(dst + 8) = *(const vuint4*)(srcl + 8);
    }
    return;
  }

#pragma unroll
  for (int i = 0; i < 4; i++) {
    int em = m0 + wr * 64 + i * 16 + ((lane >> 4) << 2);
#pragma unroll
    for (int j = 0; j < 4; j++) {
      int n = n0 + wc * 64 + j * 16 + (lane & 15);
      f32x4 v = acc[i][j];
      if (V == 0) {
        int b = em >> 10, s = em & 1023;
        int jj = (n - 24576) >> 9, o = n & 511;
#pragma unroll
        for (int t = 0; t < 4; t++)
          a.Au[((size_t)(b * 3 + jj) * 1024 + (s + t)) * 512 + o] = f2b(v[t]);
      } else if (V == 1) {
        u16* C = a.Cb + (size_t)slot * 524288;
#pragma unroll
        for (int t = 0; t < 4; t++) C[(size_t)(em + t) * 512 + n] = f2b(v[t]);
      } else if (V == 2) {
        float* C = a.Cf + (size_t)zz * 1048576;
#pragma unroll
        for (int t = 0; t < 4; t++) C[(size_t)(em + t) * 512 + n] = v[t];
      } else if (V == 3) {
        int jj = n >> 9, oo = n & 511;
#pragma unroll
        for (int t = 0; t < 4; t++) {
          int m = em + t;
          if (m < a.M) {
            int b = m >> 5, c = m & 31;
            float zv = a.zf[(size_t)(jj * 64 + b * 32 + c) * 512 + oo];
            a.out[(size_t)b * 524288 + (size_t)(c * 32 + jj) * 512 + oo] = v[t] + zv;
          }
        }
      } else if (V == 5) {
        u16* C = a.Cb + (size_t)zz * 524288;
#pragma unroll
        for (int t = 0; t < 4; t++) C[(size_t)(em + t) * 1024 + n] = f2b(v[t]);
      } else if (V == 6) {
        int jrow = (n < 512) ? 31 : 30, oo = n & 511;
#pragma unroll
        for (int t = 0; t < 4; t++) {
          int m = em + t;
          if (m < 62) {
            int b = m & 1, c = m >> 1;
            a.Cf[(size_t)m * 1024 + n] =
                v[t] + a.zf[(size_t)(jrow * 64 + b * 32 + (c + 1)) * 512 + oo];
          }
        }
      } else { // V7: odd states
        int jrow = (n < 512) ? 31 : 30, oo = n & 511;
#pragma unroll
        for (int t = 0; t < 4; t++) {
          int m = em + t;
          if (m < 32) {
            int b = m & 1, k2 = m >> 1;
            float val = v[t] + a.zf[(size_t)(jrow * 64 + b * 32 + 2 * k2) * 512 + oo];
            a.Cb[(size_t)(b * 32 + 2 * k2 + 1) * 1024 + n] = f2b(val);
          }
        }
      }
    }
  }
}

// ---------------------------------------------------------------------------
// prep / glue kernels
// ---------------------------------------------------------------------------
// phis[tau*48 + kf]: kf<24 -> phi_s[tau,kf]; kf>=24 -> phi_s[tau,kf-24]*(-1)^tau
__global__ void k_prep_phis(const float* __restrict__ phi, const float* __restrict__ sigma,
                            float* __restrict__ phis) {
  int i = blockIdx.x * 256 + threadIdx.x;
  if (i >= 1024 * 48) return;
  int tau = i / 48, kf = i % 48, k = (kf >= 24) ? kf - 24 : kf;
  float v = phi[tau * 24 + k] * powf(sigma[k], 0.25f);
  if (kf >= 24 && (tau & 1)) v = -v;
  phis[i] = v;
}

// fused: X convert (vec4), W1 convert (vec4 x4 rounds), Wtoep build (vec8)
__global__ void k_prep_all(const float* __restrict__ u, const float* __restrict__ Mp,
                           const float* __restrict__ Mm, const float* __restrict__ Mu,
                           const float* __restrict__ phis,
                           u16* __restrict__ X, u16* __restrict__ W1,
                           u16* __restrict__ Wtoep) {
  int gid = blockIdx.x * 256 + threadIdx.x;   // [0, 1048576)
  if (gid < 262144) {
    int i4 = gid * 4;
    f32x4 v = *(const f32x4*)(u + i4);
    vshort4 pk = { (short)f2b(v[0]), (short)f2b(v[1]), (short)f2b(v[2]), (short)f2b(v[3]) };
    *(vshort4*)(X + i4) = pk;
  }
#pragma unroll
  for (int r = 0; r < 4; ++r) {
    int item = gid + r * 1048576;
    if (item < 3342336) {
      int i4 = item * 4;
      const float* src; int off;
      if (i4 < 6291456) { src = Mp; off = i4; }
      else if (i4 < 12582912) { src = Mm; off = i4 - 6291456; }
      else { src = Mu; off = i4 - 12582912; }
      f32x4 v = *(const f32x4*)(src + off);
      vshort4 pk = { (short)f2b(v[0]), (short)f2b(v[1]), (short)f2b(v[2]), (short)f2b(v[3]) };
      *(vshort4*)(W1 + i4) = pk;
    }
  }
  if (gid < 786432) {
    int i = gid * 8;
    int kap = i % 6144, row = i / 6144;
    int tp = row & 127, d = row >> 7;
    int kh = kap >> 7, sp = kap & 127;
    int tau0 = d * 128 + tp - sp;
    u16 vals[8];
#pragma unroll
    for (int e = 0; e < 8; ++e) {
      int tau = tau0 - e;
      vals[e] = (tau >= 0 && tau < 1024) ? f2b(phis[tau * 48 + kh]) : (u16)0;
    }
    *(vuint4*)(Wtoep + i) = *(const vuint4*)vals;
  }
}

// Top[0]=[I|0], Top[1]=[M1|M2]
__global__ void k_initTop(const float* __restrict__ my, u16* __restrict__ Top) {
  int i = blockIdx.x * 256 + threadIdx.x;
  if (i >= 1048576) return;
  int mat = i >> 19, rem = i & 524287, o = rem >> 10, k = rem & 1023;
  u16 v;
  if (mat == 0) v = (k == o) ? (u16)0x3F80 : (u16)0;
  else v = (k < 512) ? f2b(my[o * 512 + k]) : f2b(my[262144 + o * 512 + (k - 512)]);
  Top[i] = v;
}

// STc[n][k] = S^c[k][n];  S^c = [Top[c]; Top[c-1]]  (tiled transpose)
__global__ __launch_bounds__(256) void k_transT(const u16* __restrict__ Top,
                                                u16* __restrict__ STc, int c) {
  __shared__ u16 tile[64][72];
  int tx = blockIdx.x, ty = blockIdx.y;  // n-tile, k-tile
  int tid = threadIdx.x;
  int r = tid >> 2, seg = tid & 3;
  int k = ty * 64 + r;
  const u16* src = (k < 512) ? Top + (size_t)c * 524288 + (size_t)k * 1024 + tx * 64
                             : Top + (size_t)(c - 1) * 524288 + (size_t)(k - 512) * 1024 + tx * 64;
  *(vuint4*)&tile[r][seg * 16]     = *(const vuint4*)(src + seg * 16);
  *(vuint4*)&tile[r][seg * 16 + 8] = *(const vuint4*)(src + seg * 16 + 8);
  __syncthreads();
  int n = tx * 64 + r;
  u16 tmp[16];
#pragma unroll
  for (int j = 0; j < 16; j++) tmp[j] = tile[seg * 16 + j][r];
  *(vuint4*)&STc[(size_t)n * 1024 + ty * 64 + seg * 16]     = *(vuint4*)&tmp[0];
  *(vuint4*)&STc[(size_t)n * 1024 + ty * 64 + seg * 16 + 8] = *(vuint4*)&tmp[8];
}

__device__ __forceinline__ void addp(float* acc, vuint4 v) {
  const unsigned int* vu = (const unsigned int*)&v;
#pragma unroll
  for (int e = 0; e < 4; ++e) {
    unsigned int pw = vu[e];
    acc[2 * e]     += __builtin_bit_cast(float, (pw & 0xffffu) << 16);
    acc[2 * e + 1] += __builtin_bit_cast(float, pw & 0xffff0000u);
  }
}

// ybf[b,t,og*8..] = sum_j Au[b,j,t-j,:] + (t>=2 ? valid bf16 conv partials : 0)
__global__ void k_combine(const u16* __restrict__ parts, const u16* __restrict__ Au,
                          u16* __restrict__ ybf) {
  int i = blockIdx.x * 256 + threadIdx.x;
  if (i >= 131072) return;
  int og = i & 63, t = (i >> 6) & 1023, b = i >> 16;
  float acc[8];
#pragma unroll
  for (int e = 0; e < 8; ++e) acc[e] = 0.f;
#pragma unroll
  for (int j = 0; j < 3; j++)
    if (t >= j)
      addp(acc, *(const vuint4*)(Au + ((size_t)(b * 3 + j) * 1024 + (t - j)) * 512 + og * 8));
  if (t >= 2) {
    int tp = t - 2, bmv = tp >> 7;
#pragma unroll
    for (int g = 0; g < 8; ++g) {
      if ((g & 1) != b) continue;
      const u16* base = parts + (size_t)(g * 8) * 524288 + (size_t)tp * 512 + og * 8;
      for (int j = 0; j <= bmv; ++j)
        addp(acc, *(const vuint4*)(base + (size_t)j * 524288));
    }
  }
  u16 o16[8];
#pragma unroll
  for (int e = 0; e < 8; ++e) o16[e] = f2b(acc[e]);
  *(vuint4*)(ybf + ((size_t)(b * 1024 + t)) * 512 + og * 8) = *(vuint4*)o16;
}

// fused: zf reduce + Wm extraction + bnd/Abnd zero-init
__global__ void k_zred(const float* __restrict__ zp, float* __restrict__ z,
                       u16* __restrict__ Wm, float* __restrict__ bnd,
                       u16* __restrict__ Abnd) {
  int i = blockIdx.x * 256 + threadIdx.x;
  if (i < 2048) bnd[i] = 0.f;
  if (i < 1024) { Abnd[i] = 0; Abnd[32768 + i] = 0; }
  if (i >= 1048576) return;
  int nsum = (i >> 16) + 1;        // bm = i>>16 in [0,16)
  float s = 0.f;
  for (int j = 0; j < nsum; ++j) s += zp[(size_t)j * 1048576 + i];
  z[i] = s;
  int m = i >> 9, jj = m >> 6, rem = m & 63, b = rem >> 5, c = rem & 31, oo = i & 511;
  if (jj == 31) Wm[(size_t)((c << 1) | b) * 1024 + oo] = f2b(s);
  if (jj == 30) Wm[(size_t)((c << 1) | b) * 1024 + 512 + oo] = f2b(s);
}

// even chain step k: E_{k+1} = S64 E_k + u_{2k}; emit Abnd row (b*32+2k+2)
__global__ __launch_bounds__(256) void k_bnd2(const u16* __restrict__ Top,
                                              const float* __restrict__ ubuf,
                                              float* __restrict__ bnd,
                                              u16* __restrict__ Abnd, int k) {
  __shared__ float st[2048];
  int tid = threadIdx.x;
  const float* s0 = bnd + (size_t)k * 2048;
  for (int j = tid; j < 2048; j += 256) st[j] = s0[j];
  __syncthreads();
  int q4 = blockIdx.x * 256 + tid;  // [0,8192)
  int q = q4 >> 2, quarter = q4 & 3;
  int b = q >> 10, kk = q & 1023;
  const u16* row = (kk < 512) ? Top + (size_t)64 * 524288 + (size_t)kk * 1024
                              : Top + (size_t)63 * 524288 + (size_t)(kk - 512) * 1024;
  const float* stb = st + b * 1024 + quarter * 256;
  const u16* rp = row + quarter * 256;
  float sum = 0.f;
  for (int t = 0; t < 32; ++t) {
    vuint4 v = *(const vuint4*)(rp + t * 8);
    const unsigned int* vu = (const unsigned int*)&v;
#pragma unroll
    for (int e = 0; e < 4; ++e) {
      unsigned int pw = vu[e];
      float lo = __builtin_bit_cast(float, (pw & 0xffffu) << 16);
      float hi = __builtin_bit_cast(float, pw & 0xffff0000u);
      sum += lo * stb[t * 8 + e * 2] + hi * stb[t * 8 + e * 2 + 1];
    }
  }
  sum += __shfl_xor(sum, 1);
  sum += __shfl_xor(sum, 2);
  if (quarter == 0) {
    float s = sum + ubuf[(size_t)(4 * k + b) * 1024 + kk];
    bnd[(size_t)(k + 1) * 2048 + b * 1024 + kk] = s;
    Abnd[(size_t)(b * 32 + 2 * k + 2) * 1024 + kk] = f2b(s);
  }
}

// ---------------------------------------------------------------------------
extern "C" void kernel_launch(void* const* d_in, const int* in_sizes, int n_in,
                              void* d_out, int out_size, void* d_ws, size_t ws_size,
                              hipStream_t stream) {
  const float* u     = (const float*)d_in[0];
  const float* Mu    = (const float*)d_in[1];
  const float* Mp    = (const float*)d_in[2];
  const float* Mm    = (const float*)d_in[3];
  const float* my    = (const float*)d_in[4];
  const float* sigma = (const float*)d_in[5];
  const float* phi   = (const float*)d_in[6];
  float* out = (float*)d_out;

  char* ws = (char*)d_ws;
  size_t off = 0;
  auto alc = [&](size_t b) { size_t p = off; off = (off + b + 255) & ~(size_t)255; return p; };
  u16*  X     = (u16*)(ws + alc(2097152));
  u16*  Wtoep = (u16*)(ws + alc(12582912));    // 8 d x 128 x 6144
  u16*  A2T   = (u16*)(ws + alc(100663296));   // (b,o)[48 kh][1024 s]
  u16*  Au    = (u16*)(ws + alc(6291456));
  u16*  W1    = (u16*)(ws + alc(26738688));    // 26112x512; parts region spans W1+tail
  char* ptail = ws + alc(40370176); (void)ptail; // W1+tail = 64 MiB exactly
  float* phis = (float*)(ws + alc(196608));    // [1024 tau][48 kf] f32
  float* bnd  = (float*)(ws + alc(131072));    // 16 even states x 2048 f32
  u16*  Abnd  = (u16*)(ws + alc(131072));      // 64 x 1024 bf16 boundary states
  u16*  Wm    = (u16*)(ws + alc(131072));      // 64 x 1024 bf16 w_c
  float* ubuf = (float*)(ws + alc(262144));    // 64 x 1024 f32 u_c
  u16*  zpad  = (u16*)(ws + alc(32768));       // zero page for predicated lanes
  if (off > ws_size) return;
  // lifetime-disjoint aliases:
  u16*  partsBf = (u16*)W1;                    // 64 conv slots x [1024][512] bf16 = 64 MiB
  float* zparts = (float*)W1;                  // 16 zgemm slots x 4 MiB f32 = 64 MiB
  u16*  ybf = A2T;                             // 2 MiB (after conv)
  float* zf = (float*)((char*)A2T + (4 << 20));
  u16*  Top = (u16*)((char*)A2T + (size_t)(8 << 20));   // 65 x 1 MiB
  u16*  STc = (u16*)((char*)A2T + (size_t)(76 << 20));  // 2 MiB scratch

  hipMemsetAsync(zpad, 0, 32768, stream);

  // prep
  k_prep_phis<<<dim3(192), 256, 0, stream>>>(phi, sigma, phis);
  k_prep_all<<<dim3(4096), 256, 0, stream>>>(u, Mp, Mm, Mu, phis, X, W1, Wtoep);

  // GEMM1: projections; 128x256 tile, 512 threads, 1-D XCD-chunked grid
  {
    GB g{}; g.A = X; g.B = W1; g.A2T = A2T; g.Au = Au; g.zp = zpad;
    g.M = 2048; g.N = 26112;
    g2<0><<<dim3(1632), 512, 0, stream>>>(g);
  }
  // CONV: global Wtoep strips, locality-ordered XCD-chunked grid, splitK=8
  {
    GB g{}; g.A = Wtoep; g.B = A2T; g.Cb = partsBf; g.zp = zpad;
    g.M = 1024; g.N = 512;
    g2<1><<<dim3(1152), 256, 0, stream>>>(g);
  }
  k_combine<<<dim3(512), 256, 0, stream>>>(partsBf, Au, ybf);

  // companion-power stack Top[0..32], then Top[63],Top[64] (= S32^2 halves)
  k_initTop<<<dim3(4096), 256, 0, stream>>>(my, Top);
  {
    const int cs[5] = {1, 2, 4, 8, 16};
    for (int li = 0; li < 5; ++li) {
      int c = cs[li];
      k_transT<<<dim3(16, 16), 256, 0, stream>>>(Top, STc, c);
      GB s{}; s.A = Top + 524288; s.B = STc; s.Cb = Top + (size_t)(c + 1) * 524288;
      s.zp = zpad; s.M = 512; s.N = 1024;
      g2<5><<<dim3(8, 4, c), 256, 0, stream>>>(s);
    }
    // Top[63] = Top[31] * S^32, Top[64] = Top[32] * S^32
    k_transT<<<dim3(16, 16), 256, 0, stream>>>(Top, STc, 32);
    GB s{}; s.A = Top + (size_t)31 * 524288; s.B = STc;
    s.Cb = Top + (size_t)63 * 524288; s.zp = zpad; s.M = 512; s.N = 1024;
    g2<5><<<dim3(8, 4, 2), 256, 0, stream>>>(s);
  }

  // within-chunk solve: z = Tri(H) y; compact triangular grid, 16 slices
  {
    GB g{}; g.A = ybf; g.B = Top; g.Cf = zparts; g.zp = zpad;
    g.M = 2048; g.N = 512;
    g2<2><<<dim3(544), 256, 0, stream>>>(g);
  }
  k_zred<<<dim3(4096), 256, 0, stream>>>(zparts, zf, Wm, bnd, Abnd);

  // boundary chain: u_c precompute, 15 even steps, batched odd fill
  {
    GB g{}; g.A = Wm; g.B = Top; g.Cf = ubuf; g.zf = zf; g.zp = zpad;
    g.M = 64; g.N = 1024;
    g2<6><<<dim3(8, 1, 1), 256, 0, stream>>>(g);
  }
  for (int k = 0; k < 15; ++k)
    k_bnd2<<<dim3(32), 256, 0, stream>>>(Top, ubuf, bnd, Abnd, k);
  {
    GB g{}; g.A = Abnd; g.B = Top; g.Cb = Abnd; g.zf = zf; g.zp = zpad;
    g.M = 32; g.N = 1024;
    g2<7><<<dim3(8, 1, 1), 256, 0, stream>>>(g);
  }

  // fixup: out = z + [H_{j+1}|G_j] @ Abnd
  {
    GB g{}; g.A = Abnd; g.B = Top; g.zf = zf; g.out = out; g.zp = zpad;
    g.M = 64; g.N = 16384;
    g2<3><<<dim3(128, 1, 1), 256, 0, stream>>>(g);
  }
}

// Round 12
// 700.019 us; speedup vs baseline: 1.2268x; 1.0038x over previous
//
#include <hip/hip_runtime.h>
#include <hip/hip_bf16.h>

// STU forward, R12: A2T relayout [b][cj][kh][o][sp] -> GEMM1 writes 64KB
// contiguous per block; conv reads compact stripes. Otherwise identical R11.
// Sizes: B=2, L=1024, K=24(x2), D=512, K_U=3, K_Y=2.

typedef unsigned short u16;
typedef __attribute__((ext_vector_type(8))) short  vshort8;
typedef __attribute__((ext_vector_type(4))) short  vshort4;
typedef __attribute__((ext_vector_type(4))) float  f32x4;
typedef __attribute__((ext_vector_type(4))) unsigned int vuint4;

__device__ __forceinline__ u16 f2b(float x) {
  __hip_bfloat16 h = __float2bfloat16(x);
  return __builtin_bit_cast(u16, h);
}
__device__ __forceinline__ float b2f(u16 x) {
  unsigned int u = ((unsigned int)x) << 16;
  return __builtin_bit_cast(float, u);
}

// async global->LDS, 16B per lane; LDS dest = wave-uniform base + lane*16
__device__ __forceinline__ void gll16(const u16* g, u16* l) {
  __builtin_amdgcn_global_load_lds((__attribute__((address_space(1))) void*)g,
                                   (__attribute__((address_space(3))) void*)l,
                                   16, 0, 0);
}

// A2T layout strides: [b:2][cj:8][kh:48][o:512][sp:128]
#define A2T_B  25165824
#define A2T_CJ 3145728
#define A2T_KH 65536

// ---------------------------------------------------------------------------
// Shared MFMA GEMM template. C[m,n] = sum_k A[m,k]*Bmat[n,k].
//  V0 GEMM1: 128x256 tile, 512 thr; A=X(2048x512) B=W1(26112x512); grid 1632
//  V1 CONV : A=Wtoep strip (d=bm-cj), B=A2T; 1-D grid 1152, splitK=8
//  V2 ZGEMM: A=gather(ybf), B=Top; 1-D grid 544 triangular, 16 slices
//  V3 FIXUP: A=Abnd(64x1024), B=Top[j+1] rows -> out = acc + zf
//  V5 SGEMM: A=Top[*+bz] (512x1024), B=STc -> Top[*+bz] bf16 (batched)
//  V6 UGEMM: A=Wm(64x1024), B=S32 rows -> ubuf = acc + w_{c+1} (f32)
//  V7 ODD  : A=Abnd even rows, B=S32 rows -> Abnd odd rows = acc + w_{2k}
// ---------------------------------------------------------------------------
struct GB {
  const u16* A; const u16* B;
  float* Cf; u16* Cb;
  const float* zf; float* out;
  u16* A2T; u16* Au;
  const u16* zp;
  int M, N;
};

template<int V>
__global__ __launch_bounds__(V == 0 ? 512 : 256) void g2(GB a) {
  const int tid = threadIdx.x;
  int bn = blockIdx.x, bm = blockIdx.y;
  int zz = blockIdx.z;
  int cj = 0, cb = 0, cd = 0, slot = 0;
  int kbeg = 0, kend = 0;
  if (V == 0) {
    int f = blockIdx.x;
    int o = (f & 7) * 204 + (f >> 3);          // 1632 = 8 x 204
    bm = o & 15; bn = o >> 4; kend = 512;
  }
  if (V == 1) {
    int f = blockIdx.x;
    int o = (f & 7) * 144 + (f >> 3);          // 1152 = 8 x 144
    const int offs1[8] = {0, 256, 480, 672, 832, 960, 1056, 1120};
    cj = 0;
    if (o >= offs1[1]) cj = 1;
    if (o >= offs1[2]) cj = 2;
    if (o >= offs1[3]) cj = 3;
    if (o >= offs1[4]) cj = 4;
    if (o >= offs1[5]) cj = 5;
    if (o >= offs1[6]) cj = 6;
    if (o >= offs1[7]) cj = 7;
    int r = o - offs1[cj];
    int run = 8 - cj;
    int combo = r / run;                       // [0,32): (zzc, bn)
    bm = cj + (r - combo * run);
    int zzc = combo >> 2; bn = combo & 3;
    cb = zzc & 1; cd = bm - cj;
    slot = zzc * 8 + cj;
    kbeg = (zzc >> 1) * 1536; kend = kbeg + 1536;
  }
  if (V == 2) {
    int f = blockIdx.x;
    int o = (f & 7) * 68 + (f >> 3);           // 544 = 8 x 68
    const int offs2[16] = {0, 64, 124, 180, 232, 280, 324, 364,
                           400, 432, 460, 484, 504, 520, 532, 540};
    int s = 0;
#pragma unroll
    for (int c = 1; c < 16; ++c)
      if (o >= offs2[c]) s = c;
    int r = o - offs2[s];
    bm = s + (r >> 2); bn = r & 3;
    zz = s;
    kbeg = s * 1024; kend = kbeg + 1024;       // s<=bm guarantees validity
  }
  const int m0 = bm * 128;
  const int n0 = (V == 0) ? bn * 256 : bn * 128;
  if (V == 3 || V == 5 || V == 6 || V == 7) kend = 1024;

  __shared__ u16 smem[V == 0 ? 24576 : 16384];
  f32x4 acc[4][4];
#pragma unroll
  for (int i = 0; i < 4; i++)
#pragma unroll
    for (int j = 0; j < 4; j++) acc[i][j] = f32x4{0.f, 0.f, 0.f, 0.f};

  const int lane = tid & 63, wv = tid >> 6;
  const int wr = (V == 0) ? (wv >> 2) : (wv >> 1);
  const int wc = (V == 0) ? (wv & 3) : (wv & 1);
  const u16* Ap = a.A;
  if (V == 5) Ap = a.A + (size_t)zz * 524288;
  const u16* zpl = a.zp + lane * 8;

  auto gaddrA = [&](int it, int k0) -> const u16* {
    int lrow = (it * 4 + wv) * 16 + (lane & 15);
    int kk = k0 + ((lane >> 4) << 3);
    if (V == 1) return Ap + (size_t)cd * 786432 + (size_t)lrow * 6144 + kk;
    if (V == 2) {
      int m = m0 + lrow, j = m >> 6, b = (m >> 5) & 1, c = m & 31;
      int tau = kk >> 9, p = kk & 511;
      if (tau > j) return zpl;
      return Ap + (size_t)(b * 1024 + c * 32 + j - tau) * 512 + p;
    }
    if (V == 3) { int m = m0 + lrow; return (m < a.M) ? Ap + (size_t)m * 1024 + kk : zpl; }
    if (V == 5) return Ap + (size_t)(m0 + lrow) * 1024 + kk;
    if (V == 6) return (lrow < 64) ? Ap + (size_t)lrow * 1024 + kk : zpl;
    // V7
    if (lrow < 32) {
      int b = lrow & 1, k2 = lrow >> 1;
      return Ap + (size_t)(b * 32 + 2 * k2) * 1024 + kk;
    }
    return zpl;
  };
  auto gaddrB = [&](int it, int k0) -> const u16* {
    int lrow = (it * 4 + wv) * 16 + (lane & 15);
    int kk = k0 + ((lane >> 4) << 3);
    int n = n0 + lrow;
    if (V == 1) {
      int kh = kk >> 7, sp = kk & 127;
      return a.B + (size_t)cb * A2T_B + (size_t)cj * A2T_CJ
           + (size_t)kh * A2T_KH + (size_t)n * 128 + sp;
    }
    if (V == 2) {
      int tau = kk >> 9, p = kk & 511;
      return a.B + (size_t)tau * 524288 + (size_t)n * 1024 + p;
    }
    if (V == 3) {
      int jn = n >> 9, o = n & 511;
      return a.B + (size_t)(jn + 1) * 524288 + (size_t)o * 1024 + kk;
    }
    if (V == 5) return a.B + (size_t)n * 1024 + kk;
    // V6/V7: rows of S32 = [Top32 ; Top31]
    return (n < 512)
        ? a.B + (size_t)32 * 524288 + (size_t)n * 1024 + kk
        : a.B + (size_t)31 * 524288 + (size_t)(n - 512) * 1024 + kk;
  };

  auto stage = [&](int c, int k0) {
    if (V == 0) {
      int kk = k0 + ((lane >> 4) << 3);
      int lrowA = wv * 16 + (lane & 15);
      gll16(Ap + (size_t)(m0 + lrowA) * 512 + kk, smem + c * 4096 + wv * 512);
#pragma unroll
      for (int it = 0; it < 2; ++it) {
        int lrowB = (it * 8 + wv) * 16 + (lane & 15);
        gll16(a.B + (size_t)(n0 + lrowB) * 512 + kk,
              smem + 8192 + c * 8192 + (it * 8 + wv) * 512);
      }
    } else {
#pragma unroll
      for (int it = 0; it < 2; ++it) {
        int weff = wv + it * 4;
        gll16(gaddrA(it, k0), smem + c * 4096 + weff * 512);
        gll16(gaddrB(it, k0), smem + 8192 + c * 4096 + weff * 512);
      }
    }
  };

  if (kbeg < kend) stage(0, kbeg);
  __syncthreads();                 // drains the prologue stage
  int cur = 0;
  for (int k0 = kbeg; k0 < kend; k0 += 32) {
    if (k0 + 32 < kend) stage(cur ^ 1, k0 + 32);   // async prefetch next tile
    vshort8 af[4], bf_[4];
#pragma unroll
    for (int s = 0; s < 4; s++) {
      af[s] = *(const vshort8*)&smem[cur * 4096 +
                (((wr * 4 + s) * 4 + (lane >> 4)) * 16 + (lane & 15)) * 8];
      if (V == 0)
        bf_[s] = *(const vshort8*)&smem[8192 + cur * 8192 +
                  (((wc * 4 + s) * 4 + (lane >> 4)) * 16 + (lane & 15)) * 8];
      else
        bf_[s] = *(const vshort8*)&smem[8192 + cur * 4096 +
                  (((wc * 4 + s) * 4 + (lane >> 4)) * 16 + (lane & 15)) * 8];
    }
#pragma unroll
    for (int i = 0; i < 4; i++)
#pragma unroll
      for (int j = 0; j < 4; j++)
        acc[i][j] = __builtin_amdgcn_mfma_f32_16x16x32_bf16(af[i], bf_[j], acc[i][j], 0, 0, 0);
    __syncthreads();               // drains prefetch + protects buffer swap
    cur ^= 1;
  }

  // ---- epilogue ----
  if (V == 0 && bn < 96) {
    // 4 phases; phase p handles n-cols [n0+p*64, +64) via LDS transpose.
    // New A2T layout: block writes [b][cjw][kh][o 256][sp 128] contiguous.
    const int strd = 136;
    const int b = m0 >> 10;
    const int cjw = (m0 & 1023) >> 7;
#pragma unroll
    for (int p = 0; p < 4; ++p) {
      __syncthreads();
      if (wc == p) {
#pragma unroll
        for (int i = 0; i < 4; i++) {
#pragma unroll
          for (int j = 0; j < 4; j++) {
            f32x4 v = acc[i][j];
            int mloc = wr * 64 + i * 16 + ((lane >> 4) << 2);  // sp in [0,128)
            int phys = j * 16 + (lane & 15);                   // n-off in [0,64)
            vshort4 pk = { (short)f2b(v[0]), (short)f2b(v[1]),
                           (short)f2b(v[2]), (short)f2b(v[3]) };
            *(vshort4*)&smem[phys * strd + mloc] = pk;
          }
        }
      }
      __syncthreads();
      int rowp = tid >> 3, t8 = tid & 7;
      int n = n0 + p * 64 + rowp;
      int o = n & 511, kh = n >> 9;
      u16* dst = a.A2T + (size_t)b * A2T_B + (size_t)cjw * A2T_CJ
               + (size_t)kh * A2T_KH + (size_t)o * 128 + t8 * 16;
      const u16* srcl = &smem[rowp * strd + t8 * 16];
      *(vuint4*)(dst)     = *(const vuint4*)(srcl);
      *(vuint4*)(dst + 8) = *(const vuint4*)(srcl + 8);
    }
    return;
  }

#pragma unroll
  for (int i = 0; i < 4; i++) {
    int em = m0 + wr * 64 + i * 16 + ((lane >> 4) << 2);
#pragma unroll
    for (int j = 0; j < 4; j++) {
      int n = n0 + wc * 64 + j * 16 + (lane & 15);
      f32x4 v = acc[i][j];
      if (V == 0) {
        int b = em >> 10, s = em & 1023;
        int jj = (n - 24576) >> 9, o = n & 511;
#pragma unroll
        for (int t = 0; t < 4; t++)
          a.Au[((size_t)(b * 3 + jj) * 1024 + (s + t)) * 512 + o] = f2b(v[t]);
      } else if (V == 1) {
        u16* C = a.Cb + (size_t)slot * 524288;
#pragma unroll
        for (int t = 0; t < 4; t++) C[(size_t)(em + t) * 512 + n] = f2b(v[t]);
      } else if (V == 2) {
        float* C = a.Cf + (size_t)zz * 1048576;
#pragma unroll
        for (int t = 0; t < 4; t++) C[(size_t)(em + t) * 512 + n] = v[t];
      } else if (V == 3) {
        int jj = n >> 9, oo = n & 511;
#pragma unroll
        for (int t = 0; t < 4; t++) {
          int m = em + t;
          if (m < a.M) {
            int b = m >> 5, c = m & 31;
            float zv = a.zf[(size_t)(jj * 64 + b * 32 + c) * 512 + oo];
            a.out[(size_t)b * 524288 + (size_t)(c * 32 + jj) * 512 + oo] = v[t] + zv;
          }
        }
      } else if (V == 5) {
        u16* C = a.Cb + (size_t)zz * 524288;
#pragma unroll
        for (int t = 0; t < 4; t++) C[(size_t)(em + t) * 1024 + n] = f2b(v[t]);
      } else if (V == 6) {
        int jrow = (n < 512) ? 31 : 30, oo = n & 511;
#pragma unroll
        for (int t = 0; t < 4; t++) {
          int m = em + t;
          if (m < 62) {
            int b = m & 1, c = m >> 1;
            a.Cf[(size_t)m * 1024 + n] =
                v[t] + a.zf[(size_t)(jrow * 64 + b * 32 + (c + 1)) * 512 + oo];
          }
        }
      } else { // V7: odd states
        int jrow = (n < 512) ? 31 : 30, oo = n & 511;
#pragma unroll
        for (int t = 0; t < 4; t++) {
          int m = em + t;
          if (m < 32) {
            int b = m & 1, k2 = m >> 1;
            float val = v[t] + a.zf[(size_t)(jrow * 64 + b * 32 + 2 * k2) * 512 + oo];
            a.Cb[(size_t)(b * 32 + 2 * k2 + 1) * 1024 + n] = f2b(val);
          }
        }
      }
    }
  }
}

// ---------------------------------------------------------------------------
// prep / glue kernels
// ---------------------------------------------------------------------------
// phis[tau*48 + kf]: kf<24 -> phi_s[tau,kf]; kf>=24 -> phi_s[tau,kf-24]*(-1)^tau
__global__ void k_prep_phis(const float* __restrict__ phi, const float* __restrict__ sigma,
                            float* __restrict__ phis) {
  int i = blockIdx.x * 256 + threadIdx.x;
  if (i >= 1024 * 48) return;
  int tau = i / 48, kf = i % 48, k = (kf >= 24) ? kf - 24 : kf;
  float v = phi[tau * 24 + k] * powf(sigma[k], 0.25f);
  if (kf >= 24 && (tau & 1)) v = -v;
  phis[i] = v;
}

// fused: X convert (vec4), W1 convert (vec4 x4 rounds), Wtoep build (vec8)
__global__ void k_prep_all(const float* __restrict__ u, const float* __restrict__ Mp,
                           const float* __restrict__ Mm, const float* __restrict__ Mu,
                           const float* __restrict__ phis,
                           u16* __restrict__ X, u16* __restrict__ W1,
                           u16* __restrict__ Wtoep) {
  int gid = blockIdx.x * 256 + threadIdx.x;   // [0, 1048576)
  if (gid < 262144) {
    int i4 = gid * 4;
    f32x4 v = *(const f32x4*)(u + i4);
    vshort4 pk = { (short)f2b(v[0]), (short)f2b(v[1]), (short)f2b(v[2]), (short)f2b(v[3]) };
    *(vshort4*)(X + i4) = pk;
  }
#pragma unroll
  for (int r = 0; r < 4; ++r) {
    int item = gid + r * 1048576;
    if (item < 3342336) {
      int i4 = item * 4;
      const float* src; int off;
      if (i4 < 6291456) { src = Mp; off = i4; }
      else if (i4 < 12582912) { src = Mm; off = i4 - 6291456; }
      else { src = Mu; off = i4 - 12582912; }
      f32x4 v = *(const f32x4*)(src + off);
      vshort4 pk = { (short)f2b(v[0]), (short)f2b(v[1]), (short)f2b(v[2]), (short)f2b(v[3]) };
      *(vshort4*)(W1 + i4) = pk;
    }
  }
  if (gid < 786432) {
    int i = gid * 8;
    int kap = i % 6144, row = i / 6144;
    int tp = row & 127, d = row >> 7;
    int kh = kap >> 7, sp = kap & 127;
    int tau0 = d * 128 + tp - sp;
    u16 vals[8];
#pragma unroll
    for (int e = 0; e < 8; ++e) {
      int tau = tau0 - e;
      vals[e] = (tau >= 0 && tau < 1024) ? f2b(phis[tau * 48 + kh]) : (u16)0;
    }
    *(vuint4*)(Wtoep + i) = *(const vuint4*)vals;
  }
}

// Top[0]=[I|0], Top[1]=[M1|M2]
__global__ void k_initTop(const float* __restrict__ my, u16* __restrict__ Top) {
  int i = blockIdx.x * 256 + threadIdx.x;
  if (i >= 1048576) return;
  int mat = i >> 19, rem = i & 524287, o = rem >> 10, k = rem & 1023;
  u16 v;
  if (mat == 0) v = (k == o) ? (u16)0x3F80 : (u16)0;
  else v = (k < 512) ? f2b(my[o * 512 + k]) : f2b(my[262144 + o * 512 + (k - 512)]);
  Top[i] = v;
}

// STc[n][k] = S^c[k][n];  S^c = [Top[c]; Top[c-1]]  (tiled transpose)
__global__ __launch_bounds__(256) void k_transT(const u16* __restrict__ Top,
                                                u16* __restrict__ STc, int c) {
  __shared__ u16 tile[64][72];
  int tx = blockIdx.x, ty = blockIdx.y;  // n-tile, k-tile
  int tid = threadIdx.x;
  int r = tid >> 2, seg = tid & 3;
  int k = ty * 64 + r;
  const u16* src = (k < 512) ? Top + (size_t)c * 524288 + (size_t)k * 1024 + tx * 64
                             : Top + (size_t)(c - 1) * 524288 + (size_t)(k - 512) * 1024 + tx * 64;
  *(vuint4*)&tile[r][seg * 16]     = *(const vuint4*)(src + seg * 16);
  *(vuint4*)&tile[r][seg * 16 + 8] = *(const vuint4*)(src + seg * 16 + 8);
  __syncthreads();
  int n = tx * 64 + r;
  u16 tmp[16];
#pragma unroll
  for (int j = 0; j < 16; j++) tmp[j] = tile[seg * 16 + j][r];
  *(vuint4*)&STc[(size_t)n * 1024 + ty * 64 + seg * 16]     = *(vuint4*)&tmp[0];
  *(vuint4*)&STc[(size_t)n * 1024 + ty * 64 + seg * 16 + 8] = *(vuint4*)&tmp[8];
}

__device__ __forceinline__ void addp(float* acc, vuint4 v) {
  const unsigned int* vu = (const unsigned int*)&v;
#pragma unroll
  for (int e = 0; e < 4; ++e) {
    unsigned int pw = vu[e];
    acc[2 * e]     += __builtin_bit_cast(float, (pw & 0xffffu) << 16);
    acc[2 * e + 1] += __builtin_bit_cast(float, pw & 0xffff0000u);
  }
}

// ybf[b,t,og*8..] = sum_j Au[b,j,t-j,:] + (t>=2 ? valid bf16 conv partials : 0)
__global__ void k_combine(const u16* __restrict__ parts, const u16* __restrict__ Au,
                          u16* __restrict__ ybf) {
  int i = blockIdx.x * 256 + threadIdx.x;
  if (i >= 131072) return;
  int og = i & 63, t = (i >> 6) & 1023, b = i >> 16;
  float acc[8];
#pragma unroll
  for (int e = 0; e < 8; ++e) acc[e] = 0.f;
#pragma unroll
  for (int j = 0; j < 3; j++)
    if (t >= j)
      addp(acc, *(const vuint4*)(Au + ((size_t)(b * 3 + j) * 1024 + (t - j)) * 512 + og * 8));
  if (t >= 2) {
    int tp = t - 2, bmv = tp >> 7;
#pragma unroll
    for (int g = 0; g < 8; ++g) {
      if ((g & 1) != b) continue;
      const u16* base = parts + (size_t)(g * 8) * 524288 + (size_t)tp * 512 + og * 8;
      for (int j = 0; j <= bmv; ++j)
        addp(acc, *(const vuint4*)(base + (size_t)j * 524288));
    }
  }
  u16 o16[8];
#pragma unroll
  for (int e = 0; e < 8; ++e) o16[e] = f2b(acc[e]);
  *(vuint4*)(ybf + ((size_t)(b * 1024 + t)) * 512 + og * 8) = *(vuint4*)o16;
}

// fused: zf reduce + Wm extraction + bnd/Abnd zero-init
__global__ void k_zred(const float* __restrict__ zp, float* __restrict__ z,
                       u16* __restrict__ Wm, float* __restrict__ bnd,
                       u16* __restrict__ Abnd) {
  int i = blockIdx.x * 256 + threadIdx.x;
  if (i < 2048) bnd[i] = 0.f;
  if (i < 1024) { Abnd[i] = 0; Abnd[32768 + i] = 0; }
  if (i >= 1048576) return;
  int nsum = (i >> 16) + 1;        // bm = i>>16 in [0,16)
  float s = 0.f;
  for (int j = 0; j < nsum; ++j) s += zp[(size_t)j * 1048576 + i];
  z[i] = s;
  int m = i >> 9, jj = m >> 6, rem = m & 63, b = rem >> 5, c = rem & 31, oo = i & 511;
  if (jj == 31) Wm[(size_t)((c << 1) | b) * 1024 + oo] = f2b(s);
  if (jj == 30) Wm[(size_t)((c << 1) | b) * 1024 + 512 + oo] = f2b(s);
}

// even chain step k: E_{k+1} = S64 E_k + u_{2k}; emit Abnd row (b*32+2k+2)
__global__ __launch_bounds__(256) void k_bnd2(const u16* __restrict__ Top,
                                              const float* __restrict__ ubuf,
                                              float* __restrict__ bnd,
                                              u16* __restrict__ Abnd, int k) {
  __shared__ float st[2048];
  int tid = threadIdx.x;
  const float* s0 = bnd + (size_t)k * 2048;
  for (int j = tid; j < 2048; j += 256) st[j] = s0[j];
  __syncthreads();
  int q4 = blockIdx.x * 256 + tid;  // [0,8192)
  int q = q4 >> 2, quarter = q4 & 3;
  int b = q >> 10, kk = q & 1023;
  const u16* row = (kk < 512) ? Top + (size_t)64 * 524288 + (size_t)kk * 1024
                              : Top + (size_t)63 * 524288 + (size_t)(kk - 512) * 1024;
  const float* stb = st + b * 1024 + quarter * 256;
  const u16* rp = row + quarter * 256;
  float sum = 0.f;
  for (int t = 0; t < 32; ++t) {
    vuint4 v = *(const vuint4*)(rp + t * 8);
    const unsigned int* vu = (const unsigned int*)&v;
#pragma unroll
    for (int e = 0; e < 4; ++e) {
      unsigned int pw = vu[e];
      float lo = __builtin_bit_cast(float, (pw & 0xffffu) << 16);
      float hi = __builtin_bit_cast(float, pw & 0xffff0000u);
      sum += lo * stb[t * 8 + e * 2] + hi * stb[t * 8 + e * 2 + 1];
    }
  }
  sum += __shfl_xor(sum, 1);
  sum += __shfl_xor(sum, 2);
  if (quarter == 0) {
    float s = sum + ubuf[(size_t)(4 * k + b) * 1024 + kk];
    bnd[(size_t)(k + 1) * 2048 + b * 1024 + kk] = s;
    Abnd[(size_t)(b * 32 + 2 * k + 2) * 1024 + kk] = f2b(s);
  }
}

// ---------------------------------------------------------------------------
extern "C" void kernel_launch(void* const* d_in, const int* in_sizes, int n_in,
                              void* d_out, int out_size, void* d_ws, size_t ws_size,
                              hipStream_t stream) {
  const float* u     = (const float*)d_in[0];
  const float* Mu    = (const float*)d_in[1];
  const float* Mp    = (const float*)d_in[2];
  const float* Mm    = (const float*)d_in[3];
  const float* my    = (const float*)d_in[4];
  const float* sigma = (const float*)d_in[5];
  const float* phi   = (const float*)d_in[6];
  float* out = (float*)d_out;

  char* ws = (char*)d_ws;
  size_t off = 0;
  auto alc = [&](size_t b) { size_t p = off; off = (off + b + 255) & ~(size_t)255; return p; };
  u16*  X     = (u16*)(ws + alc(2097152));
  u16*  Wtoep = (u16*)(ws + alc(12582912));    // 8 d x 128 x 6144
  u16*  A2T   = (u16*)(ws + alc(100663296));   // [b][cj][kh][o][sp]
  u16*  Au    = (u16*)(ws + alc(6291456));
  u16*  W1    = (u16*)(ws + alc(26738688));    // 26112x512; parts region spans W1+tail
  char* ptail = ws + alc(40370176); (void)ptail; // W1+tail = 64 MiB exactly
  float* phis = (float*)(ws + alc(196608));    // [1024 tau][48 kf] f32
  float* bnd  = (float*)(ws + alc(131072));    // 16 even states x 2048 f32
  u16*  Abnd  = (u16*)(ws + alc(131072));      // 64 x 1024 bf16 boundary states
  u16*  Wm    = (u16*)(ws + alc(131072));      // 64 x 1024 bf16 w_c
  float* ubuf = (float*)(ws + alc(262144));    // 64 x 1024 f32 u_c
  u16*  zpad  = (u16*)(ws + alc(32768));       // zero page for predicated lanes
  if (off > ws_size) return;
  // lifetime-disjoint aliases:
  u16*  partsBf = (u16*)W1;                    // 64 conv slots x [1024][512] bf16 = 64 MiB
  float* zparts = (float*)W1;                  // 16 zgemm slots x 4 MiB f32 = 64 MiB
  u16*  ybf = A2T;                             // 2 MiB (after conv)
  float* zf = (float*)((char*)A2T + (4 << 20));
  u16*  Top = (u16*)((char*)A2T + (size_t)(8 << 20));   // 65 x 1 MiB
  u16*  STc = (u16*)((char*)A2T + (size_t)(76 << 20));  // 2 MiB scratch

  hipMemsetAsync(zpad, 0, 32768, stream);

  // prep
  k_prep_phis<<<dim3(192), 256, 0, stream>>>(phi, sigma, phis);
  k_prep_all<<<dim3(4096), 256, 0, stream>>>(u, Mp, Mm, Mu, phis, X, W1, Wtoep);

  // GEMM1: projections; 128x256 tile, 512 threads, 1-D XCD-chunked grid
  {
    GB g{}; g.A = X; g.B = W1; g.A2T = A2T; g.Au = Au; g.zp = zpad;
    g.M = 2048; g.N = 26112;
    g2<0><<<dim3(1632), 512, 0, stream>>>(g);
  }
  // CONV: global Wtoep strips, locality-ordered XCD-chunked grid, splitK=8
  {
    GB g{}; g.A = Wtoep; g.B = A2T; g.Cb = partsBf; g.zp = zpad;
    g.M = 1024; g.N = 512;
    g2<1><<<dim3(1152), 256, 0, stream>>>(g);
  }
  k_combine<<<dim3(512), 256, 0, stream>>>(partsBf, Au, ybf);

  // companion-power stack Top[0..32], then Top[63],Top[64] (= S32^2 halves)
  k_initTop<<<dim3(4096), 256, 0, stream>>>(my, Top);
  {
    const int cs[5] = {1, 2, 4, 8, 16};
    for (int li = 0; li < 5; ++li) {
      int c = cs[li];
      k_transT<<<dim3(16, 16), 256, 0, stream>>>(Top, STc, c);
      GB s{}; s.A = Top + 524288; s.B = STc; s.Cb = Top + (size_t)(c + 1) * 524288;
      s.zp = zpad; s.M = 512; s.N = 1024;
      g2<5><<<dim3(8, 4, c), 256, 0, stream>>>(s);
    }
    // Top[63] = Top[31] * S^32, Top[64] = Top[32] * S^32
    k_transT<<<dim3(16, 16), 256, 0, stream>>>(Top, STc, 32);
    GB s{}; s.A = Top + (size_t)31 * 524288; s.B = STc;
    s.Cb = Top + (size_t)63 * 524288; s.zp = zpad; s.M = 512; s.N = 1024;
    g2<5><<<dim3(8, 4, 2), 256, 0, stream>>>(s);
  }

  // within-chunk solve: z = Tri(H) y; compact triangular grid, 16 slices
  {
    GB g{}; g.A = ybf; g.B = Top; g.Cf = zparts; g.zp = zpad;
    g.M = 2048; g.N = 512;
    g2<2><<<dim3(544), 256, 0, stream>>>(g);
  }
  k_zred<<<dim3(4096), 256, 0, stream>>>(zparts, zf, Wm, bnd, Abnd);

  // boundary chain: u_c precompute, 15 even steps, batched odd fill
  {
    GB g{}; g.A = Wm; g.B = Top; g.Cf = ubuf; g.zf = zf; g.zp = zpad;
    g.M = 64; g.N = 1024;
    g2<6><<<dim3(8, 1, 1), 256, 0, stream>>>(g);
  }
  for (int k = 0; k < 15; ++k)
    k_bnd2<<<dim3(32), 256, 0, stream>>>(Top, ubuf, bnd, Abnd, k);
  {
    GB g{}; g.A = Abnd; g.B = Top; g.Cb = Abnd; g.zf = zf; g.zp = zpad;
    g.M = 32; g.N = 1024;
    g2<7><<<dim3(8, 1, 1), 256, 0, stream>>>(g);
  }

  // fixup: out = z + [H_{j+1}|G_j] @ Abnd
  {
    GB g{}; g.A = Abnd; g.B = Top; g.zf = zf; g.out = out; g.zp = zpad;
    g.M = 64; g.N = 16384;
    g2<3><<<dim3(128, 1, 1), 256, 0, stream>>>(g);
  }
}

// Round 14
// 693.204 us; speedup vs baseline: 1.2389x; 1.0098x over previous
//
#include <hip/hip_runtime.h>
#include <hip/hip_bf16.h>

// STU forward, R14: R13 with the V5 dual-write epilogue copy-width bug fixed
// (each thread copies 32 u16, not 16). P-maintenance kills all transT launches.
// Sizes: B=2, L=1024, K=24(x2), D=512, K_U=3, K_Y=2.

typedef unsigned short u16;
typedef __attribute__((ext_vector_type(8))) short  vshort8;
typedef __attribute__((ext_vector_type(4))) short  vshort4;
typedef __attribute__((ext_vector_type(4))) float  f32x4;
typedef __attribute__((ext_vector_type(4))) unsigned int vuint4;

__device__ __forceinline__ u16 f2b(float x) {
  __hip_bfloat16 h = __float2bfloat16(x);
  return __builtin_bit_cast(u16, h);
}
__device__ __forceinline__ float b2f(u16 x) {
  unsigned int u = ((unsigned int)x) << 16;
  return __builtin_bit_cast(float, u);
}

// async global->LDS, 16B per lane; LDS dest = wave-uniform base + lane*16
__device__ __forceinline__ void gll16(const u16* g, u16* l) {
  __builtin_amdgcn_global_load_lds((__attribute__((address_space(1))) void*)g,
                                   (__attribute__((address_space(3))) void*)l,
                                   16, 0, 0);
}

// A2T layout strides: [b:2][cj:8][kh:48][o:512][sp:128]
#define A2T_B  25165824
#define A2T_CJ 3145728
#define A2T_KH 65536

// ---------------------------------------------------------------------------
// Shared MFMA GEMM template. C[m,n] = sum_k A[m,k]*Bmat[n,k].
//  V0 GEMM1: 128x256 tile, 512 thr; A=X(2048x512) B=W1(26112x512); grid 1632
//  V1 CONV : A=Wtoep strip (d=bm-cj), B=A2T; 1-D grid 1152, splitK=8
//  V2 ZGEMM: A=gather(ybf), B=Top; 1-D grid 544 triangular, 16 slices
//  V3 FIXUP: A=Abnd(64x1024), B=Top[j+1] rows -> out = acc + zf
//  V5 SGEMM: A=Top[1+bz], B=S^c^T from P; -> Top[c+1+bz] + P[c+1+bz] (dual)
//  V6 UGEMM: A=Wm(64x1024), B=S32 rows -> ubuf = acc + w_{c+1} (f32)
//  V7 ODD  : A=Abnd even rows, B=S32 rows -> Abnd odd rows = acc + w_{2k}
// ---------------------------------------------------------------------------
struct GB {
  const u16* A; const u16* B;
  float* Cf; u16* Cb;
  const float* zf; float* out;
  u16* A2T; u16* Au;
  const u16* zp;
  u16* Pb; int cidx; int pthr;
  int M, N;
};

template<int V>
__global__ __launch_bounds__(V == 0 ? 512 : 256) void g2(GB a) {
  const int tid = threadIdx.x;
  int bn = blockIdx.x, bm = blockIdx.y;
  int zz = blockIdx.z;
  int cj = 0, cb = 0, cd = 0, slot = 0;
  int kbeg = 0, kend = 0;
  if (V == 0) {
    int f = blockIdx.x;
    int o = (f & 7) * 204 + (f >> 3);          // 1632 = 8 x 204
    bm = o & 15; bn = o >> 4; kend = 512;
  }
  if (V == 1) {
    int f = blockIdx.x;
    int o = (f & 7) * 144 + (f >> 3);          // 1152 = 8 x 144
    const int offs1[8] = {0, 256, 480, 672, 832, 960, 1056, 1120};
    cj = 0;
    if (o >= offs1[1]) cj = 1;
    if (o >= offs1[2]) cj = 2;
    if (o >= offs1[3]) cj = 3;
    if (o >= offs1[4]) cj = 4;
    if (o >= offs1[5]) cj = 5;
    if (o >= offs1[6]) cj = 6;
    if (o >= offs1[7]) cj = 7;
    int r = o - offs1[cj];
    int run = 8 - cj;
    int combo = r / run;                       // [0,32): (zzc, bn)
    bm = cj + (r - combo * run);
    int zzc = combo >> 2; bn = combo & 3;
    cb = zzc & 1; cd = bm - cj;
    slot = zzc * 8 + cj;
    kbeg = (zzc >> 1) * 1536; kend = kbeg + 1536;
  }
  if (V == 2) {
    int f = blockIdx.x;
    int o = (f & 7) * 68 + (f >> 3);           // 544 = 8 x 68
    const int offs2[16] = {0, 64, 124, 180, 232, 280, 324, 364,
                           400, 432, 460, 484, 504, 520, 532, 540};
    int s = 0;
#pragma unroll
    for (int c = 1; c < 16; ++c)
      if (o >= offs2[c]) s = c;
    int r = o - offs2[s];
    bm = s + (r >> 2); bn = r & 3;
    zz = s;
    kbeg = s * 1024; kend = kbeg + 1024;       // s<=bm guarantees validity
  }
  const int m0 = bm * 128;
  const int n0 = (V == 0) ? bn * 256 : bn * 128;
  if (V == 3 || V == 5 || V == 6 || V == 7) kend = 1024;

  __shared__ u16 smem[V == 0 ? 24576 : 16384];
  f32x4 acc[4][4];
#pragma unroll
  for (int i = 0; i < 4; i++)
#pragma unroll
    for (int j = 0; j < 4; j++) acc[i][j] = f32x4{0.f, 0.f, 0.f, 0.f};

  const int lane = tid & 63, wv = tid >> 6;
  const int wr = (V == 0) ? (wv >> 2) : (wv >> 1);
  const int wc = (V == 0) ? (wv & 3) : (wv & 1);
  const u16* Ap = a.A;
  if (V == 5) Ap = a.A + (size_t)zz * 524288;
  const u16* zpl = a.zp + lane * 8;

  auto gaddrA = [&](int it, int k0) -> const u16* {
    int lrow = (it * 4 + wv) * 16 + (lane & 15);
    int kk = k0 + ((lane >> 4) << 3);
    if (V == 1) return Ap + (size_t)cd * 786432 + (size_t)lrow * 6144 + kk;
    if (V == 2) {
      int m = m0 + lrow, j = m >> 6, b = (m >> 5) & 1, c = m & 31;
      int tau = kk >> 9, p = kk & 511;
      if (tau > j) return zpl;
      return Ap + (size_t)(b * 1024 + c * 32 + j - tau) * 512 + p;
    }
    if (V == 3) { int m = m0 + lrow; return (m < a.M) ? Ap + (size_t)m * 1024 + kk : zpl; }
    if (V == 5) return Ap + (size_t)(m0 + lrow) * 1024 + kk;
    if (V == 6) return (lrow < 64) ? Ap + (size_t)lrow * 1024 + kk : zpl;
    // V7
    if (lrow < 32) {
      int b = lrow & 1, k2 = lrow >> 1;
      return Ap + (size_t)(b * 32 + 2 * k2) * 1024 + kk;
    }
    return zpl;
  };
  auto gaddrB = [&](int it, int k0) -> const u16* {
    int lrow = (it * 4 + wv) * 16 + (lane & 15);
    int kk = k0 + ((lane >> 4) << 3);
    int n = n0 + lrow;
    if (V == 1) {
      int kh = kk >> 7, sp = kk & 127;
      return a.B + (size_t)cb * A2T_B + (size_t)cj * A2T_CJ
           + (size_t)kh * A2T_KH + (size_t)n * 128 + sp;
    }
    if (V == 2) {
      int tau = kk >> 9, p = kk & 511;
      return a.B + (size_t)tau * 524288 + (size_t)n * 1024 + p;
    }
    if (V == 3) {
      int jn = n >> 9, o = n & 511;
      return a.B + (size_t)(jn + 1) * 524288 + (size_t)o * 1024 + kk;
    }
    if (V == 5) {
      // B[n][kk] = S^c^T[n][kk] from P
      return (kk < 512)
          ? a.Pb + (size_t)a.cidx * 524288 + (size_t)n * 512 + kk
          : a.Pb + (size_t)(a.cidx - 1) * 524288 + (size_t)n * 512 + (kk - 512);
    }
    // V6/V7: rows of S32 = [Top32 ; Top31]
    return (n < 512)
        ? a.B + (size_t)32 * 524288 + (size_t)n * 1024 + kk
        : a.B + (size_t)31 * 524288 + (size_t)(n - 512) * 1024 + kk;
  };

  auto stage = [&](int c, int k0) {
    if (V == 0) {
      int kk = k0 + ((lane >> 4) << 3);
      int lrowA = wv * 16 + (lane & 15);
      gll16(Ap + (size_t)(m0 + lrowA) * 512 + kk, smem + c * 4096 + wv * 512);
#pragma unroll
      for (int it = 0; it < 2; ++it) {
        int lrowB = (it * 8 + wv) * 16 + (lane & 15);
        gll16(a.B + (size_t)(n0 + lrowB) * 512 + kk,
              smem + 8192 + c * 8192 + (it * 8 + wv) * 512);
      }
    } else {
#pragma unroll
      for (int it = 0; it < 2; ++it) {
        int weff = wv + it * 4;
        gll16(gaddrA(it, k0), smem + c * 4096 + weff * 512);
        gll16(gaddrB(it, k0), smem + 8192 + c * 4096 + weff * 512);
      }
    }
  };

  if (kbeg < kend) stage(0, kbeg);
  __syncthreads();                 // drains the prologue stage
  int cur = 0;
  for (int k0 = kbeg; k0 < kend; k0 += 32) {
    if (k0 + 32 < kend) stage(cur ^ 1, k0 + 32);   // async prefetch next tile
    vshort8 af[4], bf_[4];
#pragma unroll
    for (int s = 0; s < 4; s++) {
      af[s] = *(const vshort8*)&smem[cur * 4096 +
                (((wr * 4 + s) * 4 + (lane >> 4)) * 16 + (lane & 15)) * 8];
      if (V == 0)
        bf_[s] = *(const vshort8*)&smem[8192 + cur * 8192 +
                  (((wc * 4 + s) * 4 + (lane >> 4)) * 16 + (lane & 15)) * 8];
      else
        bf_[s] = *(const vshort8*)&smem[8192 + cur * 4096 +
                  (((wc * 4 + s) * 4 + (lane >> 4)) * 16 + (lane & 15)) * 8];
    }
#pragma unroll
    for (int i = 0; i < 4; i++)
#pragma unroll
      for (int j = 0; j < 4; j++)
        acc[i][j] = __builtin_amdgcn_mfma_f32_16x16x32_bf16(af[i], bf_[j], acc[i][j], 0, 0, 0);
    __syncthreads();               // drains prefetch + protects buffer swap
    cur ^= 1;
  }

  // ---- epilogue ----
  if (V == 0 && bn < 96) {
    // 4 phases; phase p handles n-cols [n0+p*64, +64) via LDS transpose.
    const int strd = 136;
    const int b = m0 >> 10;
    const int cjw = (m0 & 1023) >> 7;
#pragma unroll
    for (int p = 0; p < 4; ++p) {
      __syncthreads();
      if (wc == p) {
#pragma unroll
        for (int i = 0; i < 4; i++) {
#pragma unroll
          for (int j = 0; j < 4; j++) {
            f32x4 v = acc[i][j];
            int mloc = wr * 64 + i * 16 + ((lane >> 4) << 2);  // sp in [0,128)
            int phys = j * 16 + (lane & 15);                   // n-off in [0,64)
            vshort4 pk = { (short)f2b(v[0]), (short)f2b(v[1]),
                           (short)f2b(v[2]), (short)f2b(v[3]) };
            *(vshort4*)&smem[phys * strd + mloc] = pk;
          }
        }
      }
      __syncthreads();
      int rowp = tid >> 3, t8 = tid & 7;
      int n = n0 + p * 64 + rowp;
      int o = n & 511, kh = n >> 9;
      u16* dst = a.A2T + (size_t)b * A2T_B + (size_t)cjw * A2T_CJ
               + (size_t)kh * A2T_KH + (size_t)o * 128 + t8 * 16;
      const u16* srcl = &smem[rowp * strd + t8 * 16];
      *(vuint4*)(dst)     = *(const vuint4*)(srcl);
      *(vuint4*)(dst + 8) = *(const vuint4*)(srcl + 8);
    }
    return;
  }

#pragma unroll
  for (int i = 0; i < 4; i++) {
    int em = m0 + wr * 64 + i * 16 + ((lane >> 4) << 2);
#pragma unroll
    for (int j = 0; j < 4; j++) {
      int n = n0 + wc * 64 + j * 16 + (lane & 15);
      f32x4 v = acc[i][j];
      if (V == 0) {
        int b = em >> 10, s = em & 1023;
        int jj = (n - 24576) >> 9, o = n & 511;
#pragma unroll
        for (int t = 0; t < 4; t++)
          a.Au[((size_t)(b * 3 + jj) * 1024 + (s + t)) * 512 + o] = f2b(v[t]);
      } else if (V == 1) {
        u16* C = a.Cb + (size_t)slot * 524288;
#pragma unroll
        for (int t = 0; t < 4; t++) C[(size_t)(em + t) * 512 + n] = f2b(v[t]);
      } else if (V == 2) {
        float* C = a.Cf + (size_t)zz * 1048576;
#pragma unroll
        for (int t = 0; t < 4; t++) C[(size_t)(em + t) * 512 + n] = v[t];
      } else if (V == 3) {
        int jj = n >> 9, oo = n & 511;
#pragma unroll
        for (int t = 0; t < 4; t++) {
          int m = em + t;
          if (m < a.M) {
            int b = m >> 5, c = m & 31;
            float zv = a.zf[(size_t)(jj * 64 + b * 32 + c) * 512 + oo];
            a.out[(size_t)b * 524288 + (size_t)(c * 32 + jj) * 512 + oo] = v[t] + zv;
          }
        }
      } else if (V == 5) {
        u16* C = a.Cb + (size_t)zz * 524288;
#pragma unroll
        for (int t = 0; t < 4; t++) C[(size_t)(em + t) * 1024 + n] = f2b(v[t]);
      } else if (V == 6) {
        int jrow = (n < 512) ? 31 : 30, oo = n & 511;
#pragma unroll
        for (int t = 0; t < 4; t++) {
          int m = em + t;
          if (m < 62) {
            int b = m & 1, c = m >> 1;
            a.Cf[(size_t)m * 1024 + n] =
                v[t] + a.zf[(size_t)(jrow * 64 + b * 32 + (c + 1)) * 512 + oo];
          }
        }
      } else { // V7: odd states
        int jrow = (n < 512) ? 31 : 30, oo = n & 511;
#pragma unroll
        for (int t = 0; t < 4; t++) {
          int m = em + t;
          if (m < 32) {
            int b = m & 1, k2 = m >> 1;
            float val = v[t] + a.zf[(size_t)(jrow * 64 + b * 32 + 2 * k2) * 512 + oo];
            a.Cb[(size_t)(b * 32 + 2 * k2 + 1) * 1024 + n] = f2b(val);
          }
        }
      }
    }
  }

  // V5 dual-write: P[c+1+zz][n][m] = C[m][n] via LDS transpose (2 passes)
  if (V == 5) {
    if (zz >= a.pthr) {
      const int strd = 136;
      u16* Pout = a.Pb + (size_t)(a.cidx + 1 + zz) * 524288;
#pragma unroll
      for (int p = 0; p < 2; ++p) {
        __syncthreads();
        if (wc == p) {
#pragma unroll
          for (int i = 0; i < 4; i++) {
#pragma unroll
            for (int j = 0; j < 4; j++) {
              f32x4 v = acc[i][j];
              int mloc = wr * 64 + i * 16 + ((lane >> 4) << 2);  // m-off [0,128)
              int phys = j * 16 + (lane & 15);                   // n-off [0,64)
              vshort4 pk = { (short)f2b(v[0]), (short)f2b(v[1]),
                             (short)f2b(v[2]), (short)f2b(v[3]) };
              *(vshort4*)&smem[phys * strd + mloc] = pk;
            }
          }
        }
        __syncthreads();
        int rowp = tid >> 2, t4 = tid & 3;
        u16* dst = Pout + (size_t)(n0 + p * 64 + rowp) * 512 + m0 + t4 * 32;
        const u16* srcl = &smem[rowp * strd + t4 * 32];
#pragma unroll
        for (int q = 0; q < 4; ++q)
          *(vuint4*)(dst + q * 8) = *(const vuint4*)(srcl + q * 8);
      }
    }
  }
}

// ---------------------------------------------------------------------------
// prep / glue kernels
// ---------------------------------------------------------------------------
// phis[tau*48 + kf]: kf<24 -> phi_s[tau,kf]; kf>=24 -> phi_s[tau,kf-24]*(-1)^tau
__global__ void k_prep_phis(const float* __restrict__ phi, const float* __restrict__ sigma,
                            float* __restrict__ phis) {
  int i = blockIdx.x * 256 + threadIdx.x;
  if (i >= 1024 * 48) return;
  int tau = i / 48, kf = i % 48, k = (kf >= 24) ? kf - 24 : kf;
  float v = phi[tau * 24 + k] * powf(sigma[k], 0.25f);
  if (kf >= 24 && (tau & 1)) v = -v;
  phis[i] = v;
}

// fused: X convert (vec4), W1 convert (vec4 x4 rounds), Wtoep build (vec8)
__global__ void k_prep_all(const float* __restrict__ u, const float* __restrict__ Mp,
                           const float* __restrict__ Mm, const float* __restrict__ Mu,
                           const float* __restrict__ phis,
                           u16* __restrict__ X, u16* __restrict__ W1,
                           u16* __restrict__ Wtoep) {
  int gid = blockIdx.x * 256 + threadIdx.x;   // [0, 1048576)
  if (gid < 262144) {
    int i4 = gid * 4;
    f32x4 v = *(const f32x4*)(u + i4);
    vshort4 pk = { (short)f2b(v[0]), (short)f2b(v[1]), (short)f2b(v[2]), (short)f2b(v[3]) };
    *(vshort4*)(X + i4) = pk;
  }
#pragma unroll
  for (int r = 0; r < 4; ++r) {
    int item = gid + r * 1048576;
    if (item < 3342336) {
      int i4 = item * 4;
      const float* src; int off;
      if (i4 < 6291456) { src = Mp; off = i4; }
      else if (i4 < 12582912) { src = Mm; off = i4 - 6291456; }
      else { src = Mu; off = i4 - 12582912; }
      f32x4 v = *(const f32x4*)(src + off);
      vshort4 pk = { (short)f2b(v[0]), (short)f2b(v[1]), (short)f2b(v[2]), (short)f2b(v[3]) };
      *(vshort4*)(W1 + i4) = pk;
    }
  }
  if (gid < 786432) {
    int i = gid * 8;
    int kap = i % 6144, row = i / 6144;
    int tp = row & 127, d = row >> 7;
    int kh = kap >> 7, sp = kap & 127;
    int tau0 = d * 128 + tp - sp;
    u16 vals[8];
#pragma unroll
    for (int e = 0; e < 8; ++e) {
      int tau = tau0 - e;
      vals[e] = (tau >= 0 && tau < 1024) ? f2b(phis[tau * 48 + kh]) : (u16)0;
    }
    *(vuint4*)(Wtoep + i) = *(const vuint4*)vals;
  }
}

// Top[0]=[I|0], Top[1]=[M1|M2]; P[0]=Top[0]^T, P[1]=Top[1]^T
__global__ void k_initTop(const float* __restrict__ my, u16* __restrict__ Top,
                          u16* __restrict__ P) {
  int i = blockIdx.x * 256 + threadIdx.x;
  if (i >= 2097152) return;
  if (i < 1048576) {
    int mat = i >> 19, rem = i & 524287, o = rem >> 10, k = rem & 1023;
    u16 v;
    if (mat == 0) v = (k == o) ? (u16)0x3F80 : (u16)0;
    else v = (k < 512) ? f2b(my[o * 512 + k]) : f2b(my[262144 + o * 512 + (k - 512)]);
    Top[i] = v;
  } else {
    int j = i - 1048576;
    int mat = j >> 19, rem = j & 524287, n = rem >> 9, m = rem & 511;
    u16 v;
    if (mat == 0) v = (n == m) ? (u16)0x3F80 : (u16)0;
    else v = (n < 512) ? f2b(my[m * 512 + n]) : f2b(my[262144 + m * 512 + (n - 512)]);
    P[(size_t)mat * 524288 + (size_t)n * 512 + m] = v;
  }
}

__device__ __forceinline__ void addp(float* acc, vuint4 v) {
  const unsigned int* vu = (const unsigned int*)&v;
#pragma unroll
  for (int e = 0; e < 4; ++e) {
    unsigned int pw = vu[e];
    acc[2 * e]     += __builtin_bit_cast(float, (pw & 0xffffu) << 16);
    acc[2 * e + 1] += __builtin_bit_cast(float, pw & 0xffff0000u);
  }
}

// ybf[b,t,og*8..] = sum_j Au[b,j,t-j,:] + (t>=2 ? valid bf16 conv partials : 0)
__global__ void k_combine(const u16* __restrict__ parts, const u16* __restrict__ Au,
                          u16* __restrict__ ybf) {
  int i = blockIdx.x * 256 + threadIdx.x;
  if (i >= 131072) return;
  int og = i & 63, t = (i >> 6) & 1023, b = i >> 16;
  float acc[8];
#pragma unroll
  for (int e = 0; e < 8; ++e) acc[e] = 0.f;
#pragma unroll
  for (int j = 0; j < 3; j++)
    if (t >= j)
      addp(acc, *(const vuint4*)(Au + ((size_t)(b * 3 + j) * 1024 + (t - j)) * 512 + og * 8));
  if (t >= 2) {
    int tp = t - 2, bmv = tp >> 7;
#pragma unroll
    for (int g = 0; g < 8; ++g) {
      if ((g & 1) != b) continue;
      const u16* base = parts + (size_t)(g * 8) * 524288 + (size_t)tp * 512 + og * 8;
      for (int j = 0; j <= bmv; ++j)
        addp(acc, *(const vuint4*)(base + (size_t)j * 524288));
    }
  }
  u16 o16[8];
#pragma unroll
  for (int e = 0; e < 8; ++e) o16[e] = f2b(acc[e]);
  *(vuint4*)(ybf + ((size_t)(b * 1024 + t)) * 512 + og * 8) = *(vuint4*)o16;
}

// fused: zf reduce + Wm extraction + bnd/Abnd zero-init
__global__ void k_zred(const float* __restrict__ zp, float* __restrict__ z,
                       u16* __restrict__ Wm, float* __restrict__ bnd,
                       u16* __restrict__ Abnd) {
  int i = blockIdx.x * 256 + threadIdx.x;
  if (i < 2048) bnd[i] = 0.f;
  if (i < 1024) { Abnd[i] = 0; Abnd[32768 + i] = 0; }
  if (i >= 1048576) return;
  int nsum = (i >> 16) + 1;        // bm = i>>16 in [0,16)
  float s = 0.f;
  for (int j = 0; j < nsum; ++j) s += zp[(size_t)j * 1048576 + i];
  z[i] = s;
  int m = i >> 9, jj = m >> 6, rem = m & 63, b = rem >> 5, c = rem & 31, oo = i & 511;
  if (jj == 31) Wm[(size_t)((c << 1) | b) * 1024 + oo] = f2b(s);
  if (jj == 30) Wm[(size_t)((c << 1) | b) * 1024 + 512 + oo] = f2b(s);
}

// even chain step k: E_{k+1} = S64 E_k + u_{2k}; emit Abnd row (b*32+2k+2)
// S64 rows: top = Top slot34, bottom = Top slot33
__global__ __launch_bounds__(256) void k_bnd2(const u16* __restrict__ Top,
                                              const float* __restrict__ ubuf,
                                              float* __restrict__ bnd,
                                              u16* __restrict__ Abnd, int k) {
  __shared__ float st[2048];
  int tid = threadIdx.x;
  const float* s0 = bnd + (size_t)k * 2048;
  for (int j = tid; j < 2048; j += 256) st[j] = s0[j];
  __syncthreads();
  int q4 = blockIdx.x * 256 + tid;  // [0,8192)
  int q = q4 >> 2, quarter = q4 & 3;
  int b = q >> 10, kk = q & 1023;
  const u16* row = (kk < 512) ? Top + (size_t)34 * 524288 + (size_t)kk * 1024
                              : Top + (size_t)33 * 524288 + (size_t)(kk - 512) * 1024;
  const float* stb = st + b * 1024 + quarter * 256;
  const u16* rp = row + quarter * 256;
  float sum = 0.f;
  for (int t = 0; t < 32; ++t) {
    vuint4 v = *(const vuint4*)(rp + t * 8);
    const unsigned int* vu = (const unsigned int*)&v;
#pragma unroll
    for (int e = 0; e < 4; ++e) {
      unsigned int pw = vu[e];
      float lo = __builtin_bit_cast(float, (pw & 0xffffu) << 16);
      float hi = __builtin_bit_cast(float, pw & 0xffff0000u);
      sum += lo * stb[t * 8 + e * 2] + hi * stb[t * 8 + e * 2 + 1];
    }
  }
  sum += __shfl_xor(sum, 1);
  sum += __shfl_xor(sum, 2);
  if (quarter == 0) {
    float s = sum + ubuf[(size_t)(4 * k + b) * 1024 + kk];
    bnd[(size_t)(k + 1) * 2048 + b * 1024 + kk] = s;
    Abnd[(size_t)(b * 32 + 2 * k + 2) * 1024 + kk] = f2b(s);
  }
}

// ---------------------------------------------------------------------------
extern "C" void kernel_launch(void* const* d_in, const int* in_sizes, int n_in,
                              void* d_out, int out_size, void* d_ws, size_t ws_size,
                              hipStream_t stream) {
  const float* u     = (const float*)d_in[0];
  const float* Mu    = (const float*)d_in[1];
  const float* Mp    = (const float*)d_in[2];
  const float* Mm    = (const float*)d_in[3];
  const float* my    = (const float*)d_in[4];
  const float* sigma = (const float*)d_in[5];
  const float* phi   = (const float*)d_in[6];
  float* out = (float*)d_out;

  char* ws = (char*)d_ws;
  size_t off = 0;
  auto alc = [&](size_t b) { size_t p = off; off = (off + b + 255) & ~(size_t)255; return p; };
  u16*  X     = (u16*)(ws + alc(2097152));
  u16*  Wtoep = (u16*)(ws + alc(12582912));    // 8 d x 128 x 6144
  u16*  A2T   = (u16*)(ws + alc(100663296));   // [b][cj][kh][o][sp]
  u16*  Au    = (u16*)(ws + alc(6291456));
  u16*  W1    = (u16*)(ws + alc(26738688));    // 26112x512; parts region spans W1+tail
  char* ptail = ws + alc(40370176); (void)ptail; // W1+tail = 64 MiB exactly
  float* phis = (float*)(ws + alc(196608));    // [1024 tau][48 kf] f32
  float* bnd  = (float*)(ws + alc(131072));    // 16 even states x 2048 f32
  u16*  Abnd  = (u16*)(ws + alc(131072));      // 64 x 1024 bf16 boundary states
  u16*  Wm    = (u16*)(ws + alc(131072));      // 64 x 1024 bf16 w_c
  float* ubuf = (float*)(ws + alc(262144));    // 64 x 1024 f32 u_c
  u16*  zpad  = (u16*)(ws + alc(32768));       // zero page for predicated lanes
  if (off > ws_size) return;
  // lifetime-disjoint aliases:
  u16*  partsBf = (u16*)W1;                    // 64 conv slots x [1024][512] bf16 = 64 MiB
  float* zparts = (float*)W1;                  // 16 zgemm slots x 4 MiB f32 = 64 MiB
  u16*  ybf = A2T;                             // 2 MiB (after conv)
  float* zf = (float*)((char*)A2T + (4 << 20));
  u16*  Top = (u16*)((char*)A2T + (size_t)(8 << 20));   // 35 slots x 1 MiB (0..32,33=H63,34=H64)
  u16*  P   = (u16*)((char*)A2T + (size_t)(44 << 20));  // 33 slots x 1 MiB (Top^T)

  hipMemsetAsync(zpad, 0, 32768, stream);

  // prep
  k_prep_phis<<<dim3(192), 256, 0, stream>>>(phi, sigma, phis);
  k_prep_all<<<dim3(4096), 256, 0, stream>>>(u, Mp, Mm, Mu, phis, X, W1, Wtoep);

  // GEMM1: projections; 128x256 tile, 512 threads, 1-D XCD-chunked grid
  {
    GB g{}; g.A = X; g.B = W1; g.A2T = A2T; g.Au = Au; g.zp = zpad;
    g.M = 2048; g.N = 26112;
    g2<0><<<dim3(1632), 512, 0, stream>>>(g);
  }
  // CONV: global Wtoep strips, locality-ordered XCD-chunked grid, splitK=8
  {
    GB g{}; g.A = Wtoep; g.B = A2T; g.Cb = partsBf; g.zp = zpad;
    g.M = 1024; g.N = 512;
    g2<1><<<dim3(1152), 256, 0, stream>>>(g);
  }
  k_combine<<<dim3(512), 256, 0, stream>>>(partsBf, Au, ybf);

  // companion-power stack Top[0..32] (+P at needed indices), then slots 33/34
  k_initTop<<<dim3(8192), 256, 0, stream>>>(my, Top, P);
  {
    const int cs[5] = {1, 2, 4, 8, 16};
    for (int li = 0; li < 5; ++li) {
      int c = cs[li];
      GB s{}; s.A = Top + 524288; s.Cb = Top + (size_t)(c + 1) * 524288;
      s.Pb = P; s.cidx = c; s.pthr = c - 2;
      s.zp = zpad; s.M = 512; s.N = 1024;
      g2<5><<<dim3(8, 4, c), 256, 0, stream>>>(s);
    }
    // slot33 = Top[31]*S^32 (=H63), slot34 = Top[32]*S^32 (=H64)
    GB s{}; s.A = Top + (size_t)31 * 524288;
    s.Cb = Top + (size_t)33 * 524288;
    s.Pb = P; s.cidx = 32; s.pthr = 99;
    s.zp = zpad; s.M = 512; s.N = 1024;
    g2<5><<<dim3(8, 4, 2), 256, 0, stream>>>(s);
  }

  // within-chunk solve: z = Tri(H) y; compact triangular grid, 16 slices
  {
    GB g{}; g.A = ybf; g.B = Top; g.Cf = zparts; g.zp = zpad;
    g.M = 2048; g.N = 512;
    g2<2><<<dim3(544), 256, 0, stream>>>(g);
  }
  k_zred<<<dim3(4096), 256, 0, stream>>>(zparts, zf, Wm, bnd, Abnd);

  // boundary chain: u_c precompute, 15 even steps, batched odd fill
  {
    GB g{}; g.A = Wm; g.B = Top; g.Cf = ubuf; g.zf = zf; g.zp = zpad;
    g.M = 64; g.N = 1024;
    g2<6><<<dim3(8, 1, 1), 256, 0, stream>>>(g);
  }
  for (int k = 0; k < 15; ++k)
    k_bnd2<<<dim3(32), 256, 0, stream>>>(Top, ubuf, bnd, Abnd, k);
  {
    GB g{}; g.A = Abnd; g.B = Top; g.Cb = Abnd; g.zf = zf; g.zp = zpad;
    g.M = 32; g.N = 1024;
    g2<7><<<dim3(8, 1, 1), 256, 0, stream>>>(g);
  }

  // fixup: out = z + [H_{j+1}|G_j] @ Abnd
  {
    GB g{}; g.A = Abnd; g.B = Top; g.zf = zf; g.out = out; g.zp = zpad;
    g.M = 64; g.N = 16384;
    g2<3><<<dim3(128, 1, 1), 256, 0, stream>>>(g);
  }
}